// Round 1
// baseline (1030.472 us; speedup 1.0000x reference)
//
#include <hip/hip_runtime.h>
#include <hip/hip_bf16.h>
#include <math.h>

// ---------------------------------------------------------------------------
// GAT 3-layer forward. N=50000 nodes, E=800000 edges, H=4 heads.
// Layers 1,2: in 128 -> 4x32 (relu, identity residual)
// Layer 3:    in 128 -> 4x64 (projected residual, mean over heads) -> [N,64]
// ---------------------------------------------------------------------------

#define NEG_SLOPE 0.2f

// ------------------------- CSR build (per dst) ------------------------------

__global__ void hist_kernel(const int* __restrict__ dst, int* __restrict__ deg, int E) {
    int i = blockIdx.x * blockDim.x + threadIdx.x;
    if (i < E) atomicAdd(&deg[dst[i]], 1);
}

// single-block exclusive scan over n values (cursor holds degrees on entry,
// row starts on exit; row_ptr gets the exclusive scan with row_ptr[n]=total)
__global__ void scan_kernel(int* __restrict__ cursor, int* __restrict__ row_ptr, int n) {
    __shared__ int smem[1024];
    const int tid = threadIdx.x;
    int running = 0;
    for (int base = 0; base < n; base += 1024) {
        int i = base + tid;
        int v = (i < n) ? cursor[i] : 0;
        smem[tid] = v;
        __syncthreads();
        for (int off = 1; off < 1024; off <<= 1) {
            int t = (tid >= off) ? smem[tid - off] : 0;
            __syncthreads();
            smem[tid] += t;
            __syncthreads();
        }
        if (i < n) {
            int excl = running + smem[tid] - v;
            row_ptr[i] = excl;
            cursor[i]  = excl;
        }
        running += smem[1023];
        __syncthreads();
    }
    if (tid == 0) row_ptr[n] = running;
}

__global__ void scatter_kernel(const int* __restrict__ src, const int* __restrict__ dst,
                               int* __restrict__ cursor, int* __restrict__ ssrc, int E) {
    int i = blockIdx.x * blockDim.x + threadIdx.x;
    if (i < E) {
        int d = dst[i];
        int pos = atomicAdd(&cursor[d], 1);
        ssrc[pos] = src[i];
    }
}

// ------------------------------- GEMM ---------------------------------------
// C[M,Ncols] = A[M,K] @ B[K,Ncols], fp32, 64x64 tile, BK=32, 4x4 per thread.

__global__ void __launch_bounds__(256)
gemm_kernel(const float* __restrict__ A, const float* __restrict__ B,
            float* __restrict__ C, int M, int K, int Ncols) {
    __shared__ float As[64][33];
    __shared__ float Bs[32][64];
    const int bm = blockIdx.x * 64;
    const int bn = blockIdx.y * 64;
    const int tid = threadIdx.x;
    const int tx = tid & 15;
    const int ty = tid >> 4;
    float acc[4][4] = {};

    for (int k0 = 0; k0 < K; k0 += 32) {
        // A tile: 64 rows x 32 cols
        {
            int r = tid >> 3;          // 0..31
            int c = (tid & 7) * 4;     // 0..28
#pragma unroll
            for (int pass = 0; pass < 2; ++pass) {
                int row = r + pass * 32;
                int grow = bm + row;
                float4 v = make_float4(0.f, 0.f, 0.f, 0.f);
                if (grow < M) v = *(const float4*)&A[(size_t)grow * K + k0 + c];
                As[row][c + 0] = v.x; As[row][c + 1] = v.y;
                As[row][c + 2] = v.z; As[row][c + 3] = v.w;
            }
        }
        // B tile: 32 rows x 64 cols
        {
            int r = tid >> 4;          // 0..15
            int c = (tid & 15) * 4;    // 0..60
#pragma unroll
            for (int pass = 0; pass < 2; ++pass) {
                int row = r + pass * 16;
                float4 v = *(const float4*)&B[(size_t)(k0 + row) * Ncols + bn + c];
                *(float4*)&Bs[row][c] = v;
            }
        }
        __syncthreads();
#pragma unroll
        for (int kk = 0; kk < 32; ++kk) {
            float a0 = As[ty * 4 + 0][kk];
            float a1 = As[ty * 4 + 1][kk];
            float a2 = As[ty * 4 + 2][kk];
            float a3 = As[ty * 4 + 3][kk];
            float4 b = *(const float4*)&Bs[kk][tx * 4];
            acc[0][0] += a0 * b.x; acc[0][1] += a0 * b.y; acc[0][2] += a0 * b.z; acc[0][3] += a0 * b.w;
            acc[1][0] += a1 * b.x; acc[1][1] += a1 * b.y; acc[1][2] += a1 * b.z; acc[1][3] += a1 * b.w;
            acc[2][0] += a2 * b.x; acc[2][1] += a2 * b.y; acc[2][2] += a2 * b.z; acc[2][3] += a2 * b.w;
            acc[3][0] += a3 * b.x; acc[3][1] += a3 * b.y; acc[3][2] += a3 * b.z; acc[3][3] += a3 * b.w;
        }
        __syncthreads();
    }
#pragma unroll
    for (int i = 0; i < 4; ++i) {
        int grow = bm + ty * 4 + i;
        if (grow < M) {
            float4 v = make_float4(acc[i][0], acc[i][1], acc[i][2], acc[i][3]);
            *(float4*)&C[(size_t)grow * Ncols + bn + tx * 4] = v;
        }
    }
}

// ------------------------------ scores ---------------------------------------
// el[n,h] = feat[n,h,:].al[h,:]   er likewise. One thread per (n,h).

__global__ void scores_kernel(const float* __restrict__ feat, const float* __restrict__ al,
                              const float* __restrict__ ar, float* __restrict__ el,
                              float* __restrict__ er, int n, int C, int D) {
    int idx = blockIdx.x * blockDim.x + threadIdx.x;
    if (idx >= n * 4) return;
    int node = idx >> 2;
    int h = idx & 3;
    const float* f = feat + (size_t)node * C + h * D;
    const float* a = al + h * D;
    const float* b = ar + h * D;
    float sl = 0.f, sr = 0.f;
    for (int d = 0; d < D; ++d) {
        float v = f[d];
        sl += v * a[d];
        sr += v * b[d];
    }
    el[idx] = sl;
    er[idx] = sr;
}

// --------------------------- aggregation -------------------------------------
// One 64-lane wave per dst node. Layers 1/2: C=128, lane handles 2 elements,
// head = lane>>4. Edge softmax (max, exp-sum) + weighted gather of feat[src],
// identity residual + relu.

__device__ __forceinline__ float leaky(float x) {
    return (x > 0.f) ? x : NEG_SLOPE * x;
}

__global__ void __launch_bounds__(256)
aggregate12_kernel(const float* __restrict__ feat, const float* __restrict__ el,
                   const float* __restrict__ er, const int* __restrict__ row_ptr,
                   const int* __restrict__ ssrc, const float* __restrict__ resx,
                   float* __restrict__ xnext, int n) {
    const int wid = threadIdx.x >> 6;
    const int lane = threadIdx.x & 63;
    const int node = blockIdx.x * 4 + wid;
    if (node >= n) return;
    const int beg = row_ptr[node];
    const int end = row_ptr[node + 1];
    const int hh = lane >> 4;
    const float erh = er[node * 4 + hh];

    float m = -3.402823466e38f;
    for (int p = beg; p < end; ++p) {
        int s = ssrc[p];
        float e = leaky(el[s * 4 + hh] + erh);
        m = fmaxf(m, e);
    }
    float ssum = 0.f, a0 = 0.f, a1 = 0.f;
    for (int p = beg; p < end; ++p) {
        int s = ssrc[p];
        float e = leaky(el[s * 4 + hh] + erh);
        float w = expf(e - m);
        ssum += w;
        float2 f = *(const float2*)&feat[(size_t)s * 128 + lane * 2];
        a0 += w * f.x;
        a1 += w * f.y;
    }
    float inv = (end > beg) ? 1.f / ssum : 0.f;
    float r0 = a0 * inv + resx[(size_t)node * 128 + lane * 2 + 0];
    float r1 = a1 * inv + resx[(size_t)node * 128 + lane * 2 + 1];
    r0 = fmaxf(r0, 0.f);
    r1 = fmaxf(r1, 0.f);
    *(float2*)&xnext[(size_t)node * 128 + lane * 2] = make_float2(r0, r1);
}

// Layer 3: C=256 (H=4, D=64). Lane l handles d=l for all 4 heads; fuses the
// projected residual and the mean over heads -> out[n,64].

__global__ void __launch_bounds__(256)
aggregate3_kernel(const float* __restrict__ feat, const float* __restrict__ el,
                  const float* __restrict__ er, const int* __restrict__ row_ptr,
                  const int* __restrict__ ssrc, const float* __restrict__ res3,
                  float* __restrict__ out, int n) {
    const int wid = threadIdx.x >> 6;
    const int lane = threadIdx.x & 63;
    const int node = blockIdx.x * 4 + wid;
    if (node >= n) return;
    const int beg = row_ptr[node];
    const int end = row_ptr[node + 1];
    const float4 er4 = *(const float4*)&er[node * 4];

    float m0 = -3.402823466e38f, m1 = m0, m2 = m0, m3 = m0;
    for (int p = beg; p < end; ++p) {
        int s = ssrc[p];
        float4 ev = *(const float4*)&el[s * 4];
        m0 = fmaxf(m0, leaky(ev.x + er4.x));
        m1 = fmaxf(m1, leaky(ev.y + er4.y));
        m2 = fmaxf(m2, leaky(ev.z + er4.z));
        m3 = fmaxf(m3, leaky(ev.w + er4.w));
    }
    float s0 = 0.f, s1 = 0.f, s2 = 0.f, s3 = 0.f;
    float c0 = 0.f, c1 = 0.f, c2 = 0.f, c3 = 0.f;
    for (int p = beg; p < end; ++p) {
        int s = ssrc[p];
        float4 ev = *(const float4*)&el[s * 4];
        float w0 = expf(leaky(ev.x + er4.x) - m0);
        float w1 = expf(leaky(ev.y + er4.y) - m1);
        float w2 = expf(leaky(ev.z + er4.z) - m2);
        float w3 = expf(leaky(ev.w + er4.w) - m3);
        s0 += w0; s1 += w1; s2 += w2; s3 += w3;
        const float* fb = &feat[(size_t)s * 256];
        c0 += w0 * fb[0 * 64 + lane];
        c1 += w1 * fb[1 * 64 + lane];
        c2 += w2 * fb[2 * 64 + lane];
        c3 += w3 * fb[3 * 64 + lane];
    }
    float i0 = (end > beg) ? 1.f / s0 : 0.f;
    float i1 = (end > beg) ? 1.f / s1 : 0.f;
    float i2 = (end > beg) ? 1.f / s2 : 0.f;
    float i3 = (end > beg) ? 1.f / s3 : 0.f;
    const float* rb = &res3[(size_t)node * 256];
    float r0 = c0 * i0 + rb[0 * 64 + lane];
    float r1 = c1 * i1 + rb[1 * 64 + lane];
    float r2 = c2 * i2 + rb[2 * 64 + lane];
    float r3 = c3 * i3 + rb[3 * 64 + lane];
    out[(size_t)node * 64 + lane] = 0.25f * (r0 + r1 + r2 + r3);
}

// ------------------------------ launch ---------------------------------------

extern "C" void kernel_launch(void* const* d_in, const int* in_sizes, int n_in,
                              void* d_out, int out_size, void* d_ws, size_t ws_size,
                              hipStream_t stream) {
    const float* h   = (const float*)d_in[0];
    const float* W1  = (const float*)d_in[1];
    const float* al1 = (const float*)d_in[2];
    const float* ar1 = (const float*)d_in[3];
    const float* W2  = (const float*)d_in[4];
    const float* al2 = (const float*)d_in[5];
    const float* ar2 = (const float*)d_in[6];
    const float* W3  = (const float*)d_in[7];
    const float* al3 = (const float*)d_in[8];
    const float* ar3 = (const float*)d_in[9];
    const float* rW3 = (const float*)d_in[10];
    const int* src   = (const int*)d_in[11];
    const int* dstv  = (const int*)d_in[12];
    const int N = in_sizes[0] / 128;
    const int E = in_sizes[11];
    float* out = (float*)d_out;

    char* p = (char*)d_ws;
    auto alloc = [&](size_t bytes) -> char* {
        char* q = p;
        p += (bytes + 255) & ~(size_t)255;
        return q;
    };
    int*   row_ptr = (int*)alloc((size_t)(N + 1) * 4);
    int*   cursor  = (int*)alloc((size_t)N * 4);
    int*   ssrc    = (int*)alloc((size_t)E * 4);
    float* el      = (float*)alloc((size_t)N * 4 * 4);
    float* er      = (float*)alloc((size_t)N * 4 * 4);
    float* feat    = (float*)alloc((size_t)N * 256 * 4);
    float* res3    = (float*)alloc((size_t)N * 256 * 4);
    float* x1      = (float*)alloc((size_t)N * 128 * 4);
    float* x2      = (float*)alloc((size_t)N * 128 * 4);

    // CSR build (shared by all 3 layers)
    hipMemsetAsync(cursor, 0, (size_t)N * 4, stream);
    hist_kernel<<<(E + 255) / 256, 256, 0, stream>>>(dstv, cursor, E);
    scan_kernel<<<1, 1024, 0, stream>>>(cursor, row_ptr, N);
    scatter_kernel<<<(E + 255) / 256, 256, 0, stream>>>(src, dstv, cursor, ssrc, E);

    dim3 g1((N + 63) / 64, 2);
    dim3 g3((N + 63) / 64, 4);
    int agg_grid = (N + 3) / 4;
    int sc_grid = (N * 4 + 255) / 256;

    // layer 1
    gemm_kernel<<<g1, 256, 0, stream>>>(h, W1, feat, N, 128, 128);
    scores_kernel<<<sc_grid, 256, 0, stream>>>(feat, al1, ar1, el, er, N, 128, 32);
    aggregate12_kernel<<<agg_grid, 256, 0, stream>>>(feat, el, er, row_ptr, ssrc, h, x1, N);

    // layer 2
    gemm_kernel<<<g1, 256, 0, stream>>>(x1, W2, feat, N, 128, 128);
    scores_kernel<<<sc_grid, 256, 0, stream>>>(feat, al2, ar2, el, er, N, 128, 32);
    aggregate12_kernel<<<agg_grid, 256, 0, stream>>>(feat, el, er, row_ptr, ssrc, x1, x2, N);

    // layer 3
    gemm_kernel<<<g3, 256, 0, stream>>>(x2, W3, feat, N, 128, 256);
    gemm_kernel<<<g3, 256, 0, stream>>>(x2, rW3, res3, N, 128, 256);
    scores_kernel<<<sc_grid, 256, 0, stream>>>(feat, al3, ar3, el, er, N, 256, 64);
    aggregate3_kernel<<<agg_grid, 256, 0, stream>>>(feat, el, er, row_ptr, ssrc, res3, out, N);
}

// Round 2
// 800.031 us; speedup vs baseline: 1.2880x; 1.2880x over previous
//
#include <hip/hip_runtime.h>
#include <hip/hip_bf16.h>
#include <math.h>

// ---------------------------------------------------------------------------
// GAT 3-layer forward. N=50000 nodes, E=800000 edges, H=4 heads.
// Layers 1,2: in 128 -> 4x32 (relu, identity residual)
// Layer 3:    in 128 -> 4x64 (projected residual, mean over heads) -> [N,64]
// Edge softmax: w = exp(leaky(el[src]+er[dst])) precomputed per (edge,head);
// the per-dst max subtraction cancels in alpha = w / sum(w), so it's omitted.
// ---------------------------------------------------------------------------

#define NEG_SLOPE 0.2f

__device__ __forceinline__ float leaky(float x) {
    return fmaxf(x, NEG_SLOPE * x);   // exact for both signs
}

// ------------------------- CSR build (per dst) ------------------------------

__global__ void hist_kernel(const int* __restrict__ dst, int* __restrict__ deg, int E) {
    int i = blockIdx.x * blockDim.x + threadIdx.x;
    if (i < E) atomicAdd(&deg[dst[i]], 1);
}

__global__ void scan_kernel(int* __restrict__ cursor, int* __restrict__ row_ptr, int n) {
    __shared__ int smem[1024];
    const int tid = threadIdx.x;
    int running = 0;
    for (int base = 0; base < n; base += 1024) {
        int i = base + tid;
        int v = (i < n) ? cursor[i] : 0;
        smem[tid] = v;
        __syncthreads();
        for (int off = 1; off < 1024; off <<= 1) {
            int t = (tid >= off) ? smem[tid - off] : 0;
            __syncthreads();
            smem[tid] += t;
            __syncthreads();
        }
        if (i < n) {
            int excl = running + smem[tid] - v;
            row_ptr[i] = excl;
            cursor[i]  = excl;
        }
        running += smem[1023];
        __syncthreads();
    }
    if (tid == 0) row_ptr[n] = running;
}

__global__ void scatter_kernel(const int* __restrict__ src, const int* __restrict__ dst,
                               int* __restrict__ cursor, int* __restrict__ ssrc,
                               int* __restrict__ sdst, int E) {
    int i = blockIdx.x * blockDim.x + threadIdx.x;
    if (i < E) {
        int s = src[i];
        int d = dst[i];
        int pos = atomicAdd(&cursor[d], 1);
        ssrc[pos] = s;
        sdst[pos] = d;
    }
}

// ------------------------------- GEMM ---------------------------------------
// C[M,Ncols] = A[M,K] @ B[K,Ncols], fp32, 64x64 tile, BK=32, 4x4 per thread.
// A tile stored transposed in LDS ([kk][row], stride 76) for b128 reads.

__global__ void __launch_bounds__(256)
gemm_kernel(const float* __restrict__ A, const float* __restrict__ B,
            float* __restrict__ C, int M, int K, int Ncols) {
    __shared__ float As[32][76];   // [kk][row], pad 76 (16B-aligned rows, 4-way wr)
    __shared__ float Bs[32][64];   // [kk][col]
    const int bm = blockIdx.x * 64;
    const int bn = blockIdx.y * 64;
    const int tid = threadIdx.x;
    const int tx = tid & 15;
    const int ty = tid >> 4;
    float acc[4][4] = {};

    for (int k0 = 0; k0 < K; k0 += 32) {
        // A tile: 64 rows x 32 cols -> transposed into As
        {
            int r = tid >> 3;          // 0..31
            int c = (tid & 7) * 4;     // 0,4,...,28
#pragma unroll
            for (int pass = 0; pass < 2; ++pass) {
                int row = r + pass * 32;
                int grow = bm + row;
                float4 v = make_float4(0.f, 0.f, 0.f, 0.f);
                if (grow < M) v = *(const float4*)&A[(size_t)grow * K + k0 + c];
                As[c + 0][row] = v.x; As[c + 1][row] = v.y;
                As[c + 2][row] = v.z; As[c + 3][row] = v.w;
            }
        }
        // B tile: 32 rows x 64 cols
        {
            int r = tid >> 4;          // 0..15
            int c = (tid & 15) * 4;    // 0..60
#pragma unroll
            for (int pass = 0; pass < 2; ++pass) {
                int row = r + pass * 16;
                float4 v = *(const float4*)&B[(size_t)(k0 + row) * Ncols + bn + c];
                *(float4*)&Bs[row][c] = v;
            }
        }
        __syncthreads();
#pragma unroll
        for (int kk = 0; kk < 32; ++kk) {
            float4 a = *(const float4*)&As[kk][ty * 4];
            float4 b = *(const float4*)&Bs[kk][tx * 4];
            acc[0][0] += a.x * b.x; acc[0][1] += a.x * b.y; acc[0][2] += a.x * b.z; acc[0][3] += a.x * b.w;
            acc[1][0] += a.y * b.x; acc[1][1] += a.y * b.y; acc[1][2] += a.y * b.z; acc[1][3] += a.y * b.w;
            acc[2][0] += a.z * b.x; acc[2][1] += a.z * b.y; acc[2][2] += a.z * b.z; acc[2][3] += a.z * b.w;
            acc[3][0] += a.w * b.x; acc[3][1] += a.w * b.y; acc[3][2] += a.w * b.z; acc[3][3] += a.w * b.w;
        }
        __syncthreads();
    }
#pragma unroll
    for (int i = 0; i < 4; ++i) {
        int grow = bm + ty * 4 + i;
        if (grow < M) {
            float4 v = make_float4(acc[i][0], acc[i][1], acc[i][2], acc[i][3]);
            *(float4*)&C[(size_t)grow * Ncols + bn + tx * 4] = v;
        }
    }
}

// ------------------------------ scores ---------------------------------------
// el[n,h] = feat[n,h,:].al[h,:]   er likewise. One thread per (n,h), float4.

__global__ void scores_kernel(const float* __restrict__ feat, const float* __restrict__ al,
                              const float* __restrict__ ar, float* __restrict__ el,
                              float* __restrict__ er, int n, int C, int D) {
    int idx = blockIdx.x * blockDim.x + threadIdx.x;
    if (idx >= n * 4) return;
    int node = idx >> 2;
    int h = idx & 3;
    const float4* f = (const float4*)(feat + (size_t)node * C + h * D);
    const float4* a = (const float4*)(al + h * D);
    const float4* b = (const float4*)(ar + h * D);
    float sl = 0.f, sr = 0.f;
    int q = D >> 2;
    for (int d = 0; d < q; ++d) {
        float4 v = f[d], x = a[d], y = b[d];
        sl += v.x * x.x + v.y * x.y + v.z * x.z + v.w * x.w;
        sr += v.x * y.x + v.y * y.y + v.z * y.z + v.w * y.w;
    }
    el[idx] = sl;
    er[idx] = sr;
}

// ------------------------------ edge weights ---------------------------------
// One thread per (sorted) edge: w[p][h] = exp(leaky(el[src][h] + er[dst][h])).

__global__ void edge_w_kernel(const float* __restrict__ el, const float* __restrict__ er,
                              const int* __restrict__ ssrc, const int* __restrict__ sdst,
                              float* __restrict__ w, int E) {
    int p = blockIdx.x * blockDim.x + threadIdx.x;
    if (p >= E) return;
    int s = ssrc[p];
    int d = sdst[p];
    float4 l = *(const float4*)&el[s * 4];
    float4 r = *(const float4*)&er[d * 4];
    float4 o;
    o.x = __expf(leaky(l.x + r.x));
    o.y = __expf(leaky(l.y + r.y));
    o.z = __expf(leaky(l.z + r.z));
    o.w = __expf(leaky(l.w + r.w));
    *(float4*)&w[(size_t)p * 4] = o;
}

// --------------------------- aggregation -------------------------------------
// One 64-lane wave per dst node; w precomputed, denominator accumulated inline.

__global__ void __launch_bounds__(256)
aggregate12_kernel(const float* __restrict__ feat, const float* __restrict__ w,
                   const int* __restrict__ row_ptr, const int* __restrict__ ssrc,
                   const float* __restrict__ resx, float* __restrict__ xnext, int n) {
    const int wid = threadIdx.x >> 6;
    const int lane = threadIdx.x & 63;
    const int node = blockIdx.x * 4 + wid;
    if (node >= n) return;
    const int beg = row_ptr[node];
    const int end = row_ptr[node + 1];
    const int hh = lane >> 4;           // head for elements 2*lane, 2*lane+1

    float ssum = 0.f, a0 = 0.f, a1 = 0.f;
    for (int p = beg; p < end; ++p) {
        int s = __builtin_amdgcn_readfirstlane(ssrc[p]);
        float wv = w[(size_t)p * 4 + hh];
        ssum += wv;
        float2 f = *(const float2*)&feat[(size_t)s * 128 + lane * 2];
        a0 += wv * f.x;
        a1 += wv * f.y;
    }
    float inv = (end > beg) ? 1.f / ssum : 0.f;
    float r0 = a0 * inv + resx[(size_t)node * 128 + lane * 2 + 0];
    float r1 = a1 * inv + resx[(size_t)node * 128 + lane * 2 + 1];
    r0 = fmaxf(r0, 0.f);
    r1 = fmaxf(r1, 0.f);
    *(float2*)&xnext[(size_t)node * 128 + lane * 2] = make_float2(r0, r1);
}

// Layer 3: C=256 (H=4, D=64); fuses projected residual + mean over heads.

__global__ void __launch_bounds__(256)
aggregate3_kernel(const float* __restrict__ feat, const float* __restrict__ w,
                  const int* __restrict__ row_ptr, const int* __restrict__ ssrc,
                  const float* __restrict__ res3, float* __restrict__ out, int n) {
    const int wid = threadIdx.x >> 6;
    const int lane = threadIdx.x & 63;
    const int node = blockIdx.x * 4 + wid;
    if (node >= n) return;
    const int beg = row_ptr[node];
    const int end = row_ptr[node + 1];

    float s0 = 0.f, s1 = 0.f, s2 = 0.f, s3 = 0.f;
    float c0 = 0.f, c1 = 0.f, c2 = 0.f, c3 = 0.f;
    for (int p = beg; p < end; ++p) {
        int s = __builtin_amdgcn_readfirstlane(ssrc[p]);
        float4 wv = *(const float4*)&w[(size_t)p * 4];
        s0 += wv.x; s1 += wv.y; s2 += wv.z; s3 += wv.w;
        const float* fb = &feat[(size_t)s * 256];
        c0 += wv.x * fb[0 * 64 + lane];
        c1 += wv.y * fb[1 * 64 + lane];
        c2 += wv.z * fb[2 * 64 + lane];
        c3 += wv.w * fb[3 * 64 + lane];
    }
    float i0 = (end > beg) ? 1.f / s0 : 0.f;
    float i1 = (end > beg) ? 1.f / s1 : 0.f;
    float i2 = (end > beg) ? 1.f / s2 : 0.f;
    float i3 = (end > beg) ? 1.f / s3 : 0.f;
    const float* rb = &res3[(size_t)node * 256];
    float r0 = c0 * i0 + rb[0 * 64 + lane];
    float r1 = c1 * i1 + rb[1 * 64 + lane];
    float r2 = c2 * i2 + rb[2 * 64 + lane];
    float r3 = c3 * i3 + rb[3 * 64 + lane];
    out[(size_t)node * 64 + lane] = 0.25f * (r0 + r1 + r2 + r3);
}

// ------------------------------ launch ---------------------------------------

extern "C" void kernel_launch(void* const* d_in, const int* in_sizes, int n_in,
                              void* d_out, int out_size, void* d_ws, size_t ws_size,
                              hipStream_t stream) {
    const float* h   = (const float*)d_in[0];
    const float* W1  = (const float*)d_in[1];
    const float* al1 = (const float*)d_in[2];
    const float* ar1 = (const float*)d_in[3];
    const float* W2  = (const float*)d_in[4];
    const float* al2 = (const float*)d_in[5];
    const float* ar2 = (const float*)d_in[6];
    const float* W3  = (const float*)d_in[7];
    const float* al3 = (const float*)d_in[8];
    const float* ar3 = (const float*)d_in[9];
    const float* rW3 = (const float*)d_in[10];
    const int* src   = (const int*)d_in[11];
    const int* dstv  = (const int*)d_in[12];
    const int N = in_sizes[0] / 128;
    const int E = in_sizes[11];
    float* out = (float*)d_out;

    char* p = (char*)d_ws;
    auto alloc = [&](size_t bytes) -> char* {
        char* q = p;
        p += (bytes + 255) & ~(size_t)255;
        return q;
    };
    int*   row_ptr = (int*)alloc((size_t)(N + 1) * 4);
    int*   cursor  = (int*)alloc((size_t)N * 4);
    int*   ssrc    = (int*)alloc((size_t)E * 4);
    int*   sdst    = (int*)alloc((size_t)E * 4);
    float* w       = (float*)alloc((size_t)E * 4 * 4);
    float* el      = (float*)alloc((size_t)N * 4 * 4);
    float* er      = (float*)alloc((size_t)N * 4 * 4);
    float* feat    = (float*)alloc((size_t)N * 256 * 4);
    float* res3    = (float*)alloc((size_t)N * 256 * 4);
    float* x1      = (float*)alloc((size_t)N * 128 * 4);
    float* x2      = (float*)alloc((size_t)N * 128 * 4);

    // CSR build (shared by all 3 layers)
    hipMemsetAsync(cursor, 0, (size_t)N * 4, stream);
    hist_kernel<<<(E + 255) / 256, 256, 0, stream>>>(dstv, cursor, E);
    scan_kernel<<<1, 1024, 0, stream>>>(cursor, row_ptr, N);
    scatter_kernel<<<(E + 255) / 256, 256, 0, stream>>>(src, dstv, cursor, ssrc, sdst, E);

    dim3 g1((N + 63) / 64, 2);
    dim3 g3((N + 63) / 64, 4);
    int agg_grid = (N + 3) / 4;
    int sc_grid = (N * 4 + 255) / 256;
    int ew_grid = (E + 255) / 256;

    // layer 1
    gemm_kernel<<<g1, 256, 0, stream>>>(h, W1, feat, N, 128, 128);
    scores_kernel<<<sc_grid, 256, 0, stream>>>(feat, al1, ar1, el, er, N, 128, 32);
    edge_w_kernel<<<ew_grid, 256, 0, stream>>>(el, er, ssrc, sdst, w, E);
    aggregate12_kernel<<<agg_grid, 256, 0, stream>>>(feat, w, row_ptr, ssrc, h, x1, N);

    // layer 2
    gemm_kernel<<<g1, 256, 0, stream>>>(x1, W2, feat, N, 128, 128);
    scores_kernel<<<sc_grid, 256, 0, stream>>>(feat, al2, ar2, el, er, N, 128, 32);
    edge_w_kernel<<<ew_grid, 256, 0, stream>>>(el, er, ssrc, sdst, w, E);
    aggregate12_kernel<<<agg_grid, 256, 0, stream>>>(feat, w, row_ptr, ssrc, x1, x2, N);

    // layer 3
    gemm_kernel<<<g3, 256, 0, stream>>>(x2, W3, feat, N, 128, 256);
    gemm_kernel<<<g3, 256, 0, stream>>>(x2, rW3, res3, N, 128, 256);
    scores_kernel<<<sc_grid, 256, 0, stream>>>(feat, al3, ar3, el, er, N, 256, 64);
    edge_w_kernel<<<ew_grid, 256, 0, stream>>>(el, er, ssrc, sdst, w, E);
    aggregate3_kernel<<<agg_grid, 256, 0, stream>>>(feat, w, row_ptr, ssrc, res3, out, N);
}

// Round 3
// 758.295 us; speedup vs baseline: 1.3589x; 1.0550x over previous
//
#include <hip/hip_runtime.h>
#include <hip/hip_bf16.h>
#include <math.h>

// ---------------------------------------------------------------------------
// GAT 3-layer forward. N=50000 nodes, E=800000 edges, H=4 heads.
// GEMMs: split-bf16 MFMA (hi/lo planes, 3 mfma -> ~fp32 accuracy), el/er
// fused into the GEMM epilogue, bf16 feature copy emitted for gathers.
// Aggregation: one wave per dst node, bf16 gathers, fp32 accumulate.
// ---------------------------------------------------------------------------

#define NEG_SLOPE 0.2f

typedef __attribute__((ext_vector_type(8))) __bf16 bf16x8;
typedef __attribute__((ext_vector_type(4))) float f32x4;

__device__ __forceinline__ float leaky(float x) {
    return fmaxf(x, NEG_SLOPE * x);
}
__device__ __forceinline__ ushort f2bf(float f) {      // RNE float->bf16 bits
    unsigned u = __float_as_uint(f);
    return (ushort)((u + 0x7fffu + ((u >> 16) & 1u)) >> 16);
}
__device__ __forceinline__ float bf2f(ushort b) {
    return __uint_as_float(((unsigned)b) << 16);
}

// ------------------------- CSR build (per dst) ------------------------------

__global__ void hist_kernel(const int* __restrict__ dst, int* __restrict__ deg, int E) {
    int i = blockIdx.x * blockDim.x + threadIdx.x;
    if (i < E) atomicAdd(&deg[dst[i]], 1);
}

__global__ void scan_kernel(int* __restrict__ cursor, int* __restrict__ row_ptr, int n) {
    __shared__ int smem[1024];
    const int tid = threadIdx.x;
    int running = 0;
    for (int base = 0; base < n; base += 1024) {
        int i = base + tid;
        int v = (i < n) ? cursor[i] : 0;
        smem[tid] = v;
        __syncthreads();
        for (int off = 1; off < 1024; off <<= 1) {
            int t = (tid >= off) ? smem[tid - off] : 0;
            __syncthreads();
            smem[tid] += t;
            __syncthreads();
        }
        if (i < n) {
            int excl = running + smem[tid] - v;
            row_ptr[i] = excl;
            cursor[i]  = excl;
        }
        running += smem[1023];
        __syncthreads();
    }
    if (tid == 0) row_ptr[n] = running;
}

__global__ void scatter_kernel(const int* __restrict__ src, const int* __restrict__ dst,
                               int* __restrict__ cursor, int* __restrict__ ssrc,
                               int* __restrict__ sdst, int E) {
    int i = blockIdx.x * blockDim.x + threadIdx.x;
    if (i < E) {
        int s = src[i];
        int d = dst[i];
        int pos = atomicAdd(&cursor[d], 1);
        ssrc[pos] = s;
        sdst[pos] = d;
    }
}

// ----------------------------- casts ----------------------------------------

__global__ void cast_split_kernel(const float* __restrict__ in, ushort* __restrict__ hi,
                                  ushort* __restrict__ lo, int n4) {
    int i = blockIdx.x * blockDim.x + threadIdx.x;
    if (i >= n4) return;
    float4 v = ((const float4*)in)[i];
    ushort4 h, l;
    h.x = f2bf(v.x); l.x = f2bf(v.x - bf2f(h.x));
    h.y = f2bf(v.y); l.y = f2bf(v.y - bf2f(h.y));
    h.z = f2bf(v.z); l.z = f2bf(v.z - bf2f(h.z));
    h.w = f2bf(v.w); l.w = f2bf(v.w - bf2f(h.w));
    ((ushort4*)hi)[i] = h;
    ((ushort4*)lo)[i] = l;
}

// W [128][Ncols] fp32 -> Wt hi/lo [Ncols][128] bf16
__global__ void castT_split_kernel(const float* __restrict__ in, ushort* __restrict__ hi,
                                   ushort* __restrict__ lo, int Ncols) {
    int i = blockIdx.x * blockDim.x + threadIdx.x;
    if (i >= 128 * Ncols) return;
    int c = i >> 7, k = i & 127;
    float v = in[k * Ncols + c];
    ushort h = f2bf(v);
    hi[i] = h;
    lo[i] = f2bf(v - bf2f(h));
}

// ------------------------------- GEMM ---------------------------------------
// C[M,Ncols] = X[M,128] @ W[128,Ncols]; X,W given as bf16 hi/lo planes
// (Wt transposed). Block = 4 waves, tile 64(M) x 64(N), K=128 in registers.
// D = Wt_frag x Xt_frag -> lane owns row m=bm+(lane&15), cols n*16+g*4+{0..3}.
// Epilogue: optional fp32 C, optional bf16 C, optional fused el/er scores.

__global__ void __launch_bounds__(256)
gemm_kernel(const ushort* __restrict__ Ah, const ushort* __restrict__ Al,
            const ushort* __restrict__ Bth, const ushort* __restrict__ Btl,
            float* __restrict__ Cf, ushort* __restrict__ Cb,
            const float* __restrict__ alv, const float* __restrict__ arv,
            float* __restrict__ el, float* __restrict__ er,
            int M, int Ncols, int dshift) {
    const int wv = threadIdx.x >> 6;
    const int lane = threadIdx.x & 63;
    const int l15 = lane & 15;
    const int g = lane >> 4;
    const int bm = blockIdx.x * 64 + wv * 16;
    const int bn = blockIdx.y * 64;
    const int m = bm + l15;
    const int mc = (m < M) ? m : (M - 1);

    const ushort* xh = Ah + (size_t)mc * 128 + g * 8;
    const ushort* xl = Al + (size_t)mc * 128 + g * 8;
    bf16x8 xhf[4], xlf[4];
#pragma unroll
    for (int kk = 0; kk < 4; ++kk) {
        xhf[kk] = *(const bf16x8*)(xh + kk * 32);
        xlf[kk] = *(const bf16x8*)(xl + kk * 32);
    }
    f32x4 acc[4] = {};
#pragma unroll
    for (int n = 0; n < 4; ++n) {
        const ushort* wh = Bth + (size_t)(bn + n * 16 + l15) * 128 + g * 8;
        const ushort* wl = Btl + (size_t)(bn + n * 16 + l15) * 128 + g * 8;
#pragma unroll
        for (int kk = 0; kk < 4; ++kk) {
            bf16x8 whf = *(const bf16x8*)(wh + kk * 32);
            bf16x8 wlf = *(const bf16x8*)(wl + kk * 32);
            acc[n] = __builtin_amdgcn_mfma_f32_16x16x32_bf16(whf, xhf[kk], acc[n], 0, 0, 0);
            acc[n] = __builtin_amdgcn_mfma_f32_16x16x32_bf16(whf, xlf[kk], acc[n], 0, 0, 0);
            acc[n] = __builtin_amdgcn_mfma_f32_16x16x32_bf16(wlf, xhf[kk], acc[n], 0, 0, 0);
        }
    }
    const bool valid = (m < M);
    if (valid) {
        size_t ro = (size_t)m * Ncols;
#pragma unroll
        for (int n = 0; n < 4; ++n) {
            int col = bn + n * 16 + g * 4;
            if (Cf) {
                *(float4*)&Cf[ro + col] =
                    make_float4(acc[n][0], acc[n][1], acc[n][2], acc[n][3]);
            }
            if (Cb) {
                ushort4 o;
                o.x = f2bf(acc[n][0]); o.y = f2bf(acc[n][1]);
                o.z = f2bf(acc[n][2]); o.w = f2bf(acc[n][3]);
                *(ushort4*)&Cb[ro + col] = o;
            }
        }
    }
    if (alv) {
        float e0 = 0.f, e1 = 0.f, r0 = 0.f, r1 = 0.f;
#pragma unroll
        for (int n = 0; n < 4; ++n) {
#pragma unroll
            for (int r = 0; r < 4; ++r) {
                int col = n * 16 + g * 4 + r;
                float c = acc[n][r];
                float av = alv[bn + col];
                float bv = arv[bn + col];
                if ((col >> dshift) == 0) { e0 += c * av; r0 += c * bv; }
                else                      { e1 += c * av; r1 += c * bv; }
            }
        }
        e0 += __shfl_xor(e0, 16); e0 += __shfl_xor(e0, 32);
        e1 += __shfl_xor(e1, 16); e1 += __shfl_xor(e1, 32);
        r0 += __shfl_xor(r0, 16); r0 += __shfl_xor(r0, 32);
        r1 += __shfl_xor(r1, 16); r1 += __shfl_xor(r1, 32);
        if (valid && g == 0) {
            int h0 = bn >> dshift;
            el[m * 4 + h0] = e0;
            er[m * 4 + h0] = r0;
            if (dshift == 5) {
                el[m * 4 + h0 + 1] = e1;
                er[m * 4 + h0 + 1] = r1;
            }
        }
    }
}

// ------------------------------ edge weights ---------------------------------

__global__ void edge_w_kernel(const float* __restrict__ el, const float* __restrict__ er,
                              const int* __restrict__ ssrc, const int* __restrict__ sdst,
                              float* __restrict__ w, int E) {
    int p = blockIdx.x * blockDim.x + threadIdx.x;
    if (p >= E) return;
    int s = ssrc[p];
    int d = sdst[p];
    float4 l = *(const float4*)&el[s * 4];
    float4 r = *(const float4*)&er[d * 4];
    float4 o;
    o.x = __expf(leaky(l.x + r.x));
    o.y = __expf(leaky(l.y + r.y));
    o.z = __expf(leaky(l.z + r.z));
    o.w = __expf(leaky(l.w + r.w));
    *(float4*)&w[(size_t)p * 4] = o;
}

// --------------------------- aggregation -------------------------------------
// Layers 1/2: C=128, lane handles 2 elems (bf16x2 load), head = lane>>4.
// Writes fp32 xnext (optional) + bf16 hi/lo planes for the next GEMM.

__global__ void __launch_bounds__(256)
aggregate12_kernel(const ushort* __restrict__ featb, const float* __restrict__ w,
                   const int* __restrict__ row_ptr, const int* __restrict__ ssrc,
                   const float* __restrict__ resx, float* __restrict__ xnext,
                   ushort* __restrict__ xbh, ushort* __restrict__ xbl, int n) {
    const int wid = threadIdx.x >> 6;
    const int lane = threadIdx.x & 63;
    const int node = blockIdx.x * 4 + wid;
    if (node >= n) return;
    const int beg = row_ptr[node];
    const int end = row_ptr[node + 1];
    const int hh = lane >> 4;

    float ssum = 0.f, a0 = 0.f, a1 = 0.f;
    for (int p = beg; p < end; ++p) {
        int s = __builtin_amdgcn_readfirstlane(ssrc[p]);
        float wv = w[(size_t)p * 4 + hh];
        unsigned v = *(const unsigned*)&featb[(size_t)s * 128 + lane * 2];
        a0 += wv * __uint_as_float(v << 16);
        a1 += wv * __uint_as_float(v & 0xffff0000u);
        ssum += wv;
    }
    float inv = (end > beg) ? 1.f / ssum : 0.f;
    float r0 = fmaxf(a0 * inv + resx[(size_t)node * 128 + lane * 2 + 0], 0.f);
    float r1 = fmaxf(a1 * inv + resx[(size_t)node * 128 + lane * 2 + 1], 0.f);
    if (xnext) *(float2*)&xnext[(size_t)node * 128 + lane * 2] = make_float2(r0, r1);
    ushort h0 = f2bf(r0), h1 = f2bf(r1);
    ushort l0 = f2bf(r0 - bf2f(h0)), l1 = f2bf(r1 - bf2f(h1));
    *(unsigned*)&xbh[(size_t)node * 128 + lane * 2] = (unsigned)h0 | ((unsigned)h1 << 16);
    *(unsigned*)&xbl[(size_t)node * 128 + lane * 2] = (unsigned)l0 | ((unsigned)l1 << 16);
}

// Layer 3: C=256 (H=4, D=64). lane: head hh=lane>>4, dims dd=(lane&15)*4.
// bf16x4 (8B) gathers; head-mean via shfl_xor; fused projected residual.

__global__ void __launch_bounds__(256)
aggregate3_kernel(const ushort* __restrict__ featb, const float* __restrict__ w,
                  const int* __restrict__ row_ptr, const int* __restrict__ ssrc,
                  const float* __restrict__ res3, float* __restrict__ out, int n) {
    const int wid = threadIdx.x >> 6;
    const int lane = threadIdx.x & 63;
    const int node = blockIdx.x * 4 + wid;
    if (node >= n) return;
    const int beg = row_ptr[node];
    const int end = row_ptr[node + 1];
    const int hh = lane >> 4;
    const int dd = (lane & 15) * 4;
    const int off = hh * 64 + dd;

    float c0 = 0.f, c1 = 0.f, c2 = 0.f, c3 = 0.f, ssum = 0.f;
    for (int p = beg; p < end; ++p) {
        int s = __builtin_amdgcn_readfirstlane(ssrc[p]);
        float wv = w[(size_t)p * 4 + hh];
        uint2 v = *(const uint2*)&featb[(size_t)s * 256 + off];
        c0 += wv * __uint_as_float(v.x << 16);
        c1 += wv * __uint_as_float(v.x & 0xffff0000u);
        c2 += wv * __uint_as_float(v.y << 16);
        c3 += wv * __uint_as_float(v.y & 0xffff0000u);
        ssum += wv;
    }
    float inv = (end > beg) ? 1.f / ssum : 0.f;
    float4 rb = *(const float4*)&res3[(size_t)node * 256 + off];
    float r0 = c0 * inv + rb.x;
    float r1 = c1 * inv + rb.y;
    float r2 = c2 * inv + rb.z;
    float r3 = c3 * inv + rb.w;
    r0 += __shfl_xor(r0, 16); r0 += __shfl_xor(r0, 32);
    r1 += __shfl_xor(r1, 16); r1 += __shfl_xor(r1, 32);
    r2 += __shfl_xor(r2, 16); r2 += __shfl_xor(r2, 32);
    r3 += __shfl_xor(r3, 16); r3 += __shfl_xor(r3, 32);
    if (hh == 0) {
        *(float4*)&out[(size_t)node * 64 + dd] =
            make_float4(0.25f * r0, 0.25f * r1, 0.25f * r2, 0.25f * r3);
    }
}

// ------------------------------ launch ---------------------------------------

extern "C" void kernel_launch(void* const* d_in, const int* in_sizes, int n_in,
                              void* d_out, int out_size, void* d_ws, size_t ws_size,
                              hipStream_t stream) {
    const float* h   = (const float*)d_in[0];
    const float* W1  = (const float*)d_in[1];
    const float* al1 = (const float*)d_in[2];
    const float* ar1 = (const float*)d_in[3];
    const float* W2  = (const float*)d_in[4];
    const float* al2 = (const float*)d_in[5];
    const float* ar2 = (const float*)d_in[6];
    const float* W3  = (const float*)d_in[7];
    const float* al3 = (const float*)d_in[8];
    const float* ar3 = (const float*)d_in[9];
    const float* rW3 = (const float*)d_in[10];
    const int* src   = (const int*)d_in[11];
    const int* dstv  = (const int*)d_in[12];
    const int N = in_sizes[0] / 128;
    const int E = in_sizes[11];
    float* out = (float*)d_out;

    char* p = (char*)d_ws;
    auto alloc = [&](size_t bytes) -> char* {
        char* q = p;
        p += (bytes + 255) & ~(size_t)255;
        return q;
    };
    int*    row_ptr = (int*)alloc((size_t)(N + 1) * 4);
    int*    cursor  = (int*)alloc((size_t)N * 4);
    int*    ssrc    = (int*)alloc((size_t)E * 4);
    int*    sdst    = (int*)alloc((size_t)E * 4);
    float*  w       = (float*)alloc((size_t)E * 16);
    float*  el      = (float*)alloc((size_t)N * 16);
    float*  er      = (float*)alloc((size_t)N * 16);
    ushort* featb   = (ushort*)alloc((size_t)N * 256 * 2);
    ushort* xbh     = (ushort*)alloc((size_t)N * 128 * 2);
    ushort* xbl     = (ushort*)alloc((size_t)N * 128 * 2);
    ushort* W1th = (ushort*)alloc(128 * 128 * 2), *W1tl = (ushort*)alloc(128 * 128 * 2);
    ushort* W2th = (ushort*)alloc(128 * 128 * 2), *W2tl = (ushort*)alloc(128 * 128 * 2);
    ushort* W3th = (ushort*)alloc(256 * 128 * 2), *W3tl = (ushort*)alloc(256 * 128 * 2);
    ushort* rW3th = (ushort*)alloc(256 * 128 * 2), *rW3tl = (ushort*)alloc(256 * 128 * 2);
    // time-disjoint union: x1 (layers 1-2 residual) / res3 (layer 3)
    float*  xres = (float*)alloc((size_t)N * 256 * 4);
    float*  x1   = xres;
    float*  res3 = xres;

    // CSR build
    hipMemsetAsync(cursor, 0, (size_t)N * 4, stream);
    hist_kernel<<<(E + 255) / 256, 256, 0, stream>>>(dstv, cursor, E);
    scan_kernel<<<1, 1024, 0, stream>>>(cursor, row_ptr, N);
    scatter_kernel<<<(E + 255) / 256, 256, 0, stream>>>(src, dstv, cursor, ssrc, sdst, E);

    // casts
    cast_split_kernel<<<(N * 128 / 4 + 255) / 256, 256, 0, stream>>>(h, xbh, xbl, N * 128 / 4);
    castT_split_kernel<<<(128 * 128 + 255) / 256, 256, 0, stream>>>(W1, W1th, W1tl, 128);
    castT_split_kernel<<<(128 * 128 + 255) / 256, 256, 0, stream>>>(W2, W2th, W2tl, 128);
    castT_split_kernel<<<(128 * 256 + 255) / 256, 256, 0, stream>>>(W3, W3th, W3tl, 256);
    castT_split_kernel<<<(128 * 256 + 255) / 256, 256, 0, stream>>>(rW3, rW3th, rW3tl, 256);

    dim3 g1((N + 63) / 64, 2);
    dim3 g3((N + 63) / 64, 4);
    int agg_grid = (N + 3) / 4;
    int ew_grid = (E + 255) / 256;

    // layer 1
    gemm_kernel<<<g1, 256, 0, stream>>>(xbh, xbl, W1th, W1tl, nullptr, featb,
                                        al1, ar1, el, er, N, 128, 5);
    edge_w_kernel<<<ew_grid, 256, 0, stream>>>(el, er, ssrc, sdst, w, E);
    aggregate12_kernel<<<agg_grid, 256, 0, stream>>>(featb, w, row_ptr, ssrc, h, x1, xbh, xbl, N);

    // layer 2
    gemm_kernel<<<g1, 256, 0, stream>>>(xbh, xbl, W2th, W2tl, nullptr, featb,
                                        al2, ar2, el, er, N, 128, 5);
    edge_w_kernel<<<ew_grid, 256, 0, stream>>>(el, er, ssrc, sdst, w, E);
    aggregate12_kernel<<<agg_grid, 256, 0, stream>>>(featb, w, row_ptr, ssrc, x1, nullptr, xbh, xbl, N);

    // layer 3
    gemm_kernel<<<g3, 256, 0, stream>>>(xbh, xbl, W3th, W3tl, nullptr, featb,
                                        al3, ar3, el, er, N, 256, 6);
    gemm_kernel<<<g3, 256, 0, stream>>>(xbh, xbl, rW3th, rW3tl, res3, nullptr,
                                        nullptr, nullptr, nullptr, nullptr, N, 256, 6);
    edge_w_kernel<<<ew_grid, 256, 0, stream>>>(el, er, ssrc, sdst, w, E);
    aggregate3_kernel<<<agg_grid, 256, 0, stream>>>(featb, w, row_ptr, ssrc, res3, out, N);
}

// Round 4
// 546.953 us; speedup vs baseline: 1.8840x; 1.3864x over previous
//
#include <hip/hip_runtime.h>
#include <hip/hip_bf16.h>
#include <math.h>

// ---------------------------------------------------------------------------
// GAT 3-layer forward. N=50000 nodes, E=800000 edges, H=4 heads.
// GEMMs: split-bf16 MFMA (hi/lo planes, 3 mfma -> ~fp32), el/er fused into
// the epilogue; layer-3 computes W3 and resW3 in one kernel (shared X frags).
// Aggregation: one wave per dst node, exp(leaky()) computed inline (softmax
// max-subtraction cancels in alpha), 4x-unrolled gathers for latency hiding.
// ---------------------------------------------------------------------------

#define NEG_SLOPE 0.2f

typedef __attribute__((ext_vector_type(8))) __bf16 bf16x8;
typedef __attribute__((ext_vector_type(4))) float f32x4;

__device__ __forceinline__ float leaky(float x) { return fmaxf(x, NEG_SLOPE * x); }
__device__ __forceinline__ ushort f2bf(float f) {
    unsigned u = __float_as_uint(f);
    return (ushort)((u + 0x7fffu + ((u >> 16) & 1u)) >> 16);
}
__device__ __forceinline__ float bf2f(ushort b) { return __uint_as_float(((unsigned)b) << 16); }
__device__ __forceinline__ float lo16f(unsigned v) { return __uint_as_float(v << 16); }
__device__ __forceinline__ float hi16f(unsigned v) { return __uint_as_float(v & 0xffff0000u); }

// ------------------------- CSR build (per dst) ------------------------------

__global__ void hist_kernel(const int* __restrict__ dst, int* __restrict__ deg, int E) {
    int i = blockIdx.x * blockDim.x + threadIdx.x;
    if (i < E) atomicAdd(&deg[dst[i]], 1);
}

// per-1024-chunk local exclusive scan (parallel across blocks)
__global__ void block_scan_kernel(const int* __restrict__ deg, int* __restrict__ loc,
                                  int* __restrict__ bsum, int n) {
    __shared__ int sm[1024];
    const int tid = threadIdx.x;
    const int i = blockIdx.x * 1024 + tid;
    int v = (i < n) ? deg[i] : 0;
    sm[tid] = v;
    __syncthreads();
    for (int off = 1; off < 1024; off <<= 1) {
        int t = (tid >= off) ? sm[tid - off] : 0;
        __syncthreads();
        sm[tid] += t;
        __syncthreads();
    }
    if (i < n) loc[i] = sm[tid] - v;
    if (tid == 1023) bsum[blockIdx.x] = sm[1023];
}

// wave-scan of <=64 block sums; writes exclusive sums + grand total
__global__ void scan_bsum_kernel(int* __restrict__ bsum, int nb, int* __restrict__ total_out) {
    const int lane = threadIdx.x;
    int v = (lane < nb) ? bsum[lane] : 0;
    int orig = v;
    for (int off = 1; off < 64; off <<= 1) {
        int t = __shfl_up(v, off);
        if (lane >= off) v += t;
    }
    if (lane < nb) bsum[lane] = v - orig;
    if (lane == 63) *total_out = v;
}

__global__ void apply_scan_kernel(const int* __restrict__ loc, const int* __restrict__ bsum,
                                  int* __restrict__ row_ptr, int* __restrict__ cursor, int n) {
    int i = blockIdx.x * blockDim.x + threadIdx.x;
    if (i < n) {
        int v = loc[i] + bsum[i >> 10];
        row_ptr[i] = v;
        cursor[i]  = v;
    }
}

__global__ void scatter_kernel(const int* __restrict__ src, const int* __restrict__ dst,
                               int* __restrict__ cursor, int* __restrict__ ssrc, int E) {
    int i = blockIdx.x * blockDim.x + threadIdx.x;
    if (i < E) {
        int s = src[i];
        int pos = atomicAdd(&cursor[dst[i]], 1);
        ssrc[pos] = s;
    }
}

// ----------------------------- casts ----------------------------------------

__global__ void cast_split_kernel(const float* __restrict__ in, ushort* __restrict__ hi,
                                  ushort* __restrict__ lo, int n4) {
    int i = blockIdx.x * blockDim.x + threadIdx.x;
    if (i >= n4) return;
    float4 v = ((const float4*)in)[i];
    ushort4 h, l;
    h.x = f2bf(v.x); l.x = f2bf(v.x - bf2f(h.x));
    h.y = f2bf(v.y); l.y = f2bf(v.y - bf2f(h.y));
    h.z = f2bf(v.z); l.z = f2bf(v.z - bf2f(h.z));
    h.w = f2bf(v.w); l.w = f2bf(v.w - bf2f(h.w));
    ((ushort4*)hi)[i] = h;
    ((ushort4*)lo)[i] = l;
}

// W [128][Ncols] fp32 -> Wt hi/lo [Ncols][128] bf16
__global__ void castT_split_kernel(const float* __restrict__ in, ushort* __restrict__ hi,
                                   ushort* __restrict__ lo, int Ncols) {
    int i = blockIdx.x * blockDim.x + threadIdx.x;
    if (i >= 128 * Ncols) return;
    int c = i >> 7, k = i & 127;
    float v = in[k * Ncols + c];
    ushort h = f2bf(v);
    hi[i] = h;
    lo[i] = f2bf(v - bf2f(h));
}

// ------------------------------- GEMM ---------------------------------------
// C[M,Ncols] = X[M,128] @ W; X,W as bf16 hi/lo planes (W transposed).
// Block = 4 waves; wave tile 16(M) x 64(N); K=128 in registers.
// Optional second weight B2 -> fp32 C2 (layer-3 residual projection),
// sharing the X fragments. Optional fused el/er score epilogue.

__global__ void __launch_bounds__(256)
gemm_kernel(const ushort* __restrict__ Ah, const ushort* __restrict__ Al,
            const ushort* __restrict__ Bth, const ushort* __restrict__ Btl,
            const ushort* __restrict__ B2th, const ushort* __restrict__ B2tl,
            ushort* __restrict__ Cb, float* __restrict__ C2f,
            const float* __restrict__ alv, const float* __restrict__ arv,
            float* __restrict__ el, float* __restrict__ er,
            int M, int Ncols, int dshift) {
    const int wv = threadIdx.x >> 6;
    const int lane = threadIdx.x & 63;
    const int l15 = lane & 15;
    const int g = lane >> 4;
    const int bm = blockIdx.x * 64 + wv * 16;
    const int bn = blockIdx.y * 64;
    const int m = bm + l15;
    const int mc = (m < M) ? m : (M - 1);

    const ushort* xh = Ah + (size_t)mc * 128 + g * 8;
    const ushort* xl = Al + (size_t)mc * 128 + g * 8;
    bf16x8 xhf[4], xlf[4];
#pragma unroll
    for (int kk = 0; kk < 4; ++kk) {
        xhf[kk] = *(const bf16x8*)(xh + kk * 32);
        xlf[kk] = *(const bf16x8*)(xl + kk * 32);
    }
    f32x4 acc[4] = {};
    f32x4 acc2[4] = {};
#pragma unroll
    for (int n = 0; n < 4; ++n) {
        const size_t wo = (size_t)(bn + n * 16 + l15) * 128 + g * 8;
#pragma unroll
        for (int kk = 0; kk < 4; ++kk) {
            bf16x8 whf = *(const bf16x8*)(Bth + wo + kk * 32);
            bf16x8 wlf = *(const bf16x8*)(Btl + wo + kk * 32);
            acc[n] = __builtin_amdgcn_mfma_f32_16x16x32_bf16(whf, xhf[kk], acc[n], 0, 0, 0);
            acc[n] = __builtin_amdgcn_mfma_f32_16x16x32_bf16(whf, xlf[kk], acc[n], 0, 0, 0);
            acc[n] = __builtin_amdgcn_mfma_f32_16x16x32_bf16(wlf, xhf[kk], acc[n], 0, 0, 0);
        }
        if (B2th) {
#pragma unroll
            for (int kk = 0; kk < 4; ++kk) {
                bf16x8 whf = *(const bf16x8*)(B2th + wo + kk * 32);
                bf16x8 wlf = *(const bf16x8*)(B2tl + wo + kk * 32);
                acc2[n] = __builtin_amdgcn_mfma_f32_16x16x32_bf16(whf, xhf[kk], acc2[n], 0, 0, 0);
                acc2[n] = __builtin_amdgcn_mfma_f32_16x16x32_bf16(whf, xlf[kk], acc2[n], 0, 0, 0);
                acc2[n] = __builtin_amdgcn_mfma_f32_16x16x32_bf16(wlf, xhf[kk], acc2[n], 0, 0, 0);
            }
        }
    }
    const bool valid = (m < M);
    if (valid) {
        size_t ro = (size_t)m * Ncols;
#pragma unroll
        for (int n = 0; n < 4; ++n) {
            int col = bn + n * 16 + g * 4;
            ushort4 o;
            o.x = f2bf(acc[n][0]); o.y = f2bf(acc[n][1]);
            o.z = f2bf(acc[n][2]); o.w = f2bf(acc[n][3]);
            *(ushort4*)&Cb[ro + col] = o;
            if (C2f) {
                *(float4*)&C2f[ro + col] =
                    make_float4(acc2[n][0], acc2[n][1], acc2[n][2], acc2[n][3]);
            }
        }
    }
    if (alv) {
        float e0 = 0.f, e1 = 0.f, r0 = 0.f, r1 = 0.f;
#pragma unroll
        for (int n = 0; n < 4; ++n) {
#pragma unroll
            for (int r = 0; r < 4; ++r) {
                int col = n * 16 + g * 4 + r;
                float c = acc[n][r];
                float av = alv[bn + col];
                float bv = arv[bn + col];
                if ((col >> dshift) == 0) { e0 += c * av; r0 += c * bv; }
                else                      { e1 += c * av; r1 += c * bv; }
            }
        }
        e0 += __shfl_xor(e0, 16); e0 += __shfl_xor(e0, 32);
        e1 += __shfl_xor(e1, 16); e1 += __shfl_xor(e1, 32);
        r0 += __shfl_xor(r0, 16); r0 += __shfl_xor(r0, 32);
        r1 += __shfl_xor(r1, 16); r1 += __shfl_xor(r1, 32);
        if (valid && g == 0) {
            int h0 = bn >> dshift;
            el[m * 4 + h0] = e0;
            er[m * 4 + h0] = r0;
            if (dshift == 5) {
                el[m * 4 + h0 + 1] = e1;
                er[m * 4 + h0 + 1] = r1;
            }
        }
    }
}

// --------------------------- aggregation -------------------------------------
// Layers 1/2: C=128, lane owns 2 elems, head hh=lane>>4. Edge weights
// computed inline; 4x unrolled gathers. Residual read from xbh/xbl (in/out).

__global__ void __launch_bounds__(256)
aggregate12_kernel(const ushort* __restrict__ featb, const float* __restrict__ el,
                   const float* __restrict__ er, const int* __restrict__ row_ptr,
                   const int* __restrict__ ssrc, ushort* __restrict__ xbh,
                   ushort* __restrict__ xbl, int n) {
    const int wid = threadIdx.x >> 6;
    const int lane = threadIdx.x & 63;
    const int node = blockIdx.x * 4 + wid;
    if (node >= n) return;
    const int beg = row_ptr[node];
    const int end = row_ptr[node + 1];
    const int hh = lane >> 4;
    const float erh = er[node * 4 + hh];

    float ssum = 0.f, a0 = 0.f, a1 = 0.f;
    int p = beg;
    for (; p + 4 <= end; p += 4) {
        int s0 = __builtin_amdgcn_readfirstlane(ssrc[p + 0]);
        int s1 = __builtin_amdgcn_readfirstlane(ssrc[p + 1]);
        int s2 = __builtin_amdgcn_readfirstlane(ssrc[p + 2]);
        int s3 = __builtin_amdgcn_readfirstlane(ssrc[p + 3]);
        float e0 = el[s0 * 4 + hh], e1 = el[s1 * 4 + hh];
        float e2 = el[s2 * 4 + hh], e3 = el[s3 * 4 + hh];
        unsigned v0 = *(const unsigned*)&featb[(size_t)s0 * 128 + lane * 2];
        unsigned v1 = *(const unsigned*)&featb[(size_t)s1 * 128 + lane * 2];
        unsigned v2 = *(const unsigned*)&featb[(size_t)s2 * 128 + lane * 2];
        unsigned v3 = *(const unsigned*)&featb[(size_t)s3 * 128 + lane * 2];
        float w0 = __expf(leaky(e0 + erh));
        float w1 = __expf(leaky(e1 + erh));
        float w2 = __expf(leaky(e2 + erh));
        float w3 = __expf(leaky(e3 + erh));
        ssum += (w0 + w1) + (w2 + w3);
        a0 += w0 * lo16f(v0) + w1 * lo16f(v1) + w2 * lo16f(v2) + w3 * lo16f(v3);
        a1 += w0 * hi16f(v0) + w1 * hi16f(v1) + w2 * hi16f(v2) + w3 * hi16f(v3);
    }
    for (; p < end; ++p) {
        int s = __builtin_amdgcn_readfirstlane(ssrc[p]);
        float w0 = __expf(leaky(el[s * 4 + hh] + erh));
        unsigned v = *(const unsigned*)&featb[(size_t)s * 128 + lane * 2];
        ssum += w0;
        a0 += w0 * lo16f(v);
        a1 += w0 * hi16f(v);
    }
    float inv = (end > beg) ? 1.f / ssum : 0.f;
    size_t o = (size_t)node * 128 + lane * 2;
    unsigned rh = *(const unsigned*)&xbh[o];
    unsigned rl = *(const unsigned*)&xbl[o];
    float r0 = fmaxf(a0 * inv + lo16f(rh) + lo16f(rl), 0.f);
    float r1 = fmaxf(a1 * inv + hi16f(rh) + hi16f(rl), 0.f);
    ushort h0 = f2bf(r0), h1 = f2bf(r1);
    ushort l0 = f2bf(r0 - bf2f(h0)), l1 = f2bf(r1 - bf2f(h1));
    *(unsigned*)&xbh[o] = (unsigned)h0 | ((unsigned)h1 << 16);
    *(unsigned*)&xbl[o] = (unsigned)l0 | ((unsigned)l1 << 16);
}

// Layer 3: C=256 (H=4, D=64). lane: head hh=lane>>4, dims dd=(lane&15)*4.
// 8B gathers, head-mean via shfl_xor, fused projected residual.

__global__ void __launch_bounds__(256)
aggregate3_kernel(const ushort* __restrict__ featb, const float* __restrict__ el,
                  const float* __restrict__ er, const int* __restrict__ row_ptr,
                  const int* __restrict__ ssrc, const float* __restrict__ res3,
                  float* __restrict__ out, int n) {
    const int wid = threadIdx.x >> 6;
    const int lane = threadIdx.x & 63;
    const int node = blockIdx.x * 4 + wid;
    if (node >= n) return;
    const int beg = row_ptr[node];
    const int end = row_ptr[node + 1];
    const int hh = lane >> 4;
    const int dd = (lane & 15) * 4;
    const int off = hh * 64 + dd;
    const float erh = er[node * 4 + hh];

    float c0 = 0.f, c1 = 0.f, c2 = 0.f, c3 = 0.f, ssum = 0.f;
    int p = beg;
    for (; p + 4 <= end; p += 4) {
        int s0 = __builtin_amdgcn_readfirstlane(ssrc[p + 0]);
        int s1 = __builtin_amdgcn_readfirstlane(ssrc[p + 1]);
        int s2 = __builtin_amdgcn_readfirstlane(ssrc[p + 2]);
        int s3 = __builtin_amdgcn_readfirstlane(ssrc[p + 3]);
        float e0 = el[s0 * 4 + hh], e1 = el[s1 * 4 + hh];
        float e2 = el[s2 * 4 + hh], e3 = el[s3 * 4 + hh];
        uint2 v0 = *(const uint2*)&featb[(size_t)s0 * 256 + off];
        uint2 v1 = *(const uint2*)&featb[(size_t)s1 * 256 + off];
        uint2 v2 = *(const uint2*)&featb[(size_t)s2 * 256 + off];
        uint2 v3 = *(const uint2*)&featb[(size_t)s3 * 256 + off];
        float w0 = __expf(leaky(e0 + erh));
        float w1 = __expf(leaky(e1 + erh));
        float w2 = __expf(leaky(e2 + erh));
        float w3 = __expf(leaky(e3 + erh));
        ssum += (w0 + w1) + (w2 + w3);
        c0 += w0 * lo16f(v0.x) + w1 * lo16f(v1.x) + w2 * lo16f(v2.x) + w3 * lo16f(v3.x);
        c1 += w0 * hi16f(v0.x) + w1 * hi16f(v1.x) + w2 * hi16f(v2.x) + w3 * hi16f(v3.x);
        c2 += w0 * lo16f(v0.y) + w1 * lo16f(v1.y) + w2 * lo16f(v2.y) + w3 * lo16f(v3.y);
        c3 += w0 * hi16f(v0.y) + w1 * hi16f(v1.y) + w2 * hi16f(v2.y) + w3 * hi16f(v3.y);
    }
    for (; p < end; ++p) {
        int s = __builtin_amdgcn_readfirstlane(ssrc[p]);
        float w0 = __expf(leaky(el[s * 4 + hh] + erh));
        uint2 v = *(const uint2*)&featb[(size_t)s * 256 + off];
        ssum += w0;
        c0 += w0 * lo16f(v.x);
        c1 += w0 * hi16f(v.x);
        c2 += w0 * lo16f(v.y);
        c3 += w0 * hi16f(v.y);
    }
    float inv = (end > beg) ? 1.f / ssum : 0.f;
    float4 rb = *(const float4*)&res3[(size_t)node * 256 + off];
    float r0 = c0 * inv + rb.x;
    float r1 = c1 * inv + rb.y;
    float r2 = c2 * inv + rb.z;
    float r3 = c3 * inv + rb.w;
    r0 += __shfl_xor(r0, 16); r0 += __shfl_xor(r0, 32);
    r1 += __shfl_xor(r1, 16); r1 += __shfl_xor(r1, 32);
    r2 += __shfl_xor(r2, 16); r2 += __shfl_xor(r2, 32);
    r3 += __shfl_xor(r3, 16); r3 += __shfl_xor(r3, 32);
    if (hh == 0) {
        *(float4*)&out[(size_t)node * 64 + dd] =
            make_float4(0.25f * r0, 0.25f * r1, 0.25f * r2, 0.25f * r3);
    }
}

// ------------------------------ launch ---------------------------------------

extern "C" void kernel_launch(void* const* d_in, const int* in_sizes, int n_in,
                              void* d_out, int out_size, void* d_ws, size_t ws_size,
                              hipStream_t stream) {
    const float* h   = (const float*)d_in[0];
    const float* W1  = (const float*)d_in[1];
    const float* al1 = (const float*)d_in[2];
    const float* ar1 = (const float*)d_in[3];
    const float* W2  = (const float*)d_in[4];
    const float* al2 = (const float*)d_in[5];
    const float* ar2 = (const float*)d_in[6];
    const float* W3  = (const float*)d_in[7];
    const float* al3 = (const float*)d_in[8];
    const float* ar3 = (const float*)d_in[9];
    const float* rW3 = (const float*)d_in[10];
    const int* src   = (const int*)d_in[11];
    const int* dstv  = (const int*)d_in[12];
    const int N = in_sizes[0] / 128;
    const int E = in_sizes[11];
    float* out = (float*)d_out;

    char* p = (char*)d_ws;
    auto alloc = [&](size_t bytes) -> char* {
        char* q = p;
        p += (bytes + 255) & ~(size_t)255;
        return q;
    };
    int*    row_ptr = (int*)alloc((size_t)(N + 1) * 4);
    int*    cursor  = (int*)alloc((size_t)N * 4);
    int*    loc     = (int*)alloc((size_t)N * 4);
    int*    bsum    = (int*)alloc(64 * 4);
    int*    ssrc    = (int*)alloc((size_t)E * 4);
    float*  el      = (float*)alloc((size_t)N * 16);
    float*  er      = (float*)alloc((size_t)N * 16);
    ushort* featb   = (ushort*)alloc((size_t)N * 256 * 2);
    ushort* xbh     = (ushort*)alloc((size_t)N * 128 * 2);
    ushort* xbl     = (ushort*)alloc((size_t)N * 128 * 2);
    ushort* W1th = (ushort*)alloc(128 * 128 * 2), *W1tl = (ushort*)alloc(128 * 128 * 2);
    ushort* W2th = (ushort*)alloc(128 * 128 * 2), *W2tl = (ushort*)alloc(128 * 128 * 2);
    ushort* W3th = (ushort*)alloc(256 * 128 * 2), *W3tl = (ushort*)alloc(256 * 128 * 2);
    ushort* rW3th = (ushort*)alloc(256 * 128 * 2), *rW3tl = (ushort*)alloc(256 * 128 * 2);
    float*  res3 = (float*)alloc((size_t)N * 256 * 4);

    // CSR build
    hipMemsetAsync(cursor, 0, (size_t)N * 4, stream);
    hist_kernel<<<(E + 255) / 256, 256, 0, stream>>>(dstv, cursor, E);
    int nb = (N + 1023) / 1024;
    block_scan_kernel<<<nb, 1024, 0, stream>>>(cursor, loc, bsum, N);
    scan_bsum_kernel<<<1, 64, 0, stream>>>(bsum, nb, row_ptr + N);
    apply_scan_kernel<<<(N + 255) / 256, 256, 0, stream>>>(loc, bsum, row_ptr, cursor, N);
    scatter_kernel<<<(E + 255) / 256, 256, 0, stream>>>(src, dstv, cursor, ssrc, E);

    // casts
    cast_split_kernel<<<(N * 128 / 4 + 255) / 256, 256, 0, stream>>>(h, xbh, xbl, N * 128 / 4);
    castT_split_kernel<<<(128 * 128 + 255) / 256, 256, 0, stream>>>(W1, W1th, W1tl, 128);
    castT_split_kernel<<<(128 * 128 + 255) / 256, 256, 0, stream>>>(W2, W2th, W2tl, 128);
    castT_split_kernel<<<(128 * 256 + 255) / 256, 256, 0, stream>>>(W3, W3th, W3tl, 256);
    castT_split_kernel<<<(128 * 256 + 255) / 256, 256, 0, stream>>>(rW3, rW3th, rW3tl, 256);

    dim3 g1((N + 63) / 64, 2);
    dim3 g3((N + 63) / 64, 4);
    int agg_grid = (N + 3) / 4;

    // layer 1
    gemm_kernel<<<g1, 256, 0, stream>>>(xbh, xbl, W1th, W1tl, nullptr, nullptr,
                                        featb, nullptr, al1, ar1, el, er, N, 128, 5);
    aggregate12_kernel<<<agg_grid, 256, 0, stream>>>(featb, el, er, row_ptr, ssrc, xbh, xbl, N);

    // layer 2
    gemm_kernel<<<g1, 256, 0, stream>>>(xbh, xbl, W2th, W2tl, nullptr, nullptr,
                                        featb, nullptr, al2, ar2, el, er, N, 128, 5);
    aggregate12_kernel<<<agg_grid, 256, 0, stream>>>(featb, el, er, row_ptr, ssrc, xbh, xbl, N);

    // layer 3 (W3 + residual projection fused, shared X fragments)
    gemm_kernel<<<g3, 256, 0, stream>>>(xbh, xbl, W3th, W3tl, rW3th, rW3tl,
                                        featb, res3, al3, ar3, el, er, N, 256, 6);
    aggregate3_kernel<<<agg_grid, 256, 0, stream>>>(featb, el, er, row_ptr, ssrc, res3, out, N);
}

// Round 5
// 431.011 us; speedup vs baseline: 2.3908x; 1.2690x over previous
//
#include <hip/hip_runtime.h>
#include <hip/hip_bf16.h>
#include <math.h>

// ---------------------------------------------------------------------------
// GAT 3-layer forward. N=50000 nodes, E=800000 edges, H=4 heads.
// GEMMs: split-bf16 MFMA (hi/lo planes, 3 mfma -> ~fp32), W staged in LDS
// (swizzled, one load per block, 4-wave reuse), el/er fused into epilogue.
// Layer-3 residual: head-mean folded into the weight (rWm = 0.25*sum_h resW3).
// Aggregation: one wave per dst node, exp(leaky()) inline, 4x-unrolled gathers.
// ---------------------------------------------------------------------------

#define NEG_SLOPE 0.2f

typedef __attribute__((ext_vector_type(8))) __bf16 bf16x8;
typedef __attribute__((ext_vector_type(4))) float f32x4;

__device__ __forceinline__ float leaky(float x) { return fmaxf(x, NEG_SLOPE * x); }
__device__ __forceinline__ ushort f2bf(float f) {
    unsigned u = __float_as_uint(f);
    return (ushort)((u + 0x7fffu + ((u >> 16) & 1u)) >> 16);
}
__device__ __forceinline__ float bf2f(ushort b) { return __uint_as_float(((unsigned)b) << 16); }
__device__ __forceinline__ float lo16f(unsigned v) { return __uint_as_float(v << 16); }
__device__ __forceinline__ float hi16f(unsigned v) { return __uint_as_float(v & 0xffff0000u); }

// ------------------------- CSR build (per dst) ------------------------------

__global__ void hist_kernel(const int* __restrict__ dst, int* __restrict__ deg, int E) {
    int i = blockIdx.x * blockDim.x + threadIdx.x;
    if (i < E) atomicAdd(&deg[dst[i]], 1);
}

__global__ void block_scan_kernel(const int* __restrict__ deg, int* __restrict__ loc,
                                  int* __restrict__ bsum, int n) {
    __shared__ int sm[1024];
    const int tid = threadIdx.x;
    const int i = blockIdx.x * 1024 + tid;
    int v = (i < n) ? deg[i] : 0;
    sm[tid] = v;
    __syncthreads();
    for (int off = 1; off < 1024; off <<= 1) {
        int t = (tid >= off) ? sm[tid - off] : 0;
        __syncthreads();
        sm[tid] += t;
        __syncthreads();
    }
    if (i < n) loc[i] = sm[tid] - v;
    if (tid == 1023) bsum[blockIdx.x] = sm[1023];
}

__global__ void scan_bsum_kernel(int* __restrict__ bsum, int nb, int* __restrict__ total_out) {
    const int lane = threadIdx.x;
    int v = (lane < nb) ? bsum[lane] : 0;
    int orig = v;
    for (int off = 1; off < 64; off <<= 1) {
        int t = __shfl_up(v, off);
        if (lane >= off) v += t;
    }
    if (lane < nb) bsum[lane] = v - orig;
    if (lane == 63) *total_out = v;
}

__global__ void apply_scan_kernel(const int* __restrict__ loc, const int* __restrict__ bsum,
                                  int* __restrict__ row_ptr, int* __restrict__ cursor, int n) {
    int i = blockIdx.x * blockDim.x + threadIdx.x;
    if (i < n) {
        int v = loc[i] + bsum[i >> 10];
        row_ptr[i] = v;
        cursor[i]  = v;
    }
}

__global__ void scatter_kernel(const int* __restrict__ src, const int* __restrict__ dst,
                               int* __restrict__ cursor, int* __restrict__ ssrc, int E) {
    int i = blockIdx.x * blockDim.x + threadIdx.x;
    if (i < E) {
        int s = src[i];
        int pos = atomicAdd(&cursor[dst[i]], 1);
        ssrc[pos] = s;
    }
}

// ----------------------------- casts ----------------------------------------

__global__ void cast_split_kernel(const float* __restrict__ in, ushort* __restrict__ hi,
                                  ushort* __restrict__ lo, int n4) {
    int i = blockIdx.x * blockDim.x + threadIdx.x;
    if (i >= n4) return;
    float4 v = ((const float4*)in)[i];
    ushort4 h, l;
    h.x = f2bf(v.x); l.x = f2bf(v.x - bf2f(h.x));
    h.y = f2bf(v.y); l.y = f2bf(v.y - bf2f(h.y));
    h.z = f2bf(v.z); l.z = f2bf(v.z - bf2f(h.z));
    h.w = f2bf(v.w); l.w = f2bf(v.w - bf2f(h.w));
    ((ushort4*)hi)[i] = h;
    ((ushort4*)lo)[i] = l;
}

// W [128][Ncols] fp32 -> Wt hi/lo [Ncols][128] bf16, inner index XOR-swizzled
// (k ^ ((col&7)<<3)) so the GEMM's LDS copy is linear and ds_read conflict-free.
__global__ void castT_split_kernel(const float* __restrict__ in, ushort* __restrict__ hi,
                                   ushort* __restrict__ lo, int Ncols) {
    int i = blockIdx.x * blockDim.x + threadIdx.x;
    if (i >= 128 * Ncols) return;
    int c = i >> 7, k = i & 127;
    float v = in[k * Ncols + c];
    int kd = k ^ ((c & 7) << 3);
    ushort h = f2bf(v);
    hi[c * 128 + kd] = h;
    lo[c * 128 + kd] = f2bf(v - bf2f(h));
}

// rWm[k][c] = 0.25 * sum_h resW3[k][h*64+c]  (head-mean folded into weight),
// written transposed + swizzled like castT.
__global__ void fold_resW_kernel(const float* __restrict__ rW3, ushort* __restrict__ hi,
                                 ushort* __restrict__ lo) {
    int i = blockIdx.x * blockDim.x + threadIdx.x;
    if (i >= 64 * 128) return;
    int c = i >> 7, k = i & 127;
    const float* row = rW3 + (size_t)k * 256;
    float v = 0.25f * ((row[c] + row[64 + c]) + (row[128 + c] + row[192 + c]));
    int kd = k ^ ((c & 7) << 3);
    ushort h = f2bf(v);
    hi[c * 128 + kd] = h;
    lo[c * 128 + kd] = f2bf(v - bf2f(h));
}

// ------------------------------- GEMM ---------------------------------------
// C[M,Ncols] = X[M,128] @ W; X,W as bf16 hi/lo planes; W transposed+swizzled.
// Block = 4 waves, tile 128(M) x 64(N); wave = 32(M) x 64(N); K=128 in regs.
// W slice (64 cols x 128 k x 2 planes = 32KB) staged once in LDS, 4-wave reuse.
// Epilogue: optional bf16 C, optional fp32 C, optional fused el/er scores.

__global__ void __launch_bounds__(256)
gemm_kernel(const ushort* __restrict__ Ah, const ushort* __restrict__ Al,
            const ushort* __restrict__ Bth, const ushort* __restrict__ Btl,
            ushort* __restrict__ Cb, float* __restrict__ Cf,
            const float* __restrict__ alv, const float* __restrict__ arv,
            float* __restrict__ el, float* __restrict__ er,
            int M, int Ncols, int dshift) {
    __shared__ ushort Ws[2][64 * 128];   // 32 KB
    const int tid = threadIdx.x;
    const int wv = tid >> 6;
    const int lane = tid & 63;
    const int l15 = lane & 15;
    const int g = lane >> 4;
    const int bm = blockIdx.x * 128 + wv * 32;
    const int bn = blockIdx.y * 64;

    // stage W slice (linear copy; global layout already swizzled)
    {
        const uint4* gh = (const uint4*)(Bth + (size_t)bn * 128);
        const uint4* gl = (const uint4*)(Btl + (size_t)bn * 128);
        uint4* sh = (uint4*)Ws[0];
        uint4* sl = (uint4*)Ws[1];
#pragma unroll
        for (int it = 0; it < 4; ++it) {
            sh[it * 256 + tid] = gh[it * 256 + tid];
            sl[it * 256 + tid] = gl[it * 256 + tid];
        }
    }
    __syncthreads();

    // X fragments: 2 m-frags per wave
    const int m0 = bm + l15;
    const int m1 = bm + 16 + l15;
    const int mc0 = (m0 < M) ? m0 : (M - 1);
    const int mc1 = (m1 < M) ? m1 : (M - 1);
    bf16x8 xh[2][4], xl[2][4];
#pragma unroll
    for (int kk = 0; kk < 4; ++kk) {
        xh[0][kk] = *(const bf16x8*)(Ah + (size_t)mc0 * 128 + kk * 32 + g * 8);
        xl[0][kk] = *(const bf16x8*)(Al + (size_t)mc0 * 128 + kk * 32 + g * 8);
        xh[1][kk] = *(const bf16x8*)(Ah + (size_t)mc1 * 128 + kk * 32 + g * 8);
        xl[1][kk] = *(const bf16x8*)(Al + (size_t)mc1 * 128 + kk * 32 + g * 8);
    }

    f32x4 acc[2][4] = {};
    const int swz = (l15 & 7) << 4;
#pragma unroll
    for (int n = 0; n < 4; ++n) {
        const int colb = (n * 16 + l15) * 256;
#pragma unroll
        for (int kk = 0; kk < 4; ++kk) {
            const int boff = colb + ((kk * 64 + g * 16) ^ swz);
            bf16x8 wh = *(const bf16x8*)((const char*)Ws[0] + boff);
            bf16x8 wl = *(const bf16x8*)((const char*)Ws[1] + boff);
            acc[0][n] = __builtin_amdgcn_mfma_f32_16x16x32_bf16(wh, xh[0][kk], acc[0][n], 0, 0, 0);
            acc[1][n] = __builtin_amdgcn_mfma_f32_16x16x32_bf16(wh, xh[1][kk], acc[1][n], 0, 0, 0);
            acc[0][n] = __builtin_amdgcn_mfma_f32_16x16x32_bf16(wh, xl[0][kk], acc[0][n], 0, 0, 0);
            acc[1][n] = __builtin_amdgcn_mfma_f32_16x16x32_bf16(wh, xl[1][kk], acc[1][n], 0, 0, 0);
            acc[0][n] = __builtin_amdgcn_mfma_f32_16x16x32_bf16(wl, xh[0][kk], acc[0][n], 0, 0, 0);
            acc[1][n] = __builtin_amdgcn_mfma_f32_16x16x32_bf16(wl, xh[1][kk], acc[1][n], 0, 0, 0);
        }
    }

#pragma unroll
    for (int mf = 0; mf < 2; ++mf) {
        const int m = (mf == 0) ? m0 : m1;
        const bool valid = (m < M);
        if (valid) {
            size_t ro = (size_t)m * Ncols;
#pragma unroll
            for (int n = 0; n < 4; ++n) {
                int col = bn + n * 16 + g * 4;
                if (Cb) {
                    ushort4 o;
                    o.x = f2bf(acc[mf][n][0]); o.y = f2bf(acc[mf][n][1]);
                    o.z = f2bf(acc[mf][n][2]); o.w = f2bf(acc[mf][n][3]);
                    *(ushort4*)&Cb[ro + col] = o;
                }
                if (Cf) {
                    *(float4*)&Cf[ro + col] = make_float4(acc[mf][n][0], acc[mf][n][1],
                                                          acc[mf][n][2], acc[mf][n][3]);
                }
            }
        }
        if (alv) {
            float e0 = 0.f, e1 = 0.f, r0 = 0.f, r1 = 0.f;
#pragma unroll
            for (int n = 0; n < 4; ++n) {
#pragma unroll
                for (int r = 0; r < 4; ++r) {
                    int col = n * 16 + g * 4 + r;
                    float c = acc[mf][n][r];
                    float av = alv[bn + col];
                    float bv = arv[bn + col];
                    if ((col >> dshift) == 0) { e0 += c * av; r0 += c * bv; }
                    else                      { e1 += c * av; r1 += c * bv; }
                }
            }
            e0 += __shfl_xor(e0, 16); e0 += __shfl_xor(e0, 32);
            e1 += __shfl_xor(e1, 16); e1 += __shfl_xor(e1, 32);
            r0 += __shfl_xor(r0, 16); r0 += __shfl_xor(r0, 32);
            r1 += __shfl_xor(r1, 16); r1 += __shfl_xor(r1, 32);
            if (valid && g == 0) {
                int h0 = bn >> dshift;
                el[m * 4 + h0] = e0;
                er[m * 4 + h0] = r0;
                if (dshift == 5) {
                    el[m * 4 + h0 + 1] = e1;
                    er[m * 4 + h0 + 1] = r1;
                }
            }
        }
    }
}

// --------------------------- aggregation -------------------------------------

__global__ void __launch_bounds__(256)
aggregate12_kernel(const ushort* __restrict__ featb, const float* __restrict__ el,
                   const float* __restrict__ er, const int* __restrict__ row_ptr,
                   const int* __restrict__ ssrc, ushort* __restrict__ xbh,
                   ushort* __restrict__ xbl, int n) {
    const int wid = threadIdx.x >> 6;
    const int lane = threadIdx.x & 63;
    const int node = blockIdx.x * 4 + wid;
    if (node >= n) return;
    const int beg = row_ptr[node];
    const int end = row_ptr[node + 1];
    const int hh = lane >> 4;
    const float erh = er[node * 4 + hh];

    float ssum = 0.f, a0 = 0.f, a1 = 0.f;
    int p = beg;
    for (; p + 4 <= end; p += 4) {
        int s0 = __builtin_amdgcn_readfirstlane(ssrc[p + 0]);
        int s1 = __builtin_amdgcn_readfirstlane(ssrc[p + 1]);
        int s2 = __builtin_amdgcn_readfirstlane(ssrc[p + 2]);
        int s3 = __builtin_amdgcn_readfirstlane(ssrc[p + 3]);
        float e0 = el[s0 * 4 + hh], e1 = el[s1 * 4 + hh];
        float e2 = el[s2 * 4 + hh], e3 = el[s3 * 4 + hh];
        unsigned v0 = *(const unsigned*)&featb[(size_t)s0 * 128 + lane * 2];
        unsigned v1 = *(const unsigned*)&featb[(size_t)s1 * 128 + lane * 2];
        unsigned v2 = *(const unsigned*)&featb[(size_t)s2 * 128 + lane * 2];
        unsigned v3 = *(const unsigned*)&featb[(size_t)s3 * 128 + lane * 2];
        float w0 = __expf(leaky(e0 + erh));
        float w1 = __expf(leaky(e1 + erh));
        float w2 = __expf(leaky(e2 + erh));
        float w3 = __expf(leaky(e3 + erh));
        ssum += (w0 + w1) + (w2 + w3);
        a0 += w0 * lo16f(v0) + w1 * lo16f(v1) + w2 * lo16f(v2) + w3 * lo16f(v3);
        a1 += w0 * hi16f(v0) + w1 * hi16f(v1) + w2 * hi16f(v2) + w3 * hi16f(v3);
    }
    for (; p < end; ++p) {
        int s = __builtin_amdgcn_readfirstlane(ssrc[p]);
        float w0 = __expf(leaky(el[s * 4 + hh] + erh));
        unsigned v = *(const unsigned*)&featb[(size_t)s * 128 + lane * 2];
        ssum += w0;
        a0 += w0 * lo16f(v);
        a1 += w0 * hi16f(v);
    }
    float inv = (end > beg) ? 1.f / ssum : 0.f;
    size_t o = (size_t)node * 128 + lane * 2;
    unsigned rh = *(const unsigned*)&xbh[o];
    unsigned rl = *(const unsigned*)&xbl[o];
    float r0 = fmaxf(a0 * inv + lo16f(rh) + lo16f(rl), 0.f);
    float r1 = fmaxf(a1 * inv + hi16f(rh) + hi16f(rl), 0.f);
    ushort h0 = f2bf(r0), h1 = f2bf(r1);
    ushort l0 = f2bf(r0 - bf2f(h0)), l1 = f2bf(r1 - bf2f(h1));
    *(unsigned*)&xbh[o] = (unsigned)h0 | ((unsigned)h1 << 16);
    *(unsigned*)&xbl[o] = (unsigned)l0 | ((unsigned)l1 << 16);
}

// Layer 3: C=256 (H=4, D=64). Head-mean via shfl_xor; + resmean (pre-folded).

__global__ void __launch_bounds__(256)
aggregate3_kernel(const ushort* __restrict__ featb, const float* __restrict__ el,
                  const float* __restrict__ er, const int* __restrict__ row_ptr,
                  const int* __restrict__ ssrc, const float* __restrict__ resmean,
                  float* __restrict__ out, int n) {
    const int wid = threadIdx.x >> 6;
    const int lane = threadIdx.x & 63;
    const int node = blockIdx.x * 4 + wid;
    if (node >= n) return;
    const int beg = row_ptr[node];
    const int end = row_ptr[node + 1];
    const int hh = lane >> 4;
    const int dd = (lane & 15) * 4;
    const int off = hh * 64 + dd;
    const float erh = er[node * 4 + hh];

    float c0 = 0.f, c1 = 0.f, c2 = 0.f, c3 = 0.f, ssum = 0.f;
    int p = beg;
    for (; p + 4 <= end; p += 4) {
        int s0 = __builtin_amdgcn_readfirstlane(ssrc[p + 0]);
        int s1 = __builtin_amdgcn_readfirstlane(ssrc[p + 1]);
        int s2 = __builtin_amdgcn_readfirstlane(ssrc[p + 2]);
        int s3 = __builtin_amdgcn_readfirstlane(ssrc[p + 3]);
        float e0 = el[s0 * 4 + hh], e1 = el[s1 * 4 + hh];
        float e2 = el[s2 * 4 + hh], e3 = el[s3 * 4 + hh];
        uint2 v0 = *(const uint2*)&featb[(size_t)s0 * 256 + off];
        uint2 v1 = *(const uint2*)&featb[(size_t)s1 * 256 + off];
        uint2 v2 = *(const uint2*)&featb[(size_t)s2 * 256 + off];
        uint2 v3 = *(const uint2*)&featb[(size_t)s3 * 256 + off];
        float w0 = __expf(leaky(e0 + erh));
        float w1 = __expf(leaky(e1 + erh));
        float w2 = __expf(leaky(e2 + erh));
        float w3 = __expf(leaky(e3 + erh));
        ssum += (w0 + w1) + (w2 + w3);
        c0 += w0 * lo16f(v0.x) + w1 * lo16f(v1.x) + w2 * lo16f(v2.x) + w3 * lo16f(v3.x);
        c1 += w0 * hi16f(v0.x) + w1 * hi16f(v1.x) + w2 * hi16f(v2.x) + w3 * hi16f(v3.x);
        c2 += w0 * lo16f(v0.y) + w1 * lo16f(v1.y) + w2 * lo16f(v2.y) + w3 * lo16f(v3.y);
        c3 += w0 * hi16f(v0.y) + w1 * hi16f(v1.y) + w2 * hi16f(v2.y) + w3 * hi16f(v3.y);
    }
    for (; p < end; ++p) {
        int s = __builtin_amdgcn_readfirstlane(ssrc[p]);
        float w0 = __expf(leaky(el[s * 4 + hh] + erh));
        uint2 v = *(const uint2*)&featb[(size_t)s * 256 + off];
        ssum += w0;
        c0 += w0 * lo16f(v.x);
        c1 += w0 * hi16f(v.x);
        c2 += w0 * lo16f(v.y);
        c3 += w0 * hi16f(v.y);
    }
    float inv = (end > beg) ? 1.f / ssum : 0.f;
    float r0 = c0 * inv, r1 = c1 * inv, r2 = c2 * inv, r3 = c3 * inv;
    r0 += __shfl_xor(r0, 16); r0 += __shfl_xor(r0, 32);
    r1 += __shfl_xor(r1, 16); r1 += __shfl_xor(r1, 32);
    r2 += __shfl_xor(r2, 16); r2 += __shfl_xor(r2, 32);
    r3 += __shfl_xor(r3, 16); r3 += __shfl_xor(r3, 32);
    if (hh == 0) {
        float4 rm = *(const float4*)&resmean[(size_t)node * 64 + dd];
        *(float4*)&out[(size_t)node * 64 + dd] =
            make_float4(0.25f * r0 + rm.x, 0.25f * r1 + rm.y,
                        0.25f * r2 + rm.z, 0.25f * r3 + rm.w);
    }
}

// ------------------------------ launch ---------------------------------------

extern "C" void kernel_launch(void* const* d_in, const int* in_sizes, int n_in,
                              void* d_out, int out_size, void* d_ws, size_t ws_size,
                              hipStream_t stream) {
    const float* h   = (const float*)d_in[0];
    const float* W1  = (const float*)d_in[1];
    const float* al1 = (const float*)d_in[2];
    const float* ar1 = (const float*)d_in[3];
    const float* W2  = (const float*)d_in[4];
    const float* al2 = (const float*)d_in[5];
    const float* ar2 = (const float*)d_in[6];
    const float* W3  = (const float*)d_in[7];
    const float* al3 = (const float*)d_in[8];
    const float* ar3 = (const float*)d_in[9];
    const float* rW3 = (const float*)d_in[10];
    const int* src   = (const int*)d_in[11];
    const int* dstv  = (const int*)d_in[12];
    const int N = in_sizes[0] / 128;
    const int E = in_sizes[11];
    float* out = (float*)d_out;

    char* p = (char*)d_ws;
    auto alloc = [&](size_t bytes) -> char* {
        char* q = p;
        p += (bytes + 255) & ~(size_t)255;
        return q;
    };
    int*    row_ptr = (int*)alloc((size_t)(N + 1) * 4);
    int*    cursor  = (int*)alloc((size_t)N * 4);
    int*    loc     = (int*)alloc((size_t)N * 4);
    int*    bsum    = (int*)alloc(64 * 4);
    int*    ssrc    = (int*)alloc((size_t)E * 4);
    float*  el      = (float*)alloc((size_t)N * 16);
    float*  er      = (float*)alloc((size_t)N * 16);
    ushort* featb   = (ushort*)alloc((size_t)N * 256 * 2);
    ushort* xbh     = (ushort*)alloc((size_t)N * 128 * 2);
    ushort* xbl     = (ushort*)alloc((size_t)N * 128 * 2);
    ushort* W1th = (ushort*)alloc(128 * 128 * 2), *W1tl = (ushort*)alloc(128 * 128 * 2);
    ushort* W2th = (ushort*)alloc(128 * 128 * 2), *W2tl = (ushort*)alloc(128 * 128 * 2);
    ushort* W3th = (ushort*)alloc(256 * 128 * 2), *W3tl = (ushort*)alloc(256 * 128 * 2);
    ushort* rWmh = (ushort*)alloc(64 * 128 * 2),  *rWml = (ushort*)alloc(64 * 128 * 2);
    float*  resmean = (float*)alloc((size_t)N * 64 * 4);

    // CSR build
    hipMemsetAsync(cursor, 0, (size_t)N * 4, stream);
    hist_kernel<<<(E + 255) / 256, 256, 0, stream>>>(dstv, cursor, E);
    int nb = (N + 1023) / 1024;
    block_scan_kernel<<<nb, 1024, 0, stream>>>(cursor, loc, bsum, N);
    scan_bsum_kernel<<<1, 64, 0, stream>>>(bsum, nb, row_ptr + N);
    apply_scan_kernel<<<(N + 255) / 256, 256, 0, stream>>>(loc, bsum, row_ptr, cursor, N);
    scatter_kernel<<<(E + 255) / 256, 256, 0, stream>>>(src, dstv, cursor, ssrc, E);

    // casts (weights transposed + swizzled)
    cast_split_kernel<<<(N * 128 / 4 + 255) / 256, 256, 0, stream>>>(h, xbh, xbl, N * 128 / 4);
    castT_split_kernel<<<(128 * 128 + 255) / 256, 256, 0, stream>>>(W1, W1th, W1tl, 128);
    castT_split_kernel<<<(128 * 128 + 255) / 256, 256, 0, stream>>>(W2, W2th, W2tl, 128);
    castT_split_kernel<<<(128 * 256 + 255) / 256, 256, 0, stream>>>(W3, W3th, W3tl, 256);
    fold_resW_kernel<<<(64 * 128 + 255) / 256, 256, 0, stream>>>(rW3, rWmh, rWml);

    const int gx = (N + 127) / 128;
    dim3 g1(gx, 2);
    dim3 g3(gx, 4);
    dim3 gr(gx, 1);
    int agg_grid = (N + 3) / 4;

    // layer 1
    gemm_kernel<<<g1, 256, 0, stream>>>(xbh, xbl, W1th, W1tl, featb, nullptr,
                                        al1, ar1, el, er, N, 128, 5);
    aggregate12_kernel<<<agg_grid, 256, 0, stream>>>(featb, el, er, row_ptr, ssrc, xbh, xbl, N);

    // layer 2
    gemm_kernel<<<g1, 256, 0, stream>>>(xbh, xbl, W2th, W2tl, featb, nullptr,
                                        al2, ar2, el, er, N, 128, 5);
    aggregate12_kernel<<<agg_grid, 256, 0, stream>>>(featb, el, er, row_ptr, ssrc, xbh, xbl, N);

    // layer 3
    gemm_kernel<<<g3, 256, 0, stream>>>(xbh, xbl, W3th, W3tl, featb, nullptr,
                                        al3, ar3, el, er, N, 256, 6);
    gemm_kernel<<<gr, 256, 0, stream>>>(xbh, xbl, rWmh, rWml, nullptr, resmean,
                                        nullptr, nullptr, nullptr, nullptr, N, 64, 6);
    aggregate3_kernel<<<agg_grid, 256, 0, stream>>>(featb, el, er, row_ptr, ssrc, resmean, out, N);
}

// Round 8
// 418.336 us; speedup vs baseline: 2.4633x; 1.0303x over previous
//
#include <hip/hip_runtime.h>
#include <hip/hip_bf16.h>
#include <math.h>

// ---------------------------------------------------------------------------
// GAT 3-layer forward. N=50000 nodes, E=800000 edges, H=4 heads.
// GEMMs: bf16 MFMA (hi plane only; error dominated by bf16 feature gathers),
// W staged in LDS (swizzled, one load per block, 4-wave reuse), el/er fused
// into epilogue. x kept as bf16 hi+lo planes so the residual path stays ~fp32.
// Layer-3 residual head-mean folded into weight.
// Aggregation: one wave per dst node, exp(leaky()) inline (max-subtraction
// cancels in alpha), 8x-unrolled gathers for memory-level parallelism.
// ---------------------------------------------------------------------------

#define NEG_SLOPE 0.2f

typedef __attribute__((ext_vector_type(8))) __bf16 bf16x8;
typedef __attribute__((ext_vector_type(4))) float f32x4;

__device__ __forceinline__ float leaky(float x) { return fmaxf(x, NEG_SLOPE * x); }
__device__ __forceinline__ ushort f2bf(float f) {
    unsigned u = __float_as_uint(f);
    return (ushort)((u + 0x7fffu + ((u >> 16) & 1u)) >> 16);
}
__device__ __forceinline__ float bf2f(ushort b) { return __uint_as_float(((unsigned)b) << 16); }
__device__ __forceinline__ float lo16f(unsigned v) { return __uint_as_float(v << 16); }
__device__ __forceinline__ float hi16f(unsigned v) { return __uint_as_float(v & 0xffff0000u); }

// ------------------------- CSR build (per dst) ------------------------------

__global__ void hist_kernel(const int* __restrict__ dst, int* __restrict__ deg, int E) {
    int i = blockIdx.x * blockDim.x + threadIdx.x;
    if (i < E) atomicAdd(&deg[dst[i]], 1);
}

__global__ void block_scan_kernel(const int* __restrict__ deg, int* __restrict__ loc,
                                  int* __restrict__ bsum, int n) {
    __shared__ int sm[1024];
    const int tid = threadIdx.x;
    const int i = blockIdx.x * 1024 + tid;
    int v = (i < n) ? deg[i] : 0;
    sm[tid] = v;
    __syncthreads();
    for (int off = 1; off < 1024; off <<= 1) {
        int t = (tid >= off) ? sm[tid - off] : 0;
        __syncthreads();
        sm[tid] += t;
        __syncthreads();
    }
    if (i < n) loc[i] = sm[tid] - v;
    if (tid == 1023) bsum[blockIdx.x] = sm[1023];
}

__global__ void scan_bsum_kernel(int* __restrict__ bsum, int nb, int* __restrict__ total_out) {
    const int lane = threadIdx.x;
    int v = (lane < nb) ? bsum[lane] : 0;
    int orig = v;
    for (int off = 1; off < 64; off <<= 1) {
        int t = __shfl_up(v, off);
        if (lane >= off) v += t;
    }
    if (lane < nb) bsum[lane] = v - orig;
    if (lane == 63) *total_out = v;
}

__global__ void apply_scan_kernel(const int* __restrict__ loc, const int* __restrict__ bsum,
                                  int* __restrict__ row_ptr, int* __restrict__ cursor, int n) {
    int i = blockIdx.x * blockDim.x + threadIdx.x;
    if (i < n) {
        int v = loc[i] + bsum[i >> 10];
        row_ptr[i] = v;
        cursor[i]  = v;
    }
}

__global__ void scatter_kernel(const int* __restrict__ src, const int* __restrict__ dst,
                               int* __restrict__ cursor, int* __restrict__ ssrc, int E) {
    int i = blockIdx.x * blockDim.x + threadIdx.x;
    if (i < E) {
        int s = src[i];
        int pos = atomicAdd(&cursor[dst[i]], 1);
        ssrc[pos] = s;
    }
}

// ----------------------------- casts ----------------------------------------

__global__ void cast_split_kernel(const float* __restrict__ in, ushort* __restrict__ hi,
                                  ushort* __restrict__ lo, int n4) {
    int i = blockIdx.x * blockDim.x + threadIdx.x;
    if (i >= n4) return;
    float4 v = ((const float4*)in)[i];
    ushort4 h, l;
    h.x = f2bf(v.x); l.x = f2bf(v.x - bf2f(h.x));
    h.y = f2bf(v.y); l.y = f2bf(v.y - bf2f(h.y));
    h.z = f2bf(v.z); l.z = f2bf(v.z - bf2f(h.z));
    h.w = f2bf(v.w); l.w = f2bf(v.w - bf2f(h.w));
    ((ushort4*)hi)[i] = h;
    ((ushort4*)lo)[i] = l;
}

// W [128][Ncols] fp32 -> Wt [Ncols][128] bf16, inner index XOR-swizzled
// (k ^ ((col&7)<<3)) so the GEMM's LDS copy is linear and ds_read conflict-free.
__global__ void castT_kernel(const float* __restrict__ in, ushort* __restrict__ hi, int Ncols) {
    int i = blockIdx.x * blockDim.x + threadIdx.x;
    if (i >= 128 * Ncols) return;
    int c = i >> 7, k = i & 127;
    float v = in[k * Ncols + c];
    int kd = k ^ ((c & 7) << 3);
    hi[c * 128 + kd] = f2bf(v);
}

// rWm[k][c] = 0.25 * sum_h resW3[k][h*64+c], transposed + swizzled.
__global__ void fold_resW_kernel(const float* __restrict__ rW3, ushort* __restrict__ hi) {
    int i = blockIdx.x * blockDim.x + threadIdx.x;
    if (i >= 64 * 128) return;
    int c = i >> 7, k = i & 127;
    const float* row = rW3 + (size_t)k * 256;
    float v = 0.25f * ((row[c] + row[64 + c]) + (row[128 + c] + row[192 + c]));
    int kd = k ^ ((c & 7) << 3);
    hi[c * 128 + kd] = f2bf(v);
}

// ------------------------------- GEMM ---------------------------------------
// C[M,Ncols] = X[M,128] @ W; X hi-plane bf16, W transposed+swizzled bf16.
// Block = 4 waves, tile 128(M) x 64(N); wave = 32(M) x 64(N); K=128 in regs.
// W slice (64 cols x 128 k = 16KB = 1024 uint4) staged once in LDS, 4-wave reuse.
// Epilogue: optional bf16 C, optional fp32 C, optional fused el/er scores.

__global__ void __launch_bounds__(256)
gemm_kernel(const ushort* __restrict__ Ah, const ushort* __restrict__ Bth,
            ushort* __restrict__ Cb, float* __restrict__ Cf,
            const float* __restrict__ alv, const float* __restrict__ arv,
            float* __restrict__ el, float* __restrict__ er,
            int M, int Ncols, int dshift) {
    __shared__ ushort Ws[64 * 128];   // 16 KB
    const int tid = threadIdx.x;
    const int wv = tid >> 6;
    const int lane = tid & 63;
    const int l15 = lane & 15;
    const int g = lane >> 4;
    const int bm = blockIdx.x * 128 + wv * 32;
    const int bn = blockIdx.y * 64;

    // stage W slice: 1024 uint4 total, 256 threads x 4 iterations
    {
        const uint4* gh = (const uint4*)(Bth + (size_t)bn * 128);
        uint4* sh = (uint4*)Ws;
#pragma unroll
        for (int it = 0; it < 4; ++it) {
            sh[it * 256 + tid] = gh[it * 256 + tid];
        }
    }
    __syncthreads();

    // X fragments: 2 m-frags per wave
    const int m0 = bm + l15;
    const int m1 = bm + 16 + l15;
    const int mc0 = (m0 < M) ? m0 : (M - 1);
    const int mc1 = (m1 < M) ? m1 : (M - 1);
    bf16x8 xh[2][4];
#pragma unroll
    for (int kk = 0; kk < 4; ++kk) {
        xh[0][kk] = *(const bf16x8*)(Ah + (size_t)mc0 * 128 + kk * 32 + g * 8);
        xh[1][kk] = *(const bf16x8*)(Ah + (size_t)mc1 * 128 + kk * 32 + g * 8);
    }

    f32x4 acc[2][4] = {};
    const int swz = (l15 & 7) << 4;
#pragma unroll
    for (int n = 0; n < 4; ++n) {
        const int colb = (n * 16 + l15) * 256;
#pragma unroll
        for (int kk = 0; kk < 4; ++kk) {
            const int boff = colb + ((kk * 64 + g * 16) ^ swz);
            bf16x8 wh = *(const bf16x8*)((const char*)Ws + boff);
            acc[0][n] = __builtin_amdgcn_mfma_f32_16x16x32_bf16(wh, xh[0][kk], acc[0][n], 0, 0, 0);
            acc[1][n] = __builtin_amdgcn_mfma_f32_16x16x32_bf16(wh, xh[1][kk], acc[1][n], 0, 0, 0);
        }
    }

#pragma unroll
    for (int mf = 0; mf < 2; ++mf) {
        const int m = (mf == 0) ? m0 : m1;
        const bool valid = (m < M);
        if (valid) {
            size_t ro = (size_t)m * Ncols;
#pragma unroll
            for (int n = 0; n < 4; ++n) {
                int col = bn + n * 16 + g * 4;
                if (Cb) {
                    ushort4 o;
                    o.x = f2bf(acc[mf][n][0]); o.y = f2bf(acc[mf][n][1]);
                    o.z = f2bf(acc[mf][n][2]); o.w = f2bf(acc[mf][n][3]);
                    *(ushort4*)&Cb[ro + col] = o;
                }
                if (Cf) {
                    *(float4*)&Cf[ro + col] = make_float4(acc[mf][n][0], acc[mf][n][1],
                                                          acc[mf][n][2], acc[mf][n][3]);
                }
            }
        }
        if (alv) {
            float e0 = 0.f, e1 = 0.f, r0 = 0.f, r1 = 0.f;
#pragma unroll
            for (int n = 0; n < 4; ++n) {
#pragma unroll
                for (int r = 0; r < 4; ++r) {
                    int col = n * 16 + g * 4 + r;
                    float c = acc[mf][n][r];
                    float av = alv[bn + col];
                    float bv = arv[bn + col];
                    if ((col >> dshift) == 0) { e0 += c * av; r0 += c * bv; }
                    else                      { e1 += c * av; r1 += c * bv; }
                }
            }
            e0 += __shfl_xor(e0, 16); e0 += __shfl_xor(e0, 32);
            e1 += __shfl_xor(e1, 16); e1 += __shfl_xor(e1, 32);
            r0 += __shfl_xor(r0, 16); r0 += __shfl_xor(r0, 32);
            r1 += __shfl_xor(r1, 16); r1 += __shfl_xor(r1, 32);
            if (valid && g == 0) {
                int h0 = bn >> dshift;
                el[m * 4 + h0] = e0;
                er[m * 4 + h0] = r0;
                if (dshift == 5) {
                    el[m * 4 + h0 + 1] = e1;
                    er[m * 4 + h0 + 1] = r1;
                }
            }
        }
    }
}

// --------------------------- aggregation -------------------------------------
// Layers 1/2: C=128, lane owns 2 elems, head hh=lane>>4; 8x-unrolled gathers.

__global__ void __launch_bounds__(256)
aggregate12_kernel(const ushort* __restrict__ featb, const float* __restrict__ el,
                   const float* __restrict__ er, const int* __restrict__ row_ptr,
                   const int* __restrict__ ssrc, ushort* __restrict__ xbh,
                   ushort* __restrict__ xbl, int n) {
    const int wid = threadIdx.x >> 6;
    const int lane = threadIdx.x & 63;
    const int node = blockIdx.x * 4 + wid;
    if (node >= n) return;
    const int beg = row_ptr[node];
    const int end = row_ptr[node + 1];
    const int hh = lane >> 4;
    const float erh = er[node * 4 + hh];

    float ssum = 0.f, a0 = 0.f, a1 = 0.f;
    int p = beg;
    for (; p + 8 <= end; p += 8) {
        int s[8];
        float e[8];
        unsigned v[8];
#pragma unroll
        for (int j = 0; j < 8; ++j) s[j] = __builtin_amdgcn_readfirstlane(ssrc[p + j]);
#pragma unroll
        for (int j = 0; j < 8; ++j) v[j] = *(const unsigned*)&featb[(size_t)s[j] * 128 + lane * 2];
#pragma unroll
        for (int j = 0; j < 8; ++j) e[j] = el[s[j] * 4 + hh];
#pragma unroll
        for (int j = 0; j < 8; ++j) {
            float w0 = __expf(leaky(e[j] + erh));
            ssum += w0;
            a0 += w0 * lo16f(v[j]);
            a1 += w0 * hi16f(v[j]);
        }
    }
    for (; p < end; ++p) {
        int s = __builtin_amdgcn_readfirstlane(ssrc[p]);
        float w0 = __expf(leaky(el[s * 4 + hh] + erh));
        unsigned v = *(const unsigned*)&featb[(size_t)s * 128 + lane * 2];
        ssum += w0;
        a0 += w0 * lo16f(v);
        a1 += w0 * hi16f(v);
    }
    float inv = (end > beg) ? 1.f / ssum : 0.f;
    size_t o = (size_t)node * 128 + lane * 2;
    unsigned rh = *(const unsigned*)&xbh[o];
    unsigned rl = *(const unsigned*)&xbl[o];
    float r0 = fmaxf(a0 * inv + lo16f(rh) + lo16f(rl), 0.f);
    float r1 = fmaxf(a1 * inv + hi16f(rh) + hi16f(rl), 0.f);
    ushort h0 = f2bf(r0), h1 = f2bf(r1);
    ushort l0 = f2bf(r0 - bf2f(h0)), l1 = f2bf(r1 - bf2f(h1));
    *(unsigned*)&xbh[o] = (unsigned)h0 | ((unsigned)h1 << 16);
    *(unsigned*)&xbl[o] = (unsigned)l0 | ((unsigned)l1 << 16);
}

// Layer 3: C=256 (H=4, D=64). Head-mean via shfl_xor; + resmean (pre-folded).

__global__ void __launch_bounds__(256)
aggregate3_kernel(const ushort* __restrict__ featb, const float* __restrict__ el,
                  const float* __restrict__ er, const int* __restrict__ row_ptr,
                  const int* __restrict__ ssrc, const float* __restrict__ resmean,
                  float* __restrict__ out, int n) {
    const int wid = threadIdx.x >> 6;
    const int lane = threadIdx.x & 63;
    const int node = blockIdx.x * 4 + wid;
    if (node >= n) return;
    const int beg = row_ptr[node];
    const int end = row_ptr[node + 1];
    const int hh = lane >> 4;
    const int dd = (lane & 15) * 4;
    const int off = hh * 64 + dd;
    const float erh = er[node * 4 + hh];

    float c0 = 0.f, c1 = 0.f, c2 = 0.f, c3 = 0.f, ssum = 0.f;
    int p = beg;
    for (; p + 8 <= end; p += 8) {
        int s[8];
        float e[8];
        uint2 v[8];
#pragma unroll
        for (int j = 0; j < 8; ++j) s[j] = __builtin_amdgcn_readfirstlane(ssrc[p + j]);
#pragma unroll
        for (int j = 0; j < 8; ++j) v[j] = *(const uint2*)&featb[(size_t)s[j] * 256 + off];
#pragma unroll
        for (int j = 0; j < 8; ++j) e[j] = el[s[j] * 4 + hh];
#pragma unroll
        for (int j = 0; j < 8; ++j) {
            float w0 = __expf(leaky(e[j] + erh));
            ssum += w0;
            c0 += w0 * lo16f(v[j].x);
            c1 += w0 * hi16f(v[j].x);
            c2 += w0 * lo16f(v[j].y);
            c3 += w0 * hi16f(v[j].y);
        }
    }
    for (; p < end; ++p) {
        int s = __builtin_amdgcn_readfirstlane(ssrc[p]);
        float w0 = __expf(leaky(el[s * 4 + hh] + erh));
        uint2 v = *(const uint2*)&featb[(size_t)s * 256 + off];
        ssum += w0;
        c0 += w0 * lo16f(v.x);
        c1 += w0 * hi16f(v.x);
        c2 += w0 * lo16f(v.y);
        c3 += w0 * hi16f(v.y);
    }
    float inv = (end > beg) ? 1.f / ssum : 0.f;
    float r0 = c0 * inv, r1 = c1 * inv, r2 = c2 * inv, r3 = c3 * inv;
    r0 += __shfl_xor(r0, 16); r0 += __shfl_xor(r0, 32);
    r1 += __shfl_xor(r1, 16); r1 += __shfl_xor(r1, 32);
    r2 += __shfl_xor(r2, 16); r2 += __shfl_xor(r2, 32);
    r3 += __shfl_xor(r3, 16); r3 += __shfl_xor(r3, 32);
    if (hh == 0) {
        float4 rm = *(const float4*)&resmean[(size_t)node * 64 + dd];
        *(float4*)&out[(size_t)node * 64 + dd] =
            make_float4(0.25f * r0 + rm.x, 0.25f * r1 + rm.y,
                        0.25f * r2 + rm.z, 0.25f * r3 + rm.w);
    }
}

// ------------------------------ launch ---------------------------------------

extern "C" void kernel_launch(void* const* d_in, const int* in_sizes, int n_in,
                              void* d_out, int out_size, void* d_ws, size_t ws_size,
                              hipStream_t stream) {
    const float* h   = (const float*)d_in[0];
    const float* W1  = (const float*)d_in[1];
    const float* al1 = (const float*)d_in[2];
    const float* ar1 = (const float*)d_in[3];
    const float* W2  = (const float*)d_in[4];
    const float* al2 = (const float*)d_in[5];
    const float* ar2 = (const float*)d_in[6];
    const float* W3  = (const float*)d_in[7];
    const float* al3 = (const float*)d_in[8];
    const float* ar3 = (const float*)d_in[9];
    const float* rW3 = (const float*)d_in[10];
    const int* src   = (const int*)d_in[11];
    const int* dstv  = (const int*)d_in[12];
    const int N = in_sizes[0] / 128;
    const int E = in_sizes[11];
    float* out = (float*)d_out;

    char* p = (char*)d_ws;
    auto alloc = [&](size_t bytes) -> char* {
        char* q = p;
        p += (bytes + 255) & ~(size_t)255;
        return q;
    };
    int*    row_ptr = (int*)alloc((size_t)(N + 1) * 4);
    int*    cursor  = (int*)alloc((size_t)N * 4);
    int*    loc     = (int*)alloc((size_t)N * 4);
    int*    bsum    = (int*)alloc(64 * 4);
    int*    ssrc    = (int*)alloc((size_t)E * 4);
    float*  el      = (float*)alloc((size_t)N * 16);
    float*  er      = (float*)alloc((size_t)N * 16);
    ushort* featb   = (ushort*)alloc((size_t)N * 256 * 2);
    ushort* xbh     = (ushort*)alloc((size_t)N * 128 * 2);
    ushort* xbl     = (ushort*)alloc((size_t)N * 128 * 2);
    ushort* W1th = (ushort*)alloc(128 * 128 * 2);
    ushort* W2th = (ushort*)alloc(128 * 128 * 2);
    ushort* W3th = (ushort*)alloc(256 * 128 * 2);
    ushort* rWmh = (ushort*)alloc(64 * 128 * 2);
    float*  resmean = (float*)alloc((size_t)N * 64 * 4);

    // CSR build
    hipMemsetAsync(cursor, 0, (size_t)N * 4, stream);
    hist_kernel<<<(E + 255) / 256, 256, 0, stream>>>(dstv, cursor, E);
    int nb = (N + 1023) / 1024;
    block_scan_kernel<<<nb, 1024, 0, stream>>>(cursor, loc, bsum, N);
    scan_bsum_kernel<<<1, 64, 0, stream>>>(bsum, nb, row_ptr + N);
    apply_scan_kernel<<<(N + 255) / 256, 256, 0, stream>>>(loc, bsum, row_ptr, cursor, N);
    scatter_kernel<<<(E + 255) / 256, 256, 0, stream>>>(src, dstv, cursor, ssrc, E);

    // casts (weights transposed + swizzled, hi plane only)
    cast_split_kernel<<<(N * 128 / 4 + 255) / 256, 256, 0, stream>>>(h, xbh, xbl, N * 128 / 4);
    castT_kernel<<<(128 * 128 + 255) / 256, 256, 0, stream>>>(W1, W1th, 128);
    castT_kernel<<<(128 * 128 + 255) / 256, 256, 0, stream>>>(W2, W2th, 128);
    castT_kernel<<<(128 * 256 + 255) / 256, 256, 0, stream>>>(W3, W3th, 256);
    fold_resW_kernel<<<(64 * 128 + 255) / 256, 256, 0, stream>>>(rW3, rWmh);

    const int gx = (N + 127) / 128;
    dim3 g1(gx, 2);
    dim3 g3(gx, 4);
    dim3 gr(gx, 1);
    int agg_grid = (N + 3) / 4;

    // layer 1
    gemm_kernel<<<g1, 256, 0, stream>>>(xbh, W1th, featb, nullptr,
                                        al1, ar1, el, er, N, 128, 5);
    aggregate12_kernel<<<agg_grid, 256, 0, stream>>>(featb, el, er, row_ptr, ssrc, xbh, xbl, N);

    // layer 2
    gemm_kernel<<<g1, 256, 0, stream>>>(xbh, W2th, featb, nullptr,
                                        al2, ar2, el, er, N, 128, 5);
    aggregate12_kernel<<<agg_grid, 256, 0, stream>>>(featb, el, er, row_ptr, ssrc, xbh, xbl, N);

    // layer 3
    gemm_kernel<<<g3, 256, 0, stream>>>(xbh, W3th, featb, nullptr,
                                        al3, ar3, el, er, N, 256, 6);
    gemm_kernel<<<gr, 256, 0, stream>>>(xbh, rWmh, nullptr, resmean,
                                        nullptr, nullptr, nullptr, nullptr, N, 64, 6);
    aggregate3_kernel<<<agg_grid, 256, 0, stream>>>(featb, el, er, row_ptr, ssrc, resmean, out, N);
}

// Round 9
// 401.724 us; speedup vs baseline: 2.5651x; 1.0414x over previous
//
#include <hip/hip_runtime.h>
#include <hip/hip_bf16.h>
#include <math.h>

// ---------------------------------------------------------------------------
// GAT 3-layer forward. N=50000 nodes, E=800000 edges, H=4 heads.
// GEMMs: bf16 MFMA (hi plane; error dominated by bf16 feature gathers),
// W staged in dynamic LDS (swizzled), el/er fused into epilogue; layer-3
// residual GEMM fused into the L3 GEMM (blockIdx.y==0 blocks, 2nd LDS slice).
// All prep casts fused into one range-partitioned kernel.
// Aggregation: one wave per dst node, exp(leaky()) inline (max-subtraction
// cancels in alpha), 8x-unrolled gathers; layer-1 residual read from fp32 h.
// ---------------------------------------------------------------------------

#define NEG_SLOPE 0.2f

typedef __attribute__((ext_vector_type(8))) __bf16 bf16x8;
typedef __attribute__((ext_vector_type(4))) float f32x4;

__device__ __forceinline__ float leaky(float x) { return fmaxf(x, NEG_SLOPE * x); }
__device__ __forceinline__ ushort f2bf(float f) {
    unsigned u = __float_as_uint(f);
    return (ushort)((u + 0x7fffu + ((u >> 16) & 1u)) >> 16);
}
__device__ __forceinline__ float bf2f(ushort b) { return __uint_as_float(((unsigned)b) << 16); }
__device__ __forceinline__ float lo16f(unsigned v) { return __uint_as_float(v << 16); }
__device__ __forceinline__ float hi16f(unsigned v) { return __uint_as_float(v & 0xffff0000u); }

// ------------------------- CSR build (per dst) ------------------------------

__global__ void hist_kernel(const int* __restrict__ dst, int* __restrict__ deg, int E) {
    int i = blockIdx.x * blockDim.x + threadIdx.x;
    if (i < E) atomicAdd(&deg[dst[i]], 1);
}

__global__ void block_scan_kernel(const int* __restrict__ deg, int* __restrict__ loc,
                                  int* __restrict__ bsum, int n) {
    __shared__ int sm[1024];
    const int tid = threadIdx.x;
    const int i = blockIdx.x * 1024 + tid;
    int v = (i < n) ? deg[i] : 0;
    sm[tid] = v;
    __syncthreads();
    for (int off = 1; off < 1024; off <<= 1) {
        int t = (tid >= off) ? sm[tid - off] : 0;
        __syncthreads();
        sm[tid] += t;
        __syncthreads();
    }
    if (i < n) loc[i] = sm[tid] - v;
    if (tid == 1023) bsum[blockIdx.x] = sm[1023];
}

__global__ void scan_bsum_kernel(int* __restrict__ bsum, int nb, int* __restrict__ total_out) {
    const int lane = threadIdx.x;
    int v = (lane < nb) ? bsum[lane] : 0;
    int orig = v;
    for (int off = 1; off < 64; off <<= 1) {
        int t = __shfl_up(v, off);
        if (lane >= off) v += t;
    }
    if (lane < nb) bsum[lane] = v - orig;
    if (lane == 63) *total_out = v;
}

__global__ void apply_scan_kernel(const int* __restrict__ loc, const int* __restrict__ bsum,
                                  int* __restrict__ row_ptr, int* __restrict__ cursor, int n) {
    int i = blockIdx.x * blockDim.x + threadIdx.x;
    if (i < n) {
        int v = loc[i] + bsum[i >> 10];
        row_ptr[i] = v;
        cursor[i]  = v;
    }
}

__global__ void scatter_kernel(const int* __restrict__ src, const int* __restrict__ dst,
                               int* __restrict__ cursor, int* __restrict__ ssrc, int E) {
    int i = blockIdx.x * blockDim.x + threadIdx.x;
    if (i < E) {
        int s = src[i];
        int pos = atomicAdd(&cursor[dst[i]], 1);
        ssrc[pos] = s;
    }
}

// ----------------------------- fused prep ------------------------------------
// Range-partitioned: [0, N*32)           : h fp32 -> xbh (bf16 hi, float4 grp)
//                    [+0, +16384)        : W1 castT (Ncols=128)
//                    [+16384, +32768)    : W2 castT (Ncols=128)
//                    [+32768, +65536)    : W3 castT (Ncols=256)
//                    [+65536, +73728)    : rWm fold (0.25*sum_h resW3)
// All weight outputs are [col][k] with k XOR-swizzled (k ^ ((c&7)<<3)).

__global__ void prep_kernel(const float* __restrict__ h, ushort* __restrict__ xbh,
                            const float* __restrict__ W1, ushort* __restrict__ W1th,
                            const float* __restrict__ W2, ushort* __restrict__ W2th,
                            const float* __restrict__ W3, ushort* __restrict__ W3th,
                            const float* __restrict__ rW3, ushort* __restrict__ rWmh,
                            int nh4) {
    int i = blockIdx.x * blockDim.x + threadIdx.x;
    if (i < nh4) {
        float4 v = ((const float4*)h)[i];
        ushort4 o;
        o.x = f2bf(v.x); o.y = f2bf(v.y); o.z = f2bf(v.z); o.w = f2bf(v.w);
        ((ushort4*)xbh)[i] = o;
        return;
    }
    int j = i - nh4;
    if (j < 16384) {                      // W1
        int c = j >> 7, k = j & 127;
        int kd = k ^ ((c & 7) << 3);
        W1th[c * 128 + kd] = f2bf(W1[k * 128 + c]);
    } else if (j < 32768) {               // W2
        j -= 16384;
        int c = j >> 7, k = j & 127;
        int kd = k ^ ((c & 7) << 3);
        W2th[c * 128 + kd] = f2bf(W2[k * 128 + c]);
    } else if (j < 65536) {               // W3
        j -= 32768;
        int c = j >> 7, k = j & 127;
        int kd = k ^ ((c & 7) << 3);
        W3th[c * 128 + kd] = f2bf(W3[k * 256 + c]);
    } else if (j < 73728) {               // rWm fold
        j -= 65536;
        int c = j >> 7, k = j & 127;
        const float* row = rW3 + (size_t)k * 256;
        float v = 0.25f * ((row[c] + row[64 + c]) + (row[128 + c] + row[192 + c]));
        int kd = k ^ ((c & 7) << 3);
        rWmh[c * 128 + kd] = f2bf(v);
    }
}

// ------------------------------- GEMM ---------------------------------------
// C[M,Ncols] = X[M,128] @ W; X hi-plane bf16, W transposed+swizzled bf16.
// Block = 4 waves, tile 128(M) x 64(N); wave = 32(M) x 64(N); K=128 in regs.
// Dynamic LDS: W slice 16KB; +16KB rWm slice when B2th!=null && blockIdx.y==0
// (fused layer-3 residual projection -> fp32 C2f[M][64]).

__global__ void __launch_bounds__(256)
gemm_kernel(const ushort* __restrict__ Ah, const ushort* __restrict__ Bth,
            const ushort* __restrict__ B2th,
            ushort* __restrict__ Cb, float* __restrict__ C2f,
            const float* __restrict__ alv, const float* __restrict__ arv,
            float* __restrict__ el, float* __restrict__ er,
            int M, int Ncols, int dshift) {
    extern __shared__ ushort Ws[];            // [64*128] (+ [64*128] when do2)
    ushort* Ws2 = Ws + 64 * 128;
    const int tid = threadIdx.x;
    const int wv = tid >> 6;
    const int lane = tid & 63;
    const int l15 = lane & 15;
    const int g = lane >> 4;
    const int bm = blockIdx.x * 128 + wv * 32;
    const int bn = blockIdx.y * 64;
    const bool do2 = (B2th != nullptr) && (blockIdx.y == 0);

    // stage W slice: 1024 uint4, 256 threads x 4 iterations
    {
        const uint4* gh = (const uint4*)(Bth + (size_t)bn * 128);
        uint4* sh = (uint4*)Ws;
#pragma unroll
        for (int it = 0; it < 4; ++it) sh[it * 256 + tid] = gh[it * 256 + tid];
        if (do2) {
            const uint4* g2 = (const uint4*)B2th;
            uint4* s2 = (uint4*)Ws2;
#pragma unroll
            for (int it = 0; it < 4; ++it) s2[it * 256 + tid] = g2[it * 256 + tid];
        }
    }
    __syncthreads();

    // X fragments: 2 m-frags per wave
    const int m0 = bm + l15;
    const int m1 = bm + 16 + l15;
    const int mc0 = (m0 < M) ? m0 : (M - 1);
    const int mc1 = (m1 < M) ? m1 : (M - 1);
    bf16x8 xh[2][4];
#pragma unroll
    for (int kk = 0; kk < 4; ++kk) {
        xh[0][kk] = *(const bf16x8*)(Ah + (size_t)mc0 * 128 + kk * 32 + g * 8);
        xh[1][kk] = *(const bf16x8*)(Ah + (size_t)mc1 * 128 + kk * 32 + g * 8);
    }

    f32x4 acc[2][4] = {};
    f32x4 acc2[2][4] = {};
    const int swz = (l15 & 7) << 4;
#pragma unroll
    for (int n = 0; n < 4; ++n) {
        const int colb = (n * 16 + l15) * 256;
#pragma unroll
        for (int kk = 0; kk < 4; ++kk) {
            const int boff = colb + ((kk * 64 + g * 16) ^ swz);
            bf16x8 wh = *(const bf16x8*)((const char*)Ws + boff);
            acc[0][n] = __builtin_amdgcn_mfma_f32_16x16x32_bf16(wh, xh[0][kk], acc[0][n], 0, 0, 0);
            acc[1][n] = __builtin_amdgcn_mfma_f32_16x16x32_bf16(wh, xh[1][kk], acc[1][n], 0, 0, 0);
            if (do2) {
                bf16x8 w2 = *(const bf16x8*)((const char*)Ws2 + boff);
                acc2[0][n] = __builtin_amdgcn_mfma_f32_16x16x32_bf16(w2, xh[0][kk], acc2[0][n], 0, 0, 0);
                acc2[1][n] = __builtin_amdgcn_mfma_f32_16x16x32_bf16(w2, xh[1][kk], acc2[1][n], 0, 0, 0);
            }
        }
    }

#pragma unroll
    for (int mf = 0; mf < 2; ++mf) {
        const int m = (mf == 0) ? m0 : m1;
        const bool valid = (m < M);
        if (valid) {
            size_t ro = (size_t)m * Ncols;
#pragma unroll
            for (int n = 0; n < 4; ++n) {
                int col = bn + n * 16 + g * 4;
                ushort4 o;
                o.x = f2bf(acc[mf][n][0]); o.y = f2bf(acc[mf][n][1]);
                o.z = f2bf(acc[mf][n][2]); o.w = f2bf(acc[mf][n][3]);
                *(ushort4*)&Cb[ro + col] = o;
                if (do2) {
                    *(float4*)&C2f[(size_t)m * 64 + n * 16 + g * 4] =
                        make_float4(acc2[mf][n][0], acc2[mf][n][1],
                                    acc2[mf][n][2], acc2[mf][n][3]);
                }
            }
        }
        if (alv) {
            float e0 = 0.f, e1 = 0.f, r0 = 0.f, r1 = 0.f;
#pragma unroll
            for (int n = 0; n < 4; ++n) {
#pragma unroll
                for (int r = 0; r < 4; ++r) {
                    int col = n * 16 + g * 4 + r;
                    float c = acc[mf][n][r];
                    float av = alv[bn + col];
                    float bv = arv[bn + col];
                    if ((col >> dshift) == 0) { e0 += c * av; r0 += c * bv; }
                    else                      { e1 += c * av; r1 += c * bv; }
                }
            }
            e0 += __shfl_xor(e0, 16); e0 += __shfl_xor(e0, 32);
            e1 += __shfl_xor(e1, 16); e1 += __shfl_xor(e1, 32);
            r0 += __shfl_xor(r0, 16); r0 += __shfl_xor(r0, 32);
            r1 += __shfl_xor(r1, 16); r1 += __shfl_xor(r1, 32);
            if (valid && g == 0) {
                int h0 = bn >> dshift;
                el[m * 4 + h0] = e0;
                er[m * 4 + h0] = r0;
                if (dshift == 5) {
                    el[m * 4 + h0 + 1] = e1;
                    er[m * 4 + h0 + 1] = r1;
                }
            }
        }
    }
}

// --------------------------- aggregation -------------------------------------
// Layers 1/2: C=128, lane owns 2 elems, head hh=lane>>4; 8x-unrolled gathers.
// Residual: fp32 resf (layer 1, reads h) OR bf16 hi+lo planes (layer 2).

__global__ void __launch_bounds__(256)
aggregate12_kernel(const ushort* __restrict__ featb, const float* __restrict__ el,
                   const float* __restrict__ er, const int* __restrict__ row_ptr,
                   const int* __restrict__ ssrc, const float* __restrict__ resf,
                   const ushort* __restrict__ rxh, const ushort* __restrict__ rxl,
                   ushort* __restrict__ xbh, ushort* __restrict__ xbl, int n) {
    const int wid = threadIdx.x >> 6;
    const int lane = threadIdx.x & 63;
    const int node = blockIdx.x * 4 + wid;
    if (node >= n) return;
    const int beg = row_ptr[node];
    const int end = row_ptr[node + 1];
    const int hh = lane >> 4;
    const float erh = er[node * 4 + hh];

    float ssum = 0.f, a0 = 0.f, a1 = 0.f;
    int p = beg;
    for (; p + 8 <= end; p += 8) {
        int s[8];
        float e[8];
        unsigned v[8];
#pragma unroll
        for (int j = 0; j < 8; ++j) s[j] = __builtin_amdgcn_readfirstlane(ssrc[p + j]);
#pragma unroll
        for (int j = 0; j < 8; ++j) v[j] = *(const unsigned*)&featb[(size_t)s[j] * 128 + lane * 2];
#pragma unroll
        for (int j = 0; j < 8; ++j) e[j] = el[s[j] * 4 + hh];
#pragma unroll
        for (int j = 0; j < 8; ++j) {
            float w0 = __expf(leaky(e[j] + erh));
            ssum += w0;
            a0 += w0 * lo16f(v[j]);
            a1 += w0 * hi16f(v[j]);
        }
    }
    for (; p < end; ++p) {
        int s = __builtin_amdgcn_readfirstlane(ssrc[p]);
        float w0 = __expf(leaky(el[s * 4 + hh] + erh));
        unsigned v = *(const unsigned*)&featb[(size_t)s * 128 + lane * 2];
        ssum += w0;
        a0 += w0 * lo16f(v);
        a1 += w0 * hi16f(v);
    }
    float inv = (end > beg) ? 1.f / ssum : 0.f;
    size_t o = (size_t)node * 128 + lane * 2;
    float rb0, rb1;
    if (resf) {
        float2 f = *(const float2*)&resf[o];
        rb0 = f.x; rb1 = f.y;
    } else {
        unsigned rh = *(const unsigned*)&rxh[o];
        unsigned rl = *(const unsigned*)&rxl[o];
        rb0 = lo16f(rh) + lo16f(rl);
        rb1 = hi16f(rh) + hi16f(rl);
    }
    float r0 = fmaxf(a0 * inv + rb0, 0.f);
    float r1 = fmaxf(a1 * inv + rb1, 0.f);
    ushort h0 = f2bf(r0), h1 = f2bf(r1);
    ushort l0 = f2bf(r0 - bf2f(h0)), l1 = f2bf(r1 - bf2f(h1));
    *(unsigned*)&xbh[o] = (unsigned)h0 | ((unsigned)h1 << 16);
    *(unsigned*)&xbl[o] = (unsigned)l0 | ((unsigned)l1 << 16);
}

// Layer 3: C=256 (H=4, D=64). Head-mean via shfl_xor; + resmean (pre-folded).

__global__ void __launch_bounds__(256)
aggregate3_kernel(const ushort* __restrict__ featb, const float* __restrict__ el,
                  const float* __restrict__ er, const int* __restrict__ row_ptr,
                  const int* __restrict__ ssrc, const float* __restrict__ resmean,
                  float* __restrict__ out, int n) {
    const int wid = threadIdx.x >> 6;
    const int lane = threadIdx.x & 63;
    const int node = blockIdx.x * 4 + wid;
    if (node >= n) return;
    const int beg = row_ptr[node];
    const int end = row_ptr[node + 1];
    const int hh = lane >> 4;
    const int dd = (lane & 15) * 4;
    const int off = hh * 64 + dd;
    const float erh = er[node * 4 + hh];

    float c0 = 0.f, c1 = 0.f, c2 = 0.f, c3 = 0.f, ssum = 0.f;
    int p = beg;
    for (; p + 8 <= end; p += 8) {
        int s[8];
        float e[8];
        uint2 v[8];
#pragma unroll
        for (int j = 0; j < 8; ++j) s[j] = __builtin_amdgcn_readfirstlane(ssrc[p + j]);
#pragma unroll
        for (int j = 0; j < 8; ++j) v[j] = *(const uint2*)&featb[(size_t)s[j] * 256 + off];
#pragma unroll
        for (int j = 0; j < 8; ++j) e[j] = el[s[j] * 4 + hh];
#pragma unroll
        for (int j = 0; j < 8; ++j) {
            float w0 = __expf(leaky(e[j] + erh));
            ssum += w0;
            c0 += w0 * lo16f(v[j].x);
            c1 += w0 * hi16f(v[j].x);
            c2 += w0 * lo16f(v[j].y);
            c3 += w0 * hi16f(v[j].y);
        }
    }
    for (; p < end; ++p) {
        int s = __builtin_amdgcn_readfirstlane(ssrc[p]);
        float w0 = __expf(leaky(el[s * 4 + hh] + erh));
        uint2 v = *(const uint2*)&featb[(size_t)s * 256 + off];
        ssum += w0;
        c0 += w0 * lo16f(v.x);
        c1 += w0 * hi16f(v.x);
        c2 += w0 * lo16f(v.y);
        c3 += w0 * hi16f(v.y);
    }
    float inv = (end > beg) ? 1.f / ssum : 0.f;
    float r0 = c0 * inv, r1 = c1 * inv, r2 = c2 * inv, r3 = c3 * inv;
    r0 += __shfl_xor(r0, 16); r0 += __shfl_xor(r0, 32);
    r1 += __shfl_xor(r1, 16); r1 += __shfl_xor(r1, 32);
    r2 += __shfl_xor(r2, 16); r2 += __shfl_xor(r2, 32);
    r3 += __shfl_xor(r3, 16); r3 += __shfl_xor(r3, 32);
    if (hh == 0) {
        float4 rm = *(const float4*)&resmean[(size_t)node * 64 + dd];
        *(float4*)&out[(size_t)node * 64 + dd] =
            make_float4(0.25f * r0 + rm.x, 0.25f * r1 + rm.y,
                        0.25f * r2 + rm.z, 0.25f * r3 + rm.w);
    }
}

// ------------------------------ launch ---------------------------------------

extern "C" void kernel_launch(void* const* d_in, const int* in_sizes, int n_in,
                              void* d_out, int out_size, void* d_ws, size_t ws_size,
                              hipStream_t stream) {
    const float* h   = (const float*)d_in[0];
    const float* W1  = (const float*)d_in[1];
    const float* al1 = (const float*)d_in[2];
    const float* ar1 = (const float*)d_in[3];
    const float* W2  = (const float*)d_in[4];
    const float* al2 = (const float*)d_in[5];
    const float* ar2 = (const float*)d_in[6];
    const float* W3  = (const float*)d_in[7];
    const float* al3 = (const float*)d_in[8];
    const float* ar3 = (const float*)d_in[9];
    const float* rW3 = (const float*)d_in[10];
    const int* src   = (const int*)d_in[11];
    const int* dstv  = (const int*)d_in[12];
    const int N = in_sizes[0] / 128;
    const int E = in_sizes[11];
    float* out = (float*)d_out;

    char* p = (char*)d_ws;
    auto alloc = [&](size_t bytes) -> char* {
        char* q = p;
        p += (bytes + 255) & ~(size_t)255;
        return q;
    };
    int*    row_ptr = (int*)alloc((size_t)(N + 1) * 4);
    int*    cursor  = (int*)alloc((size_t)N * 4);
    int*    loc     = (int*)alloc((size_t)N * 4);
    int*    bsum    = (int*)alloc(64 * 4);
    int*    ssrc    = (int*)alloc((size_t)E * 4);
    float*  el      = (float*)alloc((size_t)N * 16);
    float*  er      = (float*)alloc((size_t)N * 16);
    ushort* featb   = (ushort*)alloc((size_t)N * 256 * 2);
    ushort* xbh     = (ushort*)alloc((size_t)N * 128 * 2);
    ushort* xbl     = (ushort*)alloc((size_t)N * 128 * 2);
    ushort* W1th = (ushort*)alloc(128 * 128 * 2);
    ushort* W2th = (ushort*)alloc(128 * 128 * 2);
    ushort* W3th = (ushort*)alloc(256 * 128 * 2);
    ushort* rWmh = (ushort*)alloc(64 * 128 * 2);
    float*  resmean = (float*)alloc((size_t)N * 64 * 4);

    // CSR build
    hipMemsetAsync(cursor, 0, (size_t)N * 4, stream);
    hist_kernel<<<(E + 255) / 256, 256, 0, stream>>>(dstv, cursor, E);
    int nb = (N + 1023) / 1024;
    block_scan_kernel<<<nb, 1024, 0, stream>>>(cursor, loc, bsum, N);
    scan_bsum_kernel<<<1, 64, 0, stream>>>(bsum, nb, row_ptr + N);
    apply_scan_kernel<<<(N + 255) / 256, 256, 0, stream>>>(loc, bsum, row_ptr, cursor, N);
    scatter_kernel<<<(E + 255) / 256, 256, 0, stream>>>(src, dstv, cursor, ssrc, E);

    // fused prep: h hi-cast + W1/W2/W3 castT + rWm fold
    const int nh4 = N * 32;               // N*128/4 float4 groups
    prep_kernel<<<(nh4 + 73728 + 255) / 256, 256, 0, stream>>>(
        h, xbh, W1, W1th, W2, W2th, W3, W3th, rW3, rWmh, nh4);

    const int gx = (N + 127) / 128;
    dim3 g1(gx, 2);
    dim3 g3(gx, 4);
    int agg_grid = (N + 3) / 4;
    const size_t lds1 = 64 * 128 * sizeof(ushort);       // 16 KB
    const size_t lds2 = 2 * 64 * 128 * sizeof(ushort);   // 32 KB

    // layer 1 (residual from fp32 h)
    gemm_kernel<<<g1, 256, lds1, stream>>>(xbh, W1th, nullptr, featb, nullptr,
                                           al1, ar1, el, er, N, 128, 5);
    aggregate12_kernel<<<agg_grid, 256, 0, stream>>>(featb, el, er, row_ptr, ssrc,
                                                     h, nullptr, nullptr, xbh, xbl, N);

    // layer 2 (residual from hi+lo planes)
    gemm_kernel<<<g1, 256, lds1, stream>>>(xbh, W2th, nullptr, featb, nullptr,
                                           al2, ar2, el, er, N, 128, 5);
    aggregate12_kernel<<<agg_grid, 256, 0, stream>>>(featb, el, er, row_ptr, ssrc,
                                                     nullptr, xbh, xbl, xbh, xbl, N);

    // layer 3 (residual projection fused into blockIdx.y==0 blocks)
    gemm_kernel<<<g3, 256, lds2, stream>>>(xbh, W3th, rWmh, featb, resmean,
                                           al3, ar3, el, er, N, 256, 6);
    aggregate3_kernel<<<agg_grid, 256, 0, stream>>>(featb, el, er, row_ptr, ssrc, resmean, out, N);
}

// Round 10
// 395.271 us; speedup vs baseline: 2.6070x; 1.0163x over previous
//
#include <hip/hip_runtime.h>
#include <hip/hip_bf16.h>
#include <math.h>

// ---------------------------------------------------------------------------
// GAT 3-layer forward. N=50000 nodes, E=800000 edges, H=4 heads.
// GEMMs: bf16 MFMA (hi plane), full 128-col W slice staged in dynamic LDS
// (swizzled), wave tile 32Mx128N, el/er fused into epilogue; layer-3 residual
// GEMM fused (blockIdx.y==0 stages rWm in a 2nd LDS slice).
// Aggregation: one wave per dst node, exp(leaky()) inline (max-subtraction
// cancels in alpha), 8x-unrolled gathers. agg3 measured at ~6.7 TB/s
// effective — memory-system roofline for the gather pattern.
// ---------------------------------------------------------------------------

#define NEG_SLOPE 0.2f

typedef __attribute__((ext_vector_type(8))) __bf16 bf16x8;
typedef __attribute__((ext_vector_type(4))) float f32x4;

__device__ __forceinline__ float leaky(float x) { return fmaxf(x, NEG_SLOPE * x); }
__device__ __forceinline__ ushort f2bf(float f) {
    unsigned u = __float_as_uint(f);
    return (ushort)((u + 0x7fffu + ((u >> 16) & 1u)) >> 16);
}
__device__ __forceinline__ float bf2f(ushort b) { return __uint_as_float(((unsigned)b) << 16); }
__device__ __forceinline__ float lo16f(unsigned v) { return __uint_as_float(v << 16); }
__device__ __forceinline__ float hi16f(unsigned v) { return __uint_as_float(v & 0xffff0000u); }

// ------------------------- CSR build (per dst) ------------------------------

__global__ void hist_kernel(const int* __restrict__ dst, int* __restrict__ deg, int E) {
    int i = blockIdx.x * blockDim.x + threadIdx.x;
    if (i < E) atomicAdd(&deg[dst[i]], 1);
}

__global__ void block_scan_kernel(const int* __restrict__ deg, int* __restrict__ loc,
                                  int* __restrict__ bsum, int n) {
    __shared__ int sm[1024];
    const int tid = threadIdx.x;
    const int i = blockIdx.x * 1024 + tid;
    int v = (i < n) ? deg[i] : 0;
    sm[tid] = v;
    __syncthreads();
    for (int off = 1; off < 1024; off <<= 1) {
        int t = (tid >= off) ? sm[tid - off] : 0;
        __syncthreads();
        sm[tid] += t;
        __syncthreads();
    }
    if (i < n) loc[i] = sm[tid] - v;
    if (tid == 1023) bsum[blockIdx.x] = sm[1023];
}

// apply + inline wave-scan of <=64 block sums (block 0 also writes total)
__global__ void apply_scan_kernel(const int* __restrict__ loc, const int* __restrict__ bsum,
                                  int* __restrict__ row_ptr, int* __restrict__ cursor,
                                  int n, int nb) {
    __shared__ int pb[64];
    const int tid = threadIdx.x;
    if (tid < 64) {
        int v = (tid < nb) ? bsum[tid] : 0;
        int orig = v;
        for (int off = 1; off < 64; off <<= 1) {
            int t = __shfl_up(v, off);
            if (tid >= off) v += t;
        }
        pb[tid] = v - orig;
        if (tid == 63 && blockIdx.x == 0) row_ptr[n] = v;
    }
    __syncthreads();
    int i = blockIdx.x * blockDim.x + tid;
    if (i < n) {
        int v = loc[i] + pb[i >> 10];
        row_ptr[i] = v;
        cursor[i]  = v;
    }
}

__global__ void scatter_kernel(const int* __restrict__ src, const int* __restrict__ dst,
                               int* __restrict__ cursor, int* __restrict__ ssrc, int E) {
    int i = blockIdx.x * blockDim.x + threadIdx.x;
    if (i < E) {
        int s = src[i];
        int pos = atomicAdd(&cursor[dst[i]], 1);
        ssrc[pos] = s;
    }
}

// ----------------------------- fused prep ------------------------------------
// Range-partitioned: h cast | W1/W2/W3 castT | rWm fold | cursor zero.
// Weight outputs are [col][k] with k XOR-swizzled (k ^ ((c&7)<<3)).

__global__ void prep_kernel(const float* __restrict__ h, ushort* __restrict__ xbh,
                            const float* __restrict__ W1, ushort* __restrict__ W1th,
                            const float* __restrict__ W2, ushort* __restrict__ W2th,
                            const float* __restrict__ W3, ushort* __restrict__ W3th,
                            const float* __restrict__ rW3, ushort* __restrict__ rWmh,
                            int* __restrict__ cursor, int nh4, int n) {
    int i = blockIdx.x * blockDim.x + threadIdx.x;
    if (i < nh4) {
        float4 v = ((const float4*)h)[i];
        ushort4 o;
        o.x = f2bf(v.x); o.y = f2bf(v.y); o.z = f2bf(v.z); o.w = f2bf(v.w);
        ((ushort4*)xbh)[i] = o;
        return;
    }
    int j = i - nh4;
    if (j < 16384) {                      // W1
        int c = j >> 7, k = j & 127;
        int kd = k ^ ((c & 7) << 3);
        W1th[c * 128 + kd] = f2bf(W1[k * 128 + c]);
    } else if (j < 32768) {               // W2
        j -= 16384;
        int c = j >> 7, k = j & 127;
        int kd = k ^ ((c & 7) << 3);
        W2th[c * 128 + kd] = f2bf(W2[k * 128 + c]);
    } else if (j < 65536) {               // W3
        j -= 32768;
        int c = j >> 7, k = j & 127;
        int kd = k ^ ((c & 7) << 3);
        W3th[c * 128 + kd] = f2bf(W3[k * 256 + c]);
    } else if (j < 73728) {               // rWm fold
        j -= 65536;
        int c = j >> 7, k = j & 127;
        const float* row = rW3 + (size_t)k * 256;
        float v = 0.25f * ((row[c] + row[64 + c]) + (row[128 + c] + row[192 + c]));
        int kd = k ^ ((c & 7) << 3);
        rWmh[c * 128 + kd] = f2bf(v);
    } else if (j < 73728 + n) {           // cursor zero
        cursor[j - 73728] = 0;
    }
}

// ------------------------------- GEMM ---------------------------------------
// C[M,Ncols] = X[M,128] @ W; X hi-plane bf16, W transposed+swizzled bf16.
// Block = 2 waves (128 thr), tile 64(M) x 128(N); wave = 32(M) x 128(N).
// W slice 128colsx128k = 32KB staged in dynamic LDS; blockIdx.y==0 of layer 3
// also stages rWm (16KB) and emits resmean. Epilogue: bf16 C + fused el/er.

__global__ void __launch_bounds__(128)
gemm_kernel(const ushort* __restrict__ Ah, const ushort* __restrict__ Bth,
            const ushort* __restrict__ B2th,
            ushort* __restrict__ Cb, float* __restrict__ C2f,
            const float* __restrict__ alv, const float* __restrict__ arv,
            float* __restrict__ el, float* __restrict__ er,
            int M, int Ncols, int dshift) {
    extern __shared__ ushort Ws[];            // [128*128] (+ [64*128] when do2)
    ushort* Ws2 = Ws + 128 * 128;
    const int tid = threadIdx.x;
    const int wv = tid >> 6;
    const int lane = tid & 63;
    const int l15 = lane & 15;
    const int g = lane >> 4;
    const int bm = blockIdx.x * 64 + wv * 32;
    const int bn = blockIdx.y * 128;
    const bool do2 = (B2th != nullptr) && (blockIdx.y == 0);

    // stage W slice: 2048 uint4, 128 threads x 16 iterations
    {
        const uint4* gh = (const uint4*)(Bth + (size_t)bn * 128);
        uint4* sh = (uint4*)Ws;
#pragma unroll
        for (int it = 0; it < 16; ++it) sh[it * 128 + tid] = gh[it * 128 + tid];
        if (do2) {
            const uint4* g2 = (const uint4*)B2th;
            uint4* s2 = (uint4*)Ws2;
#pragma unroll
            for (int it = 0; it < 8; ++it) s2[it * 128 + tid] = g2[it * 128 + tid];
        }
    }
    __syncthreads();

    // X fragments: 2 m-frags per wave
    const int m0 = bm + l15;
    const int m1 = bm + 16 + l15;
    const int mc0 = (m0 < M) ? m0 : (M - 1);
    const int mc1 = (m1 < M) ? m1 : (M - 1);
    bf16x8 xh[2][4];
#pragma unroll
    for (int kk = 0; kk < 4; ++kk) {
        xh[0][kk] = *(const bf16x8*)(Ah + (size_t)mc0 * 128 + kk * 32 + g * 8);
        xh[1][kk] = *(const bf16x8*)(Ah + (size_t)mc1 * 128 + kk * 32 + g * 8);
    }

    f32x4 acc[2][8] = {};
    f32x4 acc2[2][4] = {};
    const int swz = (l15 & 7) << 4;
#pragma unroll
    for (int n = 0; n < 8; ++n) {
        const int colb = (n * 16 + l15) * 256;
#pragma unroll
        for (int kk = 0; kk < 4; ++kk) {
            const int boff = colb + ((kk * 64 + g * 16) ^ swz);
            bf16x8 wh = *(const bf16x8*)((const char*)Ws + boff);
            acc[0][n] = __builtin_amdgcn_mfma_f32_16x16x32_bf16(wh, xh[0][kk], acc[0][n], 0, 0, 0);
            acc[1][n] = __builtin_amdgcn_mfma_f32_16x16x32_bf16(wh, xh[1][kk], acc[1][n], 0, 0, 0);
        }
    }
    if (do2) {
#pragma unroll
        for (int n = 0; n < 4; ++n) {
            const int colb = (n * 16 + l15) * 256;
#pragma unroll
            for (int kk = 0; kk < 4; ++kk) {
                const int boff = colb + ((kk * 64 + g * 16) ^ swz);
                bf16x8 w2 = *(const bf16x8*)((const char*)Ws2 + boff);
                acc2[0][n] = __builtin_amdgcn_mfma_f32_16x16x32_bf16(w2, xh[0][kk], acc2[0][n], 0, 0, 0);
                acc2[1][n] = __builtin_amdgcn_mfma_f32_16x16x32_bf16(w2, xh[1][kk], acc2[1][n], 0, 0, 0);
            }
        }
    }

#pragma unroll
    for (int mf = 0; mf < 2; ++mf) {
        const int m = (mf == 0) ? m0 : m1;
        const bool valid = (m < M);
        if (valid) {
            size_t ro = (size_t)m * Ncols;
#pragma unroll
            for (int n = 0; n < 8; ++n) {
                int col = bn + n * 16 + g * 4;
                ushort4 o;
                o.x = f2bf(acc[mf][n][0]); o.y = f2bf(acc[mf][n][1]);
                o.z = f2bf(acc[mf][n][2]); o.w = f2bf(acc[mf][n][3]);
                *(ushort4*)&Cb[ro + col] = o;
            }
            if (do2) {
#pragma unroll
                for (int n = 0; n < 4; ++n) {
                    *(float4*)&C2f[(size_t)m * 64 + n * 16 + g * 4] =
                        make_float4(acc2[mf][n][0], acc2[mf][n][1],
                                    acc2[mf][n][2], acc2[mf][n][3]);
                }
            }
        }
        if (alv) {
            float e0 = 0.f, e1 = 0.f, e2 = 0.f, e3 = 0.f;
            float r0 = 0.f, r1 = 0.f, r2 = 0.f, r3 = 0.f;
            const bool four = (dshift == 5);
#pragma unroll
            for (int n = 0; n < 8; ++n) {
                float se = 0.f, sr = 0.f;
#pragma unroll
                for (int rr = 0; rr < 4; ++rr) {
                    int col = bn + n * 16 + g * 4 + rr;
                    float c = acc[mf][n][rr];
                    se += c * alv[col];
                    sr += c * arv[col];
                }
                if (four) {
                    if (n < 2)      { e0 += se; r0 += sr; }
                    else if (n < 4) { e1 += se; r1 += sr; }
                    else if (n < 6) { e2 += se; r2 += sr; }
                    else            { e3 += se; r3 += sr; }
                } else {
                    if (n < 4)      { e0 += se; r0 += sr; }
                    else            { e1 += se; r1 += sr; }
                }
            }
            e0 += __shfl_xor(e0, 16); e0 += __shfl_xor(e0, 32);
            e1 += __shfl_xor(e1, 16); e1 += __shfl_xor(e1, 32);
            r0 += __shfl_xor(r0, 16); r0 += __shfl_xor(r0, 32);
            r1 += __shfl_xor(r1, 16); r1 += __shfl_xor(r1, 32);
            if (four) {
                e2 += __shfl_xor(e2, 16); e2 += __shfl_xor(e2, 32);
                e3 += __shfl_xor(e3, 16); e3 += __shfl_xor(e3, 32);
                r2 += __shfl_xor(r2, 16); r2 += __shfl_xor(r2, 32);
                r3 += __shfl_xor(r3, 16); r3 += __shfl_xor(r3, 32);
            }
            if (valid && g == 0) {
                if (four) {
                    el[m * 4 + 0] = e0; el[m * 4 + 1] = e1;
                    el[m * 4 + 2] = e2; el[m * 4 + 3] = e3;
                    er[m * 4 + 0] = r0; er[m * 4 + 1] = r1;
                    er[m * 4 + 2] = r2; er[m * 4 + 3] = r3;
                } else {
                    int h0 = bn >> 6;
                    el[m * 4 + h0] = e0; el[m * 4 + h0 + 1] = e1;
                    er[m * 4 + h0] = r0; er[m * 4 + h0 + 1] = r1;
                }
            }
        }
    }
}

// --------------------------- aggregation -------------------------------------
// Layers 1/2: C=128, lane owns 2 elems, head hh=lane>>4; 8x-unrolled gathers.
// Residual: fp32 resf (layer 1, reads h) OR bf16 hi+lo planes (layer 2).

__global__ void __launch_bounds__(256)
aggregate12_kernel(const ushort* __restrict__ featb, const float* __restrict__ el,
                   const float* __restrict__ er, const int* __restrict__ row_ptr,
                   const int* __restrict__ ssrc, const float* __restrict__ resf,
                   const ushort* __restrict__ rxh, const ushort* __restrict__ rxl,
                   ushort* __restrict__ xbh, ushort* __restrict__ xbl, int n) {
    const int wid = threadIdx.x >> 6;
    const int lane = threadIdx.x & 63;
    const int node = blockIdx.x * 4 + wid;
    if (node >= n) return;
    const int beg = row_ptr[node];
    const int end = row_ptr[node + 1];
    const int hh = lane >> 4;
    const float erh = er[node * 4 + hh];

    float ssum = 0.f, a0 = 0.f, a1 = 0.f;
    int p = beg;
    for (; p + 8 <= end; p += 8) {
        int s[8];
        float e[8];
        unsigned v[8];
#pragma unroll
        for (int j = 0; j < 8; ++j) s[j] = __builtin_amdgcn_readfirstlane(ssrc[p + j]);
#pragma unroll
        for (int j = 0; j < 8; ++j) v[j] = *(const unsigned*)&featb[(size_t)s[j] * 128 + lane * 2];
#pragma unroll
        for (int j = 0; j < 8; ++j) e[j] = el[s[j] * 4 + hh];
#pragma unroll
        for (int j = 0; j < 8; ++j) {
            float w0 = __expf(leaky(e[j] + erh));
            ssum += w0;
            a0 += w0 * lo16f(v[j]);
            a1 += w0 * hi16f(v[j]);
        }
    }
    for (; p < end; ++p) {
        int s = __builtin_amdgcn_readfirstlane(ssrc[p]);
        float w0 = __expf(leaky(el[s * 4 + hh] + erh));
        unsigned v = *(const unsigned*)&featb[(size_t)s * 128 + lane * 2];
        ssum += w0;
        a0 += w0 * lo16f(v);
        a1 += w0 * hi16f(v);
    }
    float inv = (end > beg) ? 1.f / ssum : 0.f;
    size_t o = (size_t)node * 128 + lane * 2;
    float rb0, rb1;
    if (resf) {
        float2 f = *(const float2*)&resf[o];
        rb0 = f.x; rb1 = f.y;
    } else {
        unsigned rh = *(const unsigned*)&rxh[o];
        unsigned rl = *(const unsigned*)&rxl[o];
        rb0 = lo16f(rh) + lo16f(rl);
        rb1 = hi16f(rh) + hi16f(rl);
    }
    float r0 = fmaxf(a0 * inv + rb0, 0.f);
    float r1 = fmaxf(a1 * inv + rb1, 0.f);
    ushort h0 = f2bf(r0), h1 = f2bf(r1);
    ushort l0 = f2bf(r0 - bf2f(h0)), l1 = f2bf(r1 - bf2f(h1));
    *(unsigned*)&xbh[o] = (unsigned)h0 | ((unsigned)h1 << 16);
    *(unsigned*)&xbl[o] = (unsigned)l0 | ((unsigned)l1 << 16);
}

// Layer 3: C=256 (H=4, D=64). Head-mean via shfl_xor; + resmean (pre-folded).

__global__ void __launch_bounds__(256)
aggregate3_kernel(const ushort* __restrict__ featb, const float* __restrict__ el,
                  const float* __restrict__ er, const int* __restrict__ row_ptr,
                  const int* __restrict__ ssrc, const float* __restrict__ resmean,
                  float* __restrict__ out, int n) {
    const int wid = threadIdx.x >> 6;
    const int lane = threadIdx.x & 63;
    const int node = blockIdx.x * 4 + wid;
    if (node >= n) return;
    const int beg = row_ptr[node];
    const int end = row_ptr[node + 1];
    const int hh = lane >> 4;
    const int dd = (lane & 15) * 4;
    const int off = hh * 64 + dd;
    const float erh = er[node * 4 + hh];

    float c0 = 0.f, c1 = 0.f, c2 = 0.f, c3 = 0.f, ssum = 0.f;
    int p = beg;
    for (; p + 8 <= end; p += 8) {
        int s[8];
        float e[8];
        uint2 v[8];
#pragma unroll
        for (int j = 0; j < 8; ++j) s[j] = __builtin_amdgcn_readfirstlane(ssrc[p + j]);
#pragma unroll
        for (int j = 0; j < 8; ++j) v[j] = *(const uint2*)&featb[(size_t)s[j] * 256 + off];
#pragma unroll
        for (int j = 0; j < 8; ++j) e[j] = el[s[j] * 4 + hh];
#pragma unroll
        for (int j = 0; j < 8; ++j) {
            float w0 = __expf(leaky(e[j] + erh));
            ssum += w0;
            c0 += w0 * lo16f(v[j].x);
            c1 += w0 * hi16f(v[j].x);
            c2 += w0 * lo16f(v[j].y);
            c3 += w0 * hi16f(v[j].y);
        }
    }
    for (; p < end; ++p) {
        int s = __builtin_amdgcn_readfirstlane(ssrc[p]);
        float w0 = __expf(leaky(el[s * 4 + hh] + erh));
        uint2 v = *(const uint2*)&featb[(size_t)s * 256 + off];
        ssum += w0;
        c0 += w0 * lo16f(v.x);
        c1 += w0 * hi16f(v.x);
        c2 += w0 * lo16f(v.y);
        c3 += w0 * hi16f(v.y);
    }
    float inv = (end > beg) ? 1.f / ssum : 0.f;
    float r0 = c0 * inv, r1 = c1 * inv, r2 = c2 * inv, r3 = c3 * inv;
    r0 += __shfl_xor(r0, 16); r0 += __shfl_xor(r0, 32);
    r1 += __shfl_xor(r1, 16); r1 += __shfl_xor(r1, 32);
    r2 += __shfl_xor(r2, 16); r2 += __shfl_xor(r2, 32);
    r3 += __shfl_xor(r3, 16); r3 += __shfl_xor(r3, 32);
    if (hh == 0) {
        float4 rm = *(const float4*)&resmean[(size_t)node * 64 + dd];
        *(float4*)&out[(size_t)node * 64 + dd] =
            make_float4(0.25f * r0 + rm.x, 0.25f * r1 + rm.y,
                        0.25f * r2 + rm.z, 0.25f * r3 + rm.w);
    }
}

// ------------------------------ launch ---------------------------------------

extern "C" void kernel_launch(void* const* d_in, const int* in_sizes, int n_in,
                              void* d_out, int out_size, void* d_ws, size_t ws_size,
                              hipStream_t stream) {
    const float* h   = (const float*)d_in[0];
    const float* W1  = (const float*)d_in[1];
    const float* al1 = (const float*)d_in[2];
    const float* ar1 = (const float*)d_in[3];
    const float* W2  = (const float*)d_in[4];
    const float* al2 = (const float*)d_in[5];
    const float* ar2 = (const float*)d_in[6];
    const float* W3  = (const float*)d_in[7];
    const float* al3 = (const float*)d_in[8];
    const float* ar3 = (const float*)d_in[9];
    const float* rW3 = (const float*)d_in[10];
    const int* src   = (const int*)d_in[11];
    const int* dstv  = (const int*)d_in[12];
    const int N = in_sizes[0] / 128;
    const int E = in_sizes[11];
    float* out = (float*)d_out;

    char* p = (char*)d_ws;
    auto alloc = [&](size_t bytes) -> char* {
        char* q = p;
        p += (bytes + 255) & ~(size_t)255;
        return q;
    };
    int*    row_ptr = (int*)alloc((size_t)(N + 1) * 4);
    int*    cursor  = (int*)alloc((size_t)N * 4);
    int*    loc     = (int*)alloc((size_t)N * 4);
    int*    bsum    = (int*)alloc(64 * 4);
    int*    ssrc    = (int*)alloc((size_t)E * 4);
    float*  el      = (float*)alloc((size_t)N * 16);
    float*  er      = (float*)alloc((size_t)N * 16);
    ushort* featb   = (ushort*)alloc((size_t)N * 256 * 2);
    ushort* xbh     = (ushort*)alloc((size_t)N * 128 * 2);
    ushort* xbl     = (ushort*)alloc((size_t)N * 128 * 2);
    ushort* W1th = (ushort*)alloc(128 * 128 * 2);
    ushort* W2th = (ushort*)alloc(128 * 128 * 2);
    ushort* W3th = (ushort*)alloc(256 * 128 * 2);
    ushort* rWmh = (ushort*)alloc(64 * 128 * 2);
    float*  resmean = (float*)alloc((size_t)N * 64 * 4);

    // fused prep: h hi-cast + W1/W2/W3 castT + rWm fold + cursor zero
    const int nh4 = N * 32;               // N*128/4 float4 groups
    const int prep_total = nh4 + 73728 + N;
    prep_kernel<<<(prep_total + 255) / 256, 256, 0, stream>>>(
        h, xbh, W1, W1th, W2, W2th, W3, W3th, rW3, rWmh, cursor, nh4, N);

    // CSR build
    hist_kernel<<<(E + 255) / 256, 256, 0, stream>>>(dstv, cursor, E);
    int nb = (N + 1023) / 1024;
    block_scan_kernel<<<nb, 1024, 0, stream>>>(cursor, loc, bsum, N);
    apply_scan_kernel<<<(N + 255) / 256, 256, 0, stream>>>(loc, bsum, row_ptr, cursor, N, nb);
    scatter_kernel<<<(E + 255) / 256, 256, 0, stream>>>(src, dstv, cursor, ssrc, E);

    const int gx = (N + 63) / 64;
    dim3 g1(gx, 1);
    dim3 g3(gx, 2);
    int agg_grid = (N + 3) / 4;
    const size_t lds1 = 128 * 128 * sizeof(ushort);                  // 32 KB
    const size_t lds3 = (128 * 128 + 64 * 128) * sizeof(ushort);     // 48 KB

    // layer 1 (residual from fp32 h)
    gemm_kernel<<<g1, 128, lds1, stream>>>(xbh, W1th, nullptr, featb, nullptr,
                                           al1, ar1, el, er, N, 128, 5);
    aggregate12_kernel<<<agg_grid, 256, 0, stream>>>(featb, el, er, row_ptr, ssrc,
                                                     h, nullptr, nullptr, xbh, xbl, N);

    // layer 2 (residual from hi+lo planes)
    gemm_kernel<<<g1, 128, lds1, stream>>>(xbh, W2th, nullptr, featb, nullptr,
                                           al2, ar2, el, er, N, 128, 5);
    aggregate12_kernel<<<agg_grid, 256, 0, stream>>>(featb, el, er, row_ptr, ssrc,
                                                     nullptr, xbh, xbl, xbh, xbl, N);

    // layer 3 (residual projection fused into blockIdx.y==0 blocks)
    gemm_kernel<<<g3, 128, lds3, stream>>>(xbh, W3th, rWmh, featb, resmean,
                                           al3, ar3, el, er, N, 256, 6);
    aggregate3_kernel<<<agg_grid, 256, 0, stream>>>(featb, el, er, row_ptr, ssrc, resmean, out, N);
}

// Round 12
// 390.078 us; speedup vs baseline: 2.6417x; 1.0133x over previous
//
#include <hip/hip_runtime.h>
#include <hip/hip_bf16.h>
#include <math.h>

// ---------------------------------------------------------------------------
// GAT 3-layer forward. N=50000 nodes, E=800000 edges, H=4 heads.
// GEMMs: bf16 MFMA (hi plane), full 128-col W slice staged in dynamic LDS
// (swizzled), wave tile 32Mx128N, el/er fused into epilogue; layer-3 residual
// GEMM fused (blockIdx.y==0 stages rWm in a 2nd LDS slice).
// Aggregation: one wave per dst node, split into two 32-lane halves doing
// 2 edges/step with wide per-lane gathers (uint2/uint4) — the gather path is
// address-throughput-bound, so fewer/wider requests = higher effective BW.
// exp(leaky()) inline (softmax max-subtraction cancels in alpha).
// ---------------------------------------------------------------------------

#define NEG_SLOPE 0.2f

typedef __attribute__((ext_vector_type(8))) __bf16 bf16x8;
typedef __attribute__((ext_vector_type(4))) float f32x4;

__device__ __forceinline__ float leaky(float x) { return fmaxf(x, NEG_SLOPE * x); }
__device__ __forceinline__ ushort f2bf(float f) {
    unsigned u = __float_as_uint(f);
    return (ushort)((u + 0x7fffu + ((u >> 16) & 1u)) >> 16);
}
__device__ __forceinline__ float bf2f(ushort b) { return __uint_as_float(((unsigned)b) << 16); }
__device__ __forceinline__ float lo16f(unsigned v) { return __uint_as_float(v << 16); }
__device__ __forceinline__ float hi16f(unsigned v) { return __uint_as_float(v & 0xffff0000u); }

// ------------------------- CSR build (per dst) ------------------------------

__global__ void hist_kernel(const int* __restrict__ dst, int* __restrict__ deg, int E) {
    int i = blockIdx.x * blockDim.x + threadIdx.x;
    if (i < E) atomicAdd(&deg[dst[i]], 1);
}

__global__ void block_scan_kernel(const int* __restrict__ deg, int* __restrict__ loc,
                                  int* __restrict__ bsum, int n) {
    __shared__ int sm[1024];
    const int tid = threadIdx.x;
    const int i = blockIdx.x * 1024 + tid;
    int v = (i < n) ? deg[i] : 0;
    sm[tid] = v;
    __syncthreads();
    for (int off = 1; off < 1024; off <<= 1) {
        int t = (tid >= off) ? sm[tid - off] : 0;
        __syncthreads();
        sm[tid] += t;
        __syncthreads();
    }
    if (i < n) loc[i] = sm[tid] - v;
    if (tid == 1023) bsum[blockIdx.x] = sm[1023];
}

// apply + inline wave-scan of <=64 block sums (block 0 also writes total)
__global__ void apply_scan_kernel(const int* __restrict__ loc, const int* __restrict__ bsum,
                                  int* __restrict__ row_ptr, int* __restrict__ cursor,
                                  int n, int nb) {
    __shared__ int pb[64];
    const int tid = threadIdx.x;
    if (tid < 64) {
        int v = (tid < nb) ? bsum[tid] : 0;
        int orig = v;
        for (int off = 1; off < 64; off <<= 1) {
            int t = __shfl_up(v, off);
            if (tid >= off) v += t;
        }
        pb[tid] = v - orig;
        if (tid == 63 && blockIdx.x == 0) row_ptr[n] = v;
    }
    __syncthreads();
    int i = blockIdx.x * blockDim.x + tid;
    if (i < n) {
        int v = loc[i] + pb[i >> 10];
        row_ptr[i] = v;
        cursor[i]  = v;
    }
}

__global__ void scatter_kernel(const int* __restrict__ src, const int* __restrict__ dst,
                               int* __restrict__ cursor, int* __restrict__ ssrc, int E) {
    int i = blockIdx.x * blockDim.x + threadIdx.x;
    if (i < E) {
        int s = src[i];
        int pos = atomicAdd(&cursor[dst[i]], 1);
        ssrc[pos] = s;
    }
}

// ----------------------------- fused prep ------------------------------------
// Range-partitioned: h cast | W1/W2/W3 castT | rWm fold | cursor zero.
// Weight outputs are [col][k] with k XOR-swizzled (k ^ ((c&7)<<3)).

__global__ void prep_kernel(const float* __restrict__ h, ushort* __restrict__ xbh,
                            const float* __restrict__ W1, ushort* __restrict__ W1th,
                            const float* __restrict__ W2, ushort* __restrict__ W2th,
                            const float* __restrict__ W3, ushort* __restrict__ W3th,
                            const float* __restrict__ rW3, ushort* __restrict__ rWmh,
                            int* __restrict__ cursor, int nh4, int n) {
    int i = blockIdx.x * blockDim.x + threadIdx.x;
    if (i < nh4) {
        float4 v = ((const float4*)h)[i];
        ushort4 o;
        o.x = f2bf(v.x); o.y = f2bf(v.y); o.z = f2bf(v.z); o.w = f2bf(v.w);
        ((ushort4*)xbh)[i] = o;
        return;
    }
    int j = i - nh4;
    if (j < 16384) {                      // W1
        int c = j >> 7, k = j & 127;
        int kd = k ^ ((c & 7) << 3);
        W1th[c * 128 + kd] = f2bf(W1[k * 128 + c]);
    } else if (j < 32768) {               // W2
        j -= 16384;
        int c = j >> 7, k = j & 127;
        int kd = k ^ ((c & 7) << 3);
        W2th[c * 128 + kd] = f2bf(W2[k * 128 + c]);
    } else if (j < 65536) {               // W3
        j -= 32768;
        int c = j >> 7, k = j & 127;
        int kd = k ^ ((c & 7) << 3);
        W3th[c * 128 + kd] = f2bf(W3[k * 256 + c]);
    } else if (j < 73728) {               // rWm fold
        j -= 65536;
        int c = j >> 7, k = j & 127;
        const float* row = rW3 + (size_t)k * 256;
        float v = 0.25f * ((row[c] + row[64 + c]) + (row[128 + c] + row[192 + c]));
        int kd = k ^ ((c & 7) << 3);
        rWmh[c * 128 + kd] = f2bf(v);
    } else if (j < 73728 + n) {           // cursor zero
        cursor[j - 73728] = 0;
    }
}

// ------------------------------- GEMM ---------------------------------------
// C[M,Ncols] = X[M,128] @ W; X hi-plane bf16, W transposed+swizzled bf16.
// Block = 2 waves (128 thr), tile 64(M) x 128(N); wave = 32(M) x 128(N).
// W slice 128colsx128k = 32KB staged in dynamic LDS; blockIdx.y==0 of layer 3
// also stages rWm (16KB) and emits resmean. Epilogue: bf16 C + fused el/er.

__global__ void __launch_bounds__(128)
gemm_kernel(const ushort* __restrict__ Ah, const ushort* __restrict__ Bth,
            const ushort* __restrict__ B2th,
            ushort* __restrict__ Cb, float* __restrict__ C2f,
            const float* __restrict__ alv, const float* __restrict__ arv,
            float* __restrict__ el, float* __restrict__ er,
            int M, int Ncols, int dshift) {
    extern __shared__ ushort Ws[];            // [128*128] (+ [64*128] when do2)
    ushort* Ws2 = Ws + 128 * 128;
    const int tid = threadIdx.x;
    const int wv = tid >> 6;
    const int lane = tid & 63;
    const int l15 = lane & 15;
    const int g = lane >> 4;
    const int bm = blockIdx.x * 64 + wv * 32;
    const int bn = blockIdx.y * 128;
    const bool do2 = (B2th != nullptr) && (blockIdx.y == 0);

    // stage W slice: 2048 uint4, 128 threads x 16 iterations
    {
        const uint4* gh = (const uint4*)(Bth + (size_t)bn * 128);
        uint4* sh = (uint4*)Ws;
#pragma unroll
        for (int it = 0; it < 16; ++it) sh[it * 128 + tid] = gh[it * 128 + tid];
        if (do2) {
            const uint4* g2 = (const uint4*)B2th;
            uint4* s2 = (uint4*)Ws2;
#pragma unroll
            for (int it = 0; it < 8; ++it) s2[it * 128 + tid] = g2[it * 128 + tid];
        }
    }
    __syncthreads();

    // X fragments: 2 m-frags per wave
    const int m0 = bm + l15;
    const int m1 = bm + 16 + l15;
    const int mc0 = (m0 < M) ? m0 : (M - 1);
    const int mc1 = (m1 < M) ? m1 : (M - 1);
    bf16x8 xh[2][4];
#pragma unroll
    for (int kk = 0; kk < 4; ++kk) {
        xh[0][kk] = *(const bf16x8*)(Ah + (size_t)mc0 * 128 + kk * 32 + g * 8);
        xh[1][kk] = *(const bf16x8*)(Ah + (size_t)mc1 * 128 + kk * 32 + g * 8);
    }

    f32x4 acc[2][8] = {};
    f32x4 acc2[2][4] = {};
    const int swz = (l15 & 7) << 4;
#pragma unroll
    for (int n = 0; n < 8; ++n) {
        const int colb = (n * 16 + l15) * 256;
#pragma unroll
        for (int kk = 0; kk < 4; ++kk) {
            const int boff = colb + ((kk * 64 + g * 16) ^ swz);
            bf16x8 wh = *(const bf16x8*)((const char*)Ws + boff);
            acc[0][n] = __builtin_amdgcn_mfma_f32_16x16x32_bf16(wh, xh[0][kk], acc[0][n], 0, 0, 0);
            acc[1][n] = __builtin_amdgcn_mfma_f32_16x16x32_bf16(wh, xh[1][kk], acc[1][n], 0, 0, 0);
        }
    }
    if (do2) {
#pragma unroll
        for (int n = 0; n < 4; ++n) {
            const int colb = (n * 16 + l15) * 256;
#pragma unroll
            for (int kk = 0; kk < 4; ++kk) {
                const int boff = colb + ((kk * 64 + g * 16) ^ swz);
                bf16x8 w2 = *(const bf16x8*)((const char*)Ws2 + boff);
                acc2[0][n] = __builtin_amdgcn_mfma_f32_16x16x32_bf16(w2, xh[0][kk], acc2[0][n], 0, 0, 0);
                acc2[1][n] = __builtin_amdgcn_mfma_f32_16x16x32_bf16(w2, xh[1][kk], acc2[1][n], 0, 0, 0);
            }
        }
    }

#pragma unroll
    for (int mf = 0; mf < 2; ++mf) {
        const int m = (mf == 0) ? m0 : m1;
        const bool valid = (m < M);
        if (valid) {
            size_t ro = (size_t)m * Ncols;
#pragma unroll
            for (int n = 0; n < 8; ++n) {
                int col = bn + n * 16 + g * 4;
                ushort4 o;
                o.x = f2bf(acc[mf][n][0]); o.y = f2bf(acc[mf][n][1]);
                o.z = f2bf(acc[mf][n][2]); o.w = f2bf(acc[mf][n][3]);
                *(ushort4*)&Cb[ro + col] = o;
            }
            if (do2) {
#pragma unroll
                for (int n = 0; n < 4; ++n) {
                    *(float4*)&C2f[(size_t)m * 64 + n * 16 + g * 4] =
                        make_float4(acc2[mf][n][0], acc2[mf][n][1],
                                    acc2[mf][n][2], acc2[mf][n][3]);
                }
            }
        }
        if (alv) {
            float e0 = 0.f, e1 = 0.f, e2 = 0.f, e3 = 0.f;
            float r0 = 0.f, r1 = 0.f, r2 = 0.f, r3 = 0.f;
            const bool four = (dshift == 5);
#pragma unroll
            for (int n = 0; n < 8; ++n) {
                float se = 0.f, sr = 0.f;
#pragma unroll
                for (int rr = 0; rr < 4; ++rr) {
                    int col = bn + n * 16 + g * 4 + rr;
                    float c = acc[mf][n][rr];
                    se += c * alv[col];
                    sr += c * arv[col];
                }
                if (four) {
                    if (n < 2)      { e0 += se; r0 += sr; }
                    else if (n < 4) { e1 += se; r1 += sr; }
                    else if (n < 6) { e2 += se; r2 += sr; }
                    else            { e3 += se; r3 += sr; }
                } else {
                    if (n < 4)      { e0 += se; r0 += sr; }
                    else            { e1 += se; r1 += sr; }
                }
            }
            e0 += __shfl_xor(e0, 16); e0 += __shfl_xor(e0, 32);
            e1 += __shfl_xor(e1, 16); e1 += __shfl_xor(e1, 32);
            r0 += __shfl_xor(r0, 16); r0 += __shfl_xor(r0, 32);
            r1 += __shfl_xor(r1, 16); r1 += __shfl_xor(r1, 32);
            if (four) {
                e2 += __shfl_xor(e2, 16); e2 += __shfl_xor(e2, 32);
                e3 += __shfl_xor(e3, 16); e3 += __shfl_xor(e3, 32);
                r2 += __shfl_xor(r2, 16); r2 += __shfl_xor(r2, 32);
                r3 += __shfl_xor(r3, 16); r3 += __shfl_xor(r3, 32);
            }
            if (valid && g == 0) {
                if (four) {
                    el[m * 4 + 0] = e0; el[m * 4 + 1] = e1;
                    el[m * 4 + 2] = e2; el[m * 4 + 3] = e3;
                    er[m * 4 + 0] = r0; er[m * 4 + 1] = r1;
                    er[m * 4 + 2] = r2; er[m * 4 + 3] = r3;
                } else {
                    int h0 = bn >> 6;
                    el[m * 4 + h0] = e0; el[m * 4 + h0 + 1] = e1;
                    er[m * 4 + h0] = r0; er[m * 4 + h0 + 1] = r1;
                }
            }
        }
    }
}

// --------------------------- aggregation -------------------------------------
// Layers 1/2: C=128. Wave = 2 half-waves of 32 lanes; each step handles 2
// edges (one per half). Lane l32 owns elements 4*l32..4*l32+3 (uint2 gather),
// head hh=l32>>3. Cross-half combine + epilogue on half 0.

__global__ void __launch_bounds__(256)
aggregate12_kernel(const ushort* __restrict__ featb, const float* __restrict__ el,
                   const float* __restrict__ er, const int* __restrict__ row_ptr,
                   const int* __restrict__ ssrc, const float* __restrict__ resf,
                   const ushort* __restrict__ rxh, const ushort* __restrict__ rxl,
                   ushort* __restrict__ xbh, ushort* __restrict__ xbl, int n) {
    const int wid = threadIdx.x >> 6;
    const int lane = threadIdx.x & 63;
    const int node = blockIdx.x * 4 + wid;
    if (node >= n) return;
    const int beg = row_ptr[node];
    const int end = row_ptr[node + 1];
    const int half = lane >> 5;
    const int l32 = lane & 31;
    const int hh = l32 >> 3;
    const float erh = er[node * 4 + hh];

    float ssum = 0.f, a0 = 0.f, a1 = 0.f, a2 = 0.f, a3 = 0.f;
    int p = beg;
    for (; p + 8 <= end; p += 8) {
        int s[4]; uint2 v[4]; float e[4];
#pragma unroll
        for (int j = 0; j < 4; ++j) s[j] = ssrc[p + 2 * j + half];
#pragma unroll
        for (int j = 0; j < 4; ++j) v[j] = *(const uint2*)&featb[(size_t)s[j] * 128 + l32 * 4];
#pragma unroll
        for (int j = 0; j < 4; ++j) e[j] = el[s[j] * 4 + hh];
#pragma unroll
        for (int j = 0; j < 4; ++j) {
            float w = __expf(leaky(e[j] + erh));
            ssum += w;
            a0 += w * lo16f(v[j].x);
            a1 += w * hi16f(v[j].x);
            a2 += w * lo16f(v[j].y);
            a3 += w * hi16f(v[j].y);
        }
    }
    for (; p < end; p += 2) {
        int pe = p + half;
        bool ok = pe < end;
        int s = ssrc[ok ? pe : beg];
        uint2 v = *(const uint2*)&featb[(size_t)s * 128 + l32 * 4];
        float w = ok ? __expf(leaky(el[s * 4 + hh] + erh)) : 0.f;
        ssum += w;
        a0 += w * lo16f(v.x);
        a1 += w * hi16f(v.x);
        a2 += w * lo16f(v.y);
        a3 += w * hi16f(v.y);
    }
    // combine halves
    ssum += __shfl_xor(ssum, 32);
    a0 += __shfl_xor(a0, 32);
    a1 += __shfl_xor(a1, 32);
    a2 += __shfl_xor(a2, 32);
    a3 += __shfl_xor(a3, 32);
    float inv = (end > beg) ? 1.f / ssum : 0.f;
    if (half == 0) {
        size_t o = (size_t)node * 128 + l32 * 4;   // element index
        float rb0, rb1, rb2, rb3;
        if (resf) {
            float4 f = *(const float4*)&resf[o];
            rb0 = f.x; rb1 = f.y; rb2 = f.z; rb3 = f.w;
        } else {
            uint2 rh = *(const uint2*)&rxh[o];
            uint2 rl = *(const uint2*)&rxl[o];
            rb0 = lo16f(rh.x) + lo16f(rl.x);
            rb1 = hi16f(rh.x) + hi16f(rl.x);
            rb2 = lo16f(rh.y) + lo16f(rl.y);
            rb3 = hi16f(rh.y) + hi16f(rl.y);
        }
        float r0 = fmaxf(a0 * inv + rb0, 0.f);
        float r1 = fmaxf(a1 * inv + rb1, 0.f);
        float r2 = fmaxf(a2 * inv + rb2, 0.f);
        float r3 = fmaxf(a3 * inv + rb3, 0.f);
        ushort h0 = f2bf(r0), h1 = f2bf(r1), h2 = f2bf(r2), h3 = f2bf(r3);
        ushort l0 = f2bf(r0 - bf2f(h0)), l1 = f2bf(r1 - bf2f(h1));
        ushort l2 = f2bf(r2 - bf2f(h2)), l3 = f2bf(r3 - bf2f(h3));
        uint2 oh, ol;
        oh.x = (unsigned)h0 | ((unsigned)h1 << 16);
        oh.y = (unsigned)h2 | ((unsigned)h3 << 16);
        ol.x = (unsigned)l0 | ((unsigned)l1 << 16);
        ol.y = (unsigned)l2 | ((unsigned)l3 << 16);
        *(uint2*)&xbh[o] = oh;
        *(uint2*)&xbl[o] = ol;
    }
}

// Layer 3: C=256 (H=4, D=64). Wave = 2 halves x 2 edges/step; lane l32 owns
// elements 8*l32..8*l32+7 (uint4 gather), head hh=l32>>3. Head-mean via
// shfl_xor(8,16) after per-head normalize; + resmean (pre-folded).

__global__ void __launch_bounds__(256)
aggregate3_kernel(const ushort* __restrict__ featb, const float* __restrict__ el,
                  const float* __restrict__ er, const int* __restrict__ row_ptr,
                  const int* __restrict__ ssrc, const float* __restrict__ resmean,
                  float* __restrict__ out, int n) {
    const int wid = threadIdx.x >> 6;
    const int lane = threadIdx.x & 63;
    const int node = blockIdx.x * 4 + wid;
    if (node >= n) return;
    const int beg = row_ptr[node];
    const int end = row_ptr[node + 1];
    const int half = lane >> 5;
    const int l32 = lane & 31;
    const int hh = l32 >> 3;
    const float erh = er[node * 4 + hh];

    float c[8] = {};
    float ssum = 0.f;
    int p = beg;
    for (; p + 8 <= end; p += 8) {
        int s[4]; uint4 v[4]; float e[4];
#pragma unroll
        for (int j = 0; j < 4; ++j) s[j] = ssrc[p + 2 * j + half];
#pragma unroll
        for (int j = 0; j < 4; ++j) v[j] = *(const uint4*)&featb[(size_t)s[j] * 256 + l32 * 8];
#pragma unroll
        for (int j = 0; j < 4; ++j) e[j] = el[s[j] * 4 + hh];
#pragma unroll
        for (int j = 0; j < 4; ++j) {
            float w = __expf(leaky(e[j] + erh));
            ssum += w;
            c[0] += w * lo16f(v[j].x); c[1] += w * hi16f(v[j].x);
            c[2] += w * lo16f(v[j].y); c[3] += w * hi16f(v[j].y);
            c[4] += w * lo16f(v[j].z); c[5] += w * hi16f(v[j].z);
            c[6] += w * lo16f(v[j].w); c[7] += w * hi16f(v[j].w);
        }
    }
    for (; p < end; p += 2) {
        int pe = p + half;
        bool ok = pe < end;
        int s = ssrc[ok ? pe : beg];
        uint4 v = *(const uint4*)&featb[(size_t)s * 256 + l32 * 8];
        float w = ok ? __expf(leaky(el[s * 4 + hh] + erh)) : 0.f;
        ssum += w;
        c[0] += w * lo16f(v.x); c[1] += w * hi16f(v.x);
        c[2] += w * lo16f(v.y); c[3] += w * hi16f(v.y);
        c[4] += w * lo16f(v.z); c[5] += w * hi16f(v.z);
        c[6] += w * lo16f(v.w); c[7] += w * hi16f(v.w);
    }
    // combine halves
    ssum += __shfl_xor(ssum, 32);
#pragma unroll
    for (int i = 0; i < 8; ++i) c[i] += __shfl_xor(c[i], 32);
    float inv = (end > beg) ? 1.f / ssum : 0.f;
#pragma unroll
    for (int i = 0; i < 8; ++i) c[i] *= inv;
    // head mean: sum over head bits (l32 bits 3,4)
#pragma unroll
    for (int i = 0; i < 8; ++i) c[i] += __shfl_xor(c[i], 8);
#pragma unroll
    for (int i = 0; i < 8; ++i) c[i] += __shfl_xor(c[i], 16);
    if (lane < 8) {
        const int d0 = lane * 8;
        float4 rm0 = *(const float4*)&resmean[(size_t)node * 64 + d0];
        float4 rm1 = *(const float4*)&resmean[(size_t)node * 64 + d0 + 4];
        *(float4*)&out[(size_t)node * 64 + d0] =
            make_float4(0.25f * c[0] + rm0.x, 0.25f * c[1] + rm0.y,
                        0.25f * c[2] + rm0.z, 0.25f * c[3] + rm0.w);
        *(float4*)&out[(size_t)node * 64 + d0 + 4] =
            make_float4(0.25f * c[4] + rm1.x, 0.25f * c[5] + rm1.y,
                        0.25f * c[6] + rm1.z, 0.25f * c[7] + rm1.w);
    }
}

// ------------------------------ launch ---------------------------------------

extern "C" void kernel_launch(void* const* d_in, const int* in_sizes, int n_in,
                              void* d_out, int out_size, void* d_ws, size_t ws_size,
                              hipStream_t stream) {
    const float* h   = (const float*)d_in[0];
    const float* W1  = (const float*)d_in[1];
    const float* al1 = (const float*)d_in[2];
    const float* ar1 = (const float*)d_in[3];
    const float* W2  = (const float*)d_in[4];
    const float* al2 = (const float*)d_in[5];
    const float* ar2 = (const float*)d_in[6];
    const float* W3  = (const float*)d_in[7];
    const float* al3 = (const float*)d_in[8];
    const float* ar3 = (const float*)d_in[9];
    const float* rW3 = (const float*)d_in[10];
    const int* src   = (const int*)d_in[11];
    const int* dstv  = (const int*)d_in[12];
    const int N = in_sizes[0] / 128;
    const int E = in_sizes[11];
    float* out = (float*)d_out;

    char* p = (char*)d_ws;
    auto alloc = [&](size_t bytes) -> char* {
        char* q = p;
        p += (bytes + 255) & ~(size_t)255;
        return q;
    };
    int*    row_ptr = (int*)alloc((size_t)(N + 1) * 4);
    int*    cursor  = (int*)alloc((size_t)N * 4);
    int*    loc     = (int*)alloc((size_t)N * 4);
    int*    bsum    = (int*)alloc(64 * 4);
    int*    ssrc    = (int*)alloc((size_t)E * 4);
    float*  el      = (float*)alloc((size_t)N * 16);
    float*  er      = (float*)alloc((size_t)N * 16);
    ushort* featb   = (ushort*)alloc((size_t)N * 256 * 2);
    ushort* xbh     = (ushort*)alloc((size_t)N * 128 * 2);
    ushort* xbl     = (ushort*)alloc((size_t)N * 128 * 2);
    ushort* W1th = (ushort*)alloc(128 * 128 * 2);
    ushort* W2th = (ushort*)alloc(128 * 128 * 2);
    ushort* W3th = (ushort*)alloc(256 * 128 * 2);
    ushort* rWmh = (ushort*)alloc(64 * 128 * 2);
    float*  resmean = (float*)alloc((size_t)N * 64 * 4);

    // fused prep: h hi-cast + W1/W2/W3 castT + rWm fold + cursor zero
    const int nh4 = N * 32;               // N*128/4 float4 groups
    const int prep_total = nh4 + 73728 + N;
    prep_kernel<<<(prep_total + 255) / 256, 256, 0, stream>>>(
        h, xbh, W1, W1th, W2, W2th, W3, W3th, rW3, rWmh, cursor, nh4, N);

    // CSR build
    hist_kernel<<<(E + 255) / 256, 256, 0, stream>>>(dstv, cursor, E);
    int nb = (N + 1023) / 1024;
    block_scan_kernel<<<nb, 1024, 0, stream>>>(cursor, loc, bsum, N);
    apply_scan_kernel<<<(N + 255) / 256, 256, 0, stream>>>(loc, bsum, row_ptr, cursor, N, nb);
    scatter_kernel<<<(E + 255) / 256, 256, 0, stream>>>(src, dstv, cursor, ssrc, E);

    const int gx = (N + 63) / 64;
    dim3 g1(gx, 1);
    dim3 g3(gx, 2);
    int agg_grid = (N + 3) / 4;
    const size_t lds1 = 128 * 128 * sizeof(ushort);                  // 32 KB
    const size_t lds3 = (128 * 128 + 64 * 128) * sizeof(ushort);     // 48 KB

    // layer 1 (residual from fp32 h)
    gemm_kernel<<<g1, 128, lds1, stream>>>(xbh, W1th, nullptr, featb, nullptr,
                                           al1, ar1, el, er, N, 128, 5);
    aggregate12_kernel<<<agg_grid, 256, 0, stream>>>(featb, el, er, row_ptr, ssrc,
                                                     h, nullptr, nullptr, xbh, xbl, N);

    // layer 2 (residual from hi+lo planes)
    gemm_kernel<<<g1, 128, lds1, stream>>>(xbh, W2th, nullptr, featb, nullptr,
                                           al2, ar2, el, er, N, 128, 5);
    aggregate12_kernel<<<agg_grid, 256, 0, stream>>>(featb, el, er, row_ptr, ssrc,
                                                     nullptr, xbh, xbl, xbh, xbl, N);

    // layer 3 (residual projection fused into blockIdx.y==0 blocks)
    gemm_kernel<<<g3, 128, lds3, stream>>>(xbh, W3th, rWmh, featb, resmean,
                                           al3, ar3, el, er, N, 256, 6);
    aggregate3_kernel<<<agg_grid, 256, 0, stream>>>(featb, el, er, row_ptr, ssrc, resmean, out, N);
}

// Round 13
// 382.968 us; speedup vs baseline: 2.6908x; 1.0186x over previous
//
#include <hip/hip_runtime.h>
#include <hip/hip_bf16.h>
#include <math.h>

// ---------------------------------------------------------------------------
// GAT 3-layer forward. N=50000 nodes, E=800000 edges, H=4 heads.
// GEMMs: bf16 MFMA (hi plane), full 128-col W slice staged in dynamic LDS
// (swizzled), 4-wave blocks BM=128, el/er fused into epilogue; layer-3
// residual GEMM fused (blockIdx.y==0 stages rWm in a 2nd LDS slice).
// Aggregation: one wave per dst node, 2 half-waves x 2 edges/step, wide
// per-lane gathers; agg3 measured at ~6.9 TB/s effective = gather roofline.
// x carried as bf16 (single plane); layer-1 residual read from fp32 h.
// ---------------------------------------------------------------------------

#define NEG_SLOPE 0.2f

typedef __attribute__((ext_vector_type(8))) __bf16 bf16x8;
typedef __attribute__((ext_vector_type(4))) float f32x4;

__device__ __forceinline__ float leaky(float x) { return fmaxf(x, NEG_SLOPE * x); }
__device__ __forceinline__ ushort f2bf(float f) {
    unsigned u = __float_as_uint(f);
    return (ushort)((u + 0x7fffu + ((u >> 16) & 1u)) >> 16);
}
__device__ __forceinline__ float bf2f(ushort b) { return __uint_as_float(((unsigned)b) << 16); }
__device__ __forceinline__ float lo16f(unsigned v) { return __uint_as_float(v << 16); }
__device__ __forceinline__ float hi16f(unsigned v) { return __uint_as_float(v & 0xffff0000u); }

// ------------------------- CSR build (per dst) ------------------------------

__global__ void hist_kernel(const int* __restrict__ dst, int* __restrict__ deg, int E) {
    int i = blockIdx.x * blockDim.x + threadIdx.x;
    if (i < E) atomicAdd(&deg[dst[i]], 1);
}

__global__ void block_scan_kernel(const int* __restrict__ deg, int* __restrict__ loc,
                                  int* __restrict__ bsum, int n) {
    __shared__ int sm[1024];
    const int tid = threadIdx.x;
    const int i = blockIdx.x * 1024 + tid;
    int v = (i < n) ? deg[i] : 0;
    sm[tid] = v;
    __syncthreads();
    for (int off = 1; off < 1024; off <<= 1) {
        int t = (tid >= off) ? sm[tid - off] : 0;
        __syncthreads();
        sm[tid] += t;
        __syncthreads();
    }
    if (i < n) loc[i] = sm[tid] - v;
    if (tid == 1023) bsum[blockIdx.x] = sm[1023];
}

// apply + inline wave-scan of <=64 block sums (block 0 also writes total)
__global__ void apply_scan_kernel(const int* __restrict__ loc, const int* __restrict__ bsum,
                                  int* __restrict__ row_ptr, int* __restrict__ cursor,
                                  int n, int nb) {
    __shared__ int pb[64];
    const int tid = threadIdx.x;
    if (tid < 64) {
        int v = (tid < nb) ? bsum[tid] : 0;
        int orig = v;
        for (int off = 1; off < 64; off <<= 1) {
            int t = __shfl_up(v, off);
            if (tid >= off) v += t;
        }
        pb[tid] = v - orig;
        if (tid == 63 && blockIdx.x == 0) row_ptr[n] = v;
    }
    __syncthreads();
    int i = blockIdx.x * blockDim.x + tid;
    if (i < n) {
        int v = loc[i] + pb[i >> 10];
        row_ptr[i] = v;
        cursor[i]  = v;
    }
}

__global__ void scatter_kernel(const int* __restrict__ src, const int* __restrict__ dst,
                               int* __restrict__ cursor, int* __restrict__ ssrc, int E) {
    int i = blockIdx.x * blockDim.x + threadIdx.x;
    if (i < E) {
        int s = src[i];
        int pos = atomicAdd(&cursor[dst[i]], 1);
        ssrc[pos] = s;
    }
}

// ----------------------------- fused prep ------------------------------------
// Range-partitioned: h cast | W1/W2/W3 castT | rWm fold | cursor zero.
// Weight outputs are [col][k] with k XOR-swizzled (k ^ ((c&7)<<3)).

__global__ void prep_kernel(const float* __restrict__ h, ushort* __restrict__ xbh,
                            const float* __restrict__ W1, ushort* __restrict__ W1th,
                            const float* __restrict__ W2, ushort* __restrict__ W2th,
                            const float* __restrict__ W3, ushort* __restrict__ W3th,
                            const float* __restrict__ rW3, ushort* __restrict__ rWmh,
                            int* __restrict__ cursor, int nh4, int n) {
    int i = blockIdx.x * blockDim.x + threadIdx.x;
    if (i < nh4) {
        float4 v = ((const float4*)h)[i];
        ushort4 o;
        o.x = f2bf(v.x); o.y = f2bf(v.y); o.z = f2bf(v.z); o.w = f2bf(v.w);
        ((ushort4*)xbh)[i] = o;
        return;
    }
    int j = i - nh4;
    if (j < 16384) {                      // W1
        int c = j >> 7, k = j & 127;
        int kd = k ^ ((c & 7) << 3);
        W1th[c * 128 + kd] = f2bf(W1[k * 128 + c]);
    } else if (j < 32768) {               // W2
        j -= 16384;
        int c = j >> 7, k = j & 127;
        int kd = k ^ ((c & 7) << 3);
        W2th[c * 128 + kd] = f2bf(W2[k * 128 + c]);
    } else if (j < 65536) {               // W3
        j -= 32768;
        int c = j >> 7, k = j & 127;
        int kd = k ^ ((c & 7) << 3);
        W3th[c * 128 + kd] = f2bf(W3[k * 256 + c]);
    } else if (j < 73728) {               // rWm fold
        j -= 65536;
        int c = j >> 7, k = j & 127;
        const float* row = rW3 + (size_t)k * 256;
        float v = 0.25f * ((row[c] + row[64 + c]) + (row[128 + c] + row[192 + c]));
        int kd = k ^ ((c & 7) << 3);
        rWmh[c * 128 + kd] = f2bf(v);
    } else if (j < 73728 + n) {           // cursor zero
        cursor[j - 73728] = 0;
    }
}

// ------------------------------- GEMM ---------------------------------------
// C[M,Ncols] = X[M,128] @ W; X hi-plane bf16, W transposed+swizzled bf16.
// Block = 4 waves (256 thr), tile 128(M) x 128(N); wave = 32(M) x 128(N).
// W slice 128colsx128k = 32KB staged in dynamic LDS; blockIdx.y==0 of layer 3
// also stages rWm (16KB) and emits resmean. Epilogue: bf16 C + fused el/er.

__global__ void __launch_bounds__(256)
gemm_kernel(const ushort* __restrict__ Ah, const ushort* __restrict__ Bth,
            const ushort* __restrict__ B2th,
            ushort* __restrict__ Cb, float* __restrict__ C2f,
            const float* __restrict__ alv, const float* __restrict__ arv,
            float* __restrict__ el, float* __restrict__ er,
            int M, int Ncols, int dshift) {
    extern __shared__ ushort Ws[];            // [128*128] (+ [64*128] when do2)
    ushort* Ws2 = Ws + 128 * 128;
    const int tid = threadIdx.x;
    const int wv = tid >> 6;                  // 0..3
    const int lane = tid & 63;
    const int l15 = lane & 15;
    const int g = lane >> 4;
    const int bm = blockIdx.x * 128 + wv * 32;
    const int bn = blockIdx.y * 128;
    const bool do2 = (B2th != nullptr) && (blockIdx.y == 0);

    // stage W slice: 2048 uint4, 256 threads x 8 iterations
    {
        const uint4* gh = (const uint4*)(Bth + (size_t)bn * 128);
        uint4* sh = (uint4*)Ws;
#pragma unroll
        for (int it = 0; it < 8; ++it) sh[it * 256 + tid] = gh[it * 256 + tid];
        if (do2) {
            const uint4* g2 = (const uint4*)B2th;
            uint4* s2 = (uint4*)Ws2;
#pragma unroll
            for (int it = 0; it < 4; ++it) s2[it * 256 + tid] = g2[it * 256 + tid];
        }
    }
    __syncthreads();

    // X fragments: 2 m-frags per wave
    const int m0 = bm + l15;
    const int m1 = bm + 16 + l15;
    const int mc0 = (m0 < M) ? m0 : (M - 1);
    const int mc1 = (m1 < M) ? m1 : (M - 1);
    bf16x8 xh[2][4];
#pragma unroll
    for (int kk = 0; kk < 4; ++kk) {
        xh[0][kk] = *(const bf16x8*)(Ah + (size_t)mc0 * 128 + kk * 32 + g * 8);
        xh[1][kk] = *(const bf16x8*)(Ah + (size_t)mc1 * 128 + kk * 32 + g * 8);
    }

    f32x4 acc[2][8] = {};
    f32x4 acc2[2][4] = {};
    const int swz = (l15 & 7) << 4;
#pragma unroll
    for (int n = 0; n < 8; ++n) {
        const int colb = (n * 16 + l15) * 256;
#pragma unroll
        for (int kk = 0; kk < 4; ++kk) {
            const int boff = colb + ((kk * 64 + g * 16) ^ swz);
            bf16x8 wh = *(const bf16x8*)((const char*)Ws + boff);
            acc[0][n] = __builtin_amdgcn_mfma_f32_16x16x32_bf16(wh, xh[0][kk], acc[0][n], 0, 0, 0);
            acc[1][n] = __builtin_amdgcn_mfma_f32_16x16x32_bf16(wh, xh[1][kk], acc[1][n], 0, 0, 0);
        }
    }
    if (do2) {
#pragma unroll
        for (int n = 0; n < 4; ++n) {
            const int colb = (n * 16 + l15) * 256;
#pragma unroll
            for (int kk = 0; kk < 4; ++kk) {
                const int boff = colb + ((kk * 64 + g * 16) ^ swz);
                bf16x8 w2 = *(const bf16x8*)((const char*)Ws2 + boff);
                acc2[0][n] = __builtin_amdgcn_mfma_f32_16x16x32_bf16(w2, xh[0][kk], acc2[0][n], 0, 0, 0);
                acc2[1][n] = __builtin_amdgcn_mfma_f32_16x16x32_bf16(w2, xh[1][kk], acc2[1][n], 0, 0, 0);
            }
        }
    }

#pragma unroll
    for (int mf = 0; mf < 2; ++mf) {
        const int m = (mf == 0) ? m0 : m1;
        const bool valid = (m < M);
        if (valid) {
            size_t ro = (size_t)m * Ncols;
#pragma unroll
            for (int n = 0; n < 8; ++n) {
                int col = bn + n * 16 + g * 4;
                ushort4 o;
                o.x = f2bf(acc[mf][n][0]); o.y = f2bf(acc[mf][n][1]);
                o.z = f2bf(acc[mf][n][2]); o.w = f2bf(acc[mf][n][3]);
                *(ushort4*)&Cb[ro + col] = o;
            }
            if (do2) {
#pragma unroll
                for (int n = 0; n < 4; ++n) {
                    *(float4*)&C2f[(size_t)m * 64 + n * 16 + g * 4] =
                        make_float4(acc2[mf][n][0], acc2[mf][n][1],
                                    acc2[mf][n][2], acc2[mf][n][3]);
                }
            }
        }
        if (alv) {
            float e0 = 0.f, e1 = 0.f, e2 = 0.f, e3 = 0.f;
            float r0 = 0.f, r1 = 0.f, r2 = 0.f, r3 = 0.f;
            const bool four = (dshift == 5);
#pragma unroll
            for (int n = 0; n < 8; ++n) {
                float se = 0.f, sr = 0.f;
#pragma unroll
                for (int rr = 0; rr < 4; ++rr) {
                    int col = bn + n * 16 + g * 4 + rr;
                    float c = acc[mf][n][rr];
                    se += c * alv[col];
                    sr += c * arv[col];
                }
                if (four) {
                    if (n < 2)      { e0 += se; r0 += sr; }
                    else if (n < 4) { e1 += se; r1 += sr; }
                    else if (n < 6) { e2 += se; r2 += sr; }
                    else            { e3 += se; r3 += sr; }
                } else {
                    if (n < 4)      { e0 += se; r0 += sr; }
                    else            { e1 += se; r1 += sr; }
                }
            }
            e0 += __shfl_xor(e0, 16); e0 += __shfl_xor(e0, 32);
            e1 += __shfl_xor(e1, 16); e1 += __shfl_xor(e1, 32);
            r0 += __shfl_xor(r0, 16); r0 += __shfl_xor(r0, 32);
            r1 += __shfl_xor(r1, 16); r1 += __shfl_xor(r1, 32);
            if (four) {
                e2 += __shfl_xor(e2, 16); e2 += __shfl_xor(e2, 32);
                e3 += __shfl_xor(e3, 16); e3 += __shfl_xor(e3, 32);
                r2 += __shfl_xor(r2, 16); r2 += __shfl_xor(r2, 32);
                r3 += __shfl_xor(r3, 16); r3 += __shfl_xor(r3, 32);
            }
            if (valid && g == 0) {
                if (four) {
                    el[m * 4 + 0] = e0; el[m * 4 + 1] = e1;
                    el[m * 4 + 2] = e2; el[m * 4 + 3] = e3;
                    er[m * 4 + 0] = r0; er[m * 4 + 1] = r1;
                    er[m * 4 + 2] = r2; er[m * 4 + 3] = r3;
                } else {
                    int h0 = bn >> 6;
                    el[m * 4 + h0] = e0; el[m * 4 + h0 + 1] = e1;
                    er[m * 4 + h0] = r0; er[m * 4 + h0 + 1] = r1;
                }
            }
        }
    }
}

// --------------------------- aggregation -------------------------------------
// Layers 1/2: C=128. Wave = 2 half-waves of 32 lanes; each step handles 2
// edges (one per half). Lane l32 owns elements 4*l32..4*l32+3 (uint2 gather),
// head hh=l32>>3. Residual: fp32 resf (layer 1) OR bf16 rxh (layer 2).

__global__ void __launch_bounds__(256)
aggregate12_kernel(const ushort* __restrict__ featb, const float* __restrict__ el,
                   const float* __restrict__ er, const int* __restrict__ row_ptr,
                   const int* __restrict__ ssrc, const float* __restrict__ resf,
                   const ushort* __restrict__ rxh, ushort* __restrict__ xbh, int n) {
    const int wid = threadIdx.x >> 6;
    const int lane = threadIdx.x & 63;
    const int node = blockIdx.x * 4 + wid;
    if (node >= n) return;
    const int beg = row_ptr[node];
    const int end = row_ptr[node + 1];
    const int half = lane >> 5;
    const int l32 = lane & 31;
    const int hh = l32 >> 3;
    const float erh = er[node * 4 + hh];

    float ssum = 0.f, a0 = 0.f, a1 = 0.f, a2 = 0.f, a3 = 0.f;
    int p = beg;
    for (; p + 8 <= end; p += 8) {
        int s[4]; uint2 v[4]; float e[4];
#pragma unroll
        for (int j = 0; j < 4; ++j) s[j] = ssrc[p + 2 * j + half];
#pragma unroll
        for (int j = 0; j < 4; ++j) v[j] = *(const uint2*)&featb[(size_t)s[j] * 128 + l32 * 4];
#pragma unroll
        for (int j = 0; j < 4; ++j) e[j] = el[s[j] * 4 + hh];
#pragma unroll
        for (int j = 0; j < 4; ++j) {
            float w = __expf(leaky(e[j] + erh));
            ssum += w;
            a0 += w * lo16f(v[j].x);
            a1 += w * hi16f(v[j].x);
            a2 += w * lo16f(v[j].y);
            a3 += w * hi16f(v[j].y);
        }
    }
    for (; p < end; p += 2) {
        int pe = p + half;
        bool ok = pe < end;
        int s = ssrc[ok ? pe : beg];
        uint2 v = *(const uint2*)&featb[(size_t)s * 128 + l32 * 4];
        float w = ok ? __expf(leaky(el[s * 4 + hh] + erh)) : 0.f;
        ssum += w;
        a0 += w * lo16f(v.x);
        a1 += w * hi16f(v.x);
        a2 += w * lo16f(v.y);
        a3 += w * hi16f(v.y);
    }
    // combine halves
    ssum += __shfl_xor(ssum, 32);
    a0 += __shfl_xor(a0, 32);
    a1 += __shfl_xor(a1, 32);
    a2 += __shfl_xor(a2, 32);
    a3 += __shfl_xor(a3, 32);
    float inv = (end > beg) ? 1.f / ssum : 0.f;
    if (half == 0) {
        size_t o = (size_t)node * 128 + l32 * 4;   // element index
        float rb0, rb1, rb2, rb3;
        if (resf) {
            float4 f = *(const float4*)&resf[o];
            rb0 = f.x; rb1 = f.y; rb2 = f.z; rb3 = f.w;
        } else {
            uint2 rh = *(const uint2*)&rxh[o];
            rb0 = lo16f(rh.x);
            rb1 = hi16f(rh.x);
            rb2 = lo16f(rh.y);
            rb3 = hi16f(rh.y);
        }
        float r0 = fmaxf(a0 * inv + rb0, 0.f);
        float r1 = fmaxf(a1 * inv + rb1, 0.f);
        float r2 = fmaxf(a2 * inv + rb2, 0.f);
        float r3 = fmaxf(a3 * inv + rb3, 0.f);
        uint2 oh;
        oh.x = (unsigned)f2bf(r0) | ((unsigned)f2bf(r1) << 16);
        oh.y = (unsigned)f2bf(r2) | ((unsigned)f2bf(r3) << 16);
        *(uint2*)&xbh[o] = oh;
    }
}

// Layer 3: C=256 (H=4, D=64). Wave = 2 halves x 2 edges/step; lane l32 owns
// elements 8*l32..8*l32+7 (uint4 gather), head hh=l32>>3. Head-mean via
// shfl_xor(8,16) after per-head normalize; + resmean (pre-folded).

__global__ void __launch_bounds__(256)
aggregate3_kernel(const ushort* __restrict__ featb, const float* __restrict__ el,
                  const float* __restrict__ er, const int* __restrict__ row_ptr,
                  const int* __restrict__ ssrc, const float* __restrict__ resmean,
                  float* __restrict__ out, int n) {
    const int wid = threadIdx.x >> 6;
    const int lane = threadIdx.x & 63;
    const int node = blockIdx.x * 4 + wid;
    if (node >= n) return;
    const int beg = row_ptr[node];
    const int end = row_ptr[node + 1];
    const int half = lane >> 5;
    const int l32 = lane & 31;
    const int hh = l32 >> 3;
    const float erh = er[node * 4 + hh];

    float c[8] = {};
    float ssum = 0.f;
    int p = beg;
    for (; p + 8 <= end; p += 8) {
        int s[4]; uint4 v[4]; float e[4];
#pragma unroll
        for (int j = 0; j < 4; ++j) s[j] = ssrc[p + 2 * j + half];
#pragma unroll
        for (int j = 0; j < 4; ++j) v[j] = *(const uint4*)&featb[(size_t)s[j] * 256 + l32 * 8];
#pragma unroll
        for (int j = 0; j < 4; ++j) e[j] = el[s[j] * 4 + hh];
#pragma unroll
        for (int j = 0; j < 4; ++j) {
            float w = __expf(leaky(e[j] + erh));
            ssum += w;
            c[0] += w * lo16f(v[j].x); c[1] += w * hi16f(v[j].x);
            c[2] += w * lo16f(v[j].y); c[3] += w * hi16f(v[j].y);
            c[4] += w * lo16f(v[j].z); c[5] += w * hi16f(v[j].z);
            c[6] += w * lo16f(v[j].w); c[7] += w * hi16f(v[j].w);
        }
    }
    for (; p < end; p += 2) {
        int pe = p + half;
        bool ok = pe < end;
        int s = ssrc[ok ? pe : beg];
        uint4 v = *(const uint4*)&featb[(size_t)s * 256 + l32 * 8];
        float w = ok ? __expf(leaky(el[s * 4 + hh] + erh)) : 0.f;
        ssum += w;
        c[0] += w * lo16f(v.x); c[1] += w * hi16f(v.x);
        c[2] += w * lo16f(v.y); c[3] += w * hi16f(v.y);
        c[4] += w * lo16f(v.z); c[5] += w * hi16f(v.z);
        c[6] += w * lo16f(v.w); c[7] += w * hi16f(v.w);
    }
    // combine halves
    ssum += __shfl_xor(ssum, 32);
#pragma unroll
    for (int i = 0; i < 8; ++i) c[i] += __shfl_xor(c[i], 32);
    float inv = (end > beg) ? 1.f / ssum : 0.f;
#pragma unroll
    for (int i = 0; i < 8; ++i) c[i] *= inv;
    // head mean: sum over head bits (l32 bits 3,4)
#pragma unroll
    for (int i = 0; i < 8; ++i) c[i] += __shfl_xor(c[i], 8);
#pragma unroll
    for (int i = 0; i < 8; ++i) c[i] += __shfl_xor(c[i], 16);
    if (lane < 8) {
        const int d0 = lane * 8;
        float4 rm0 = *(const float4*)&resmean[(size_t)node * 64 + d0];
        float4 rm1 = *(const float4*)&resmean[(size_t)node * 64 + d0 + 4];
        *(float4*)&out[(size_t)node * 64 + d0] =
            make_float4(0.25f * c[0] + rm0.x, 0.25f * c[1] + rm0.y,
                        0.25f * c[2] + rm0.z, 0.25f * c[3] + rm0.w);
        *(float4*)&out[(size_t)node * 64 + d0 + 4] =
            make_float4(0.25f * c[4] + rm1.x, 0.25f * c[5] + rm1.y,
                        0.25f * c[6] + rm1.z, 0.25f * c[7] + rm1.w);
    }
}

// ------------------------------ launch ---------------------------------------

extern "C" void kernel_launch(void* const* d_in, const int* in_sizes, int n_in,
                              void* d_out, int out_size, void* d_ws, size_t ws_size,
                              hipStream_t stream) {
    const float* h   = (const float*)d_in[0];
    const float* W1  = (const float*)d_in[1];
    const float* al1 = (const float*)d_in[2];
    const float* ar1 = (const float*)d_in[3];
    const float* W2  = (const float*)d_in[4];
    const float* al2 = (const float*)d_in[5];
    const float* ar2 = (const float*)d_in[6];
    const float* W3  = (const float*)d_in[7];
    const float* al3 = (const float*)d_in[8];
    const float* ar3 = (const float*)d_in[9];
    const float* rW3 = (const float*)d_in[10];
    const int* src   = (const int*)d_in[11];
    const int* dstv  = (const int*)d_in[12];
    const int N = in_sizes[0] / 128;
    const int E = in_sizes[11];
    float* out = (float*)d_out;

    char* p = (char*)d_ws;
    auto alloc = [&](size_t bytes) -> char* {
        char* q = p;
        p += (bytes + 255) & ~(size_t)255;
        return q;
    };
    int*    row_ptr = (int*)alloc((size_t)(N + 1) * 4);
    int*    cursor  = (int*)alloc((size_t)N * 4);
    int*    loc     = (int*)alloc((size_t)N * 4);
    int*    bsum    = (int*)alloc(64 * 4);
    int*    ssrc    = (int*)alloc((size_t)E * 4);
    float*  el      = (float*)alloc((size_t)N * 16);
    float*  er      = (float*)alloc((size_t)N * 16);
    ushort* featb   = (ushort*)alloc((size_t)N * 256 * 2);
    ushort* xbh     = (ushort*)alloc((size_t)N * 128 * 2);
    ushort* W1th = (ushort*)alloc(128 * 128 * 2);
    ushort* W2th = (ushort*)alloc(128 * 128 * 2);
    ushort* W3th = (ushort*)alloc(256 * 128 * 2);
    ushort* rWmh = (ushort*)alloc(64 * 128 * 2);
    float*  resmean = (float*)alloc((size_t)N * 64 * 4);

    // fused prep: h hi-cast + W1/W2/W3 castT + rWm fold + cursor zero
    const int nh4 = N * 32;               // N*128/4 float4 groups
    const int prep_total = nh4 + 73728 + N;
    prep_kernel<<<(prep_total + 255) / 256, 256, 0, stream>>>(
        h, xbh, W1, W1th, W2, W2th, W3, W3th, rW3, rWmh, cursor, nh4, N);

    // CSR build
    hist_kernel<<<(E + 255) / 256, 256, 0, stream>>>(dstv, cursor, E);
    int nb = (N + 1023) / 1024;
    block_scan_kernel<<<nb, 1024, 0, stream>>>(cursor, loc, bsum, N);
    apply_scan_kernel<<<(N + 255) / 256, 256, 0, stream>>>(loc, bsum, row_ptr, cursor, N, nb);
    scatter_kernel<<<(E + 255) / 256, 256, 0, stream>>>(src, dstv, cursor, ssrc, E);

    const int gx = (N + 127) / 128;
    dim3 g1(gx, 1);
    dim3 g3(gx, 2);
    int agg_grid = (N + 3) / 4;
    const size_t lds1 = 128 * 128 * sizeof(ushort);                  // 32 KB
    const size_t lds3 = (128 * 128 + 64 * 128) * sizeof(ushort);     // 48 KB

    // layer 1 (residual from fp32 h)
    gemm_kernel<<<g1, 256, lds1, stream>>>(xbh, W1th, nullptr, featb, nullptr,
                                           al1, ar1, el, er, N, 128, 5);
    aggregate12_kernel<<<agg_grid, 256, 0, stream>>>(featb, el, er, row_ptr, ssrc,
                                                     h, nullptr, xbh, N);

    // layer 2 (residual from bf16 x)
    gemm_kernel<<<g1, 256, lds1, stream>>>(xbh, W2th, nullptr, featb, nullptr,
                                           al2, ar2, el, er, N, 128, 5);
    aggregate12_kernel<<<agg_grid, 256, 0, stream>>>(featb, el, er, row_ptr, ssrc,
                                                     nullptr, xbh, xbh, N);

    // layer 3 (residual projection fused into blockIdx.y==0 blocks)
    gemm_kernel<<<g3, 256, lds3, stream>>>(xbh, W3th, rWmh, featb, resmean,
                                           al3, ar3, el, er, N, 256, 6);
    aggregate3_kernel<<<agg_grid, 256, 0, stream>>>(featb, el, er, row_ptr, ssrc, resmean, out, N);
}

// Round 14
// 373.872 us; speedup vs baseline: 2.7562x; 1.0243x over previous
//
#include <hip/hip_runtime.h>
#include <hip/hip_bf16.h>
#include <math.h>

// ---------------------------------------------------------------------------
// GAT 3-layer forward. N=50000 nodes, E=800000 edges, H=4 heads.
// Layers 1/2: bf16 MFMA GEMM (W in LDS, swizzled) + fused el/er; wave-per-node
// aggregation of feat (rooflined gathers).
// Layer 3 (reformulated via linearity): aggregation commutes with W3 —
//   pre3:  [N,128]@[128,80] -> resmean (64 cols) + el3/er3 (W3@al folded cols)
//   agg3:  gather x[src] (256B/edge, HALF of feat's 512B), accumulate 4
//          per-head 128-dim sums, normalize, write aggv bf16 [N,512]
//   fin:   [N,512]@[512,64] block-diag 0.25*W3 + resmean -> out
// ---------------------------------------------------------------------------

#define NEG_SLOPE 0.2f

typedef __attribute__((ext_vector_type(8))) __bf16 bf16x8;
typedef __attribute__((ext_vector_type(4))) float f32x4;

__device__ __forceinline__ float leaky(float x) { return fmaxf(x, NEG_SLOPE * x); }
__device__ __forceinline__ ushort f2bf(float f) {
    unsigned u = __float_as_uint(f);
    return (ushort)((u + 0x7fffu + ((u >> 16) & 1u)) >> 16);
}
__device__ __forceinline__ float bf2f(ushort b) { return __uint_as_float(((unsigned)b) << 16); }
__device__ __forceinline__ float lo16f(unsigned v) { return __uint_as_float(v << 16); }
__device__ __forceinline__ float hi16f(unsigned v) { return __uint_as_float(v & 0xffff0000u); }

// ------------------------- CSR build (per dst) ------------------------------

__global__ void hist_kernel(const int* __restrict__ dst, int* __restrict__ deg, int E) {
    int i = blockIdx.x * blockDim.x + threadIdx.x;
    if (i < E) atomicAdd(&deg[dst[i]], 1);
}

__global__ void block_scan_kernel(const int* __restrict__ deg, int* __restrict__ loc,
                                  int* __restrict__ bsum, int n) {
    __shared__ int sm[1024];
    const int tid = threadIdx.x;
    const int i = blockIdx.x * 1024 + tid;
    int v = (i < n) ? deg[i] : 0;
    sm[tid] = v;
    __syncthreads();
    for (int off = 1; off < 1024; off <<= 1) {
        int t = (tid >= off) ? sm[tid - off] : 0;
        __syncthreads();
        sm[tid] += t;
        __syncthreads();
    }
    if (i < n) loc[i] = sm[tid] - v;
    if (tid == 1023) bsum[blockIdx.x] = sm[1023];
}

__global__ void apply_scan_kernel(const int* __restrict__ loc, const int* __restrict__ bsum,
                                  int* __restrict__ row_ptr, int* __restrict__ cursor,
                                  int n, int nb) {
    __shared__ int pb[64];
    const int tid = threadIdx.x;
    if (tid < 64) {
        int v = (tid < nb) ? bsum[tid] : 0;
        int orig = v;
        for (int off = 1; off < 64; off <<= 1) {
            int t = __shfl_up(v, off);
            if (tid >= off) v += t;
        }
        pb[tid] = v - orig;
        if (tid == 63 && blockIdx.x == 0) row_ptr[n] = v;
    }
    __syncthreads();
    int i = blockIdx.x * blockDim.x + tid;
    if (i < n) {
        int v = loc[i] + pb[i >> 10];
        row_ptr[i] = v;
        cursor[i]  = v;
    }
}

__global__ void scatter_kernel(const int* __restrict__ src, const int* __restrict__ dst,
                               int* __restrict__ cursor, int* __restrict__ ssrc, int E) {
    int i = blockIdx.x * blockDim.x + threadIdx.x;
    if (i < E) {
        int s = src[i];
        int pos = atomicAdd(&cursor[dst[i]], 1);
        ssrc[pos] = s;
    }
}

// ----------------------------- fused prep ------------------------------------
// Ranges: h cast | W1 castT | W2 castT | Bpre(rWm cols 0..63, pl/pr cols
// 64..71, zero 72..79) | Wft (block-diag 0.25*W3, [64 cols][512 k]) | cursor 0.
// All [col][k] outputs XOR-swizzled: kd = k ^ ((c&7)<<3).

__global__ void prep_kernel(const float* __restrict__ h, ushort* __restrict__ xbh,
                            const float* __restrict__ W1, ushort* __restrict__ W1th,
                            const float* __restrict__ W2, ushort* __restrict__ W2th,
                            const float* __restrict__ W3, ushort* __restrict__ Bpre,
                            ushort* __restrict__ Wft, const float* __restrict__ rW3,
                            const float* __restrict__ al3, const float* __restrict__ ar3,
                            int* __restrict__ cursor, int nh4, int n) {
    int i = blockIdx.x * blockDim.x + threadIdx.x;
    if (i < nh4) {
        float4 v = ((const float4*)h)[i];
        ushort4 o;
        o.x = f2bf(v.x); o.y = f2bf(v.y); o.z = f2bf(v.z); o.w = f2bf(v.w);
        ((ushort4*)xbh)[i] = o;
        return;
    }
    int j = i - nh4;
    if (j < 16384) {                      // W1 castT
        int c = j >> 7, k = j & 127;
        int kd = k ^ ((c & 7) << 3);
        W1th[c * 128 + kd] = f2bf(W1[k * 128 + c]);
    } else if (j < 32768) {               // W2 castT
        j -= 16384;
        int c = j >> 7, k = j & 127;
        int kd = k ^ ((c & 7) << 3);
        W2th[c * 128 + kd] = f2bf(W2[k * 128 + c]);
    } else if (j < 40960) {               // Bpre cols 0..63: rWm fold
        j -= 32768;
        int c = j >> 7, k = j & 127;
        const float* row = rW3 + (size_t)k * 256;
        float v = 0.25f * ((row[c] + row[64 + c]) + (row[128 + c] + row[192 + c]));
        int kd = k ^ ((c & 7) << 3);
        Bpre[c * 128 + kd] = f2bf(v);
    } else if (j < 41984) {               // Bpre cols 64..71: pl3 / pr3
        j -= 40960;
        int c2 = j >> 7, k = j & 127;     // c2 0..7
        int hh = c2 & 3;
        const float* vec = (c2 < 4) ? al3 : ar3;
        const float* wrow = W3 + (size_t)k * 256 + hh * 64;
        const float* vrow = vec + hh * 64;
        float s = 0.f;
        for (int d = 0; d < 64; ++d) s += wrow[d] * vrow[d];
        int c = 64 + c2;
        int kd = k ^ ((c & 7) << 3);
        Bpre[c * 128 + kd] = f2bf(s);
    } else if (j < 43008) {               // Bpre cols 72..79: zero
        j -= 41984;
        Bpre[72 * 128 + j] = 0;
    } else if (j < 75776) {               // Wft: [64 cols][512 k]
        j -= 43008;
        int c = j >> 9, k = j & 511;      // c 0..63, k 0..511
        int hh = k >> 7, d = k & 127;
        float v = 0.25f * W3[(size_t)d * 256 + hh * 64 + c];
        int kd = k ^ ((c & 7) << 3);
        Wft[c * 512 + kd] = f2bf(v);
    } else if (j < 75776 + n) {           // cursor zero
        cursor[j - 75776] = 0;
    }
}

// ------------------------------- GEMM (layers 1/2) ---------------------------
// C[M,128] = X[M,128] @ W; 4 waves, tile 128Mx128N; W slice 32KB in LDS.
// Epilogue: bf16 C + fused el/er (dshift=5: 2 heads per 64-col half).

__global__ void __launch_bounds__(256)
gemm_kernel(const ushort* __restrict__ Ah, const ushort* __restrict__ Bth,
            ushort* __restrict__ Cb,
            const float* __restrict__ alv, const float* __restrict__ arv,
            float* __restrict__ el, float* __restrict__ er, int M) {
    __shared__ ushort Ws[128 * 128];          // 32 KB
    const int tid = threadIdx.x;
    const int wv = tid >> 6;
    const int lane = tid & 63;
    const int l15 = lane & 15;
    const int g = lane >> 4;
    const int bm = blockIdx.x * 128 + wv * 32;

    {
        const uint4* gh = (const uint4*)Bth;
        uint4* sh = (uint4*)Ws;
#pragma unroll
        for (int it = 0; it < 8; ++it) sh[it * 256 + tid] = gh[it * 256 + tid];
    }
    __syncthreads();

    const int m0 = bm + l15;
    const int m1 = bm + 16 + l15;
    const int mc0 = (m0 < M) ? m0 : (M - 1);
    const int mc1 = (m1 < M) ? m1 : (M - 1);
    bf16x8 xh[2][4];
#pragma unroll
    for (int kk = 0; kk < 4; ++kk) {
        xh[0][kk] = *(const bf16x8*)(Ah + (size_t)mc0 * 128 + kk * 32 + g * 8);
        xh[1][kk] = *(const bf16x8*)(Ah + (size_t)mc1 * 128 + kk * 32 + g * 8);
    }

    f32x4 acc[2][8] = {};
    const int swz = (l15 & 7) << 4;
#pragma unroll
    for (int n = 0; n < 8; ++n) {
        const int colb = (n * 16 + l15) * 256;
#pragma unroll
        for (int kk = 0; kk < 4; ++kk) {
            const int boff = colb + ((kk * 64 + g * 16) ^ swz);
            bf16x8 wh = *(const bf16x8*)((const char*)Ws + boff);
            acc[0][n] = __builtin_amdgcn_mfma_f32_16x16x32_bf16(wh, xh[0][kk], acc[0][n], 0, 0, 0);
            acc[1][n] = __builtin_amdgcn_mfma_f32_16x16x32_bf16(wh, xh[1][kk], acc[1][n], 0, 0, 0);
        }
    }

#pragma unroll
    for (int mf = 0; mf < 2; ++mf) {
        const int m = (mf == 0) ? m0 : m1;
        const bool valid = (m < M);
        if (valid) {
            size_t ro = (size_t)m * 128;
#pragma unroll
            for (int n = 0; n < 8; ++n) {
                int col = n * 16 + g * 4;
                ushort4 o;
                o.x = f2bf(acc[mf][n][0]); o.y = f2bf(acc[mf][n][1]);
                o.z = f2bf(acc[mf][n][2]); o.w = f2bf(acc[mf][n][3]);
                *(ushort4*)&Cb[ro + col] = o;
            }
        }
        float e0 = 0.f, e1 = 0.f, e2 = 0.f, e3 = 0.f;
        float r0 = 0.f, r1 = 0.f, r2 = 0.f, r3 = 0.f;
#pragma unroll
        for (int n = 0; n < 8; ++n) {
            float se = 0.f, sr = 0.f;
#pragma unroll
            for (int rr = 0; rr < 4; ++rr) {
                int col = n * 16 + g * 4 + rr;
                float c = acc[mf][n][rr];
                se += c * alv[col];
                sr += c * arv[col];
            }
            if (n < 2)      { e0 += se; r0 += sr; }
            else if (n < 4) { e1 += se; r1 += sr; }
            else if (n < 6) { e2 += se; r2 += sr; }
            else            { e3 += se; r3 += sr; }
        }
        e0 += __shfl_xor(e0, 16); e0 += __shfl_xor(e0, 32);
        e1 += __shfl_xor(e1, 16); e1 += __shfl_xor(e1, 32);
        e2 += __shfl_xor(e2, 16); e2 += __shfl_xor(e2, 32);
        e3 += __shfl_xor(e3, 16); e3 += __shfl_xor(e3, 32);
        r0 += __shfl_xor(r0, 16); r0 += __shfl_xor(r0, 32);
        r1 += __shfl_xor(r1, 16); r1 += __shfl_xor(r1, 32);
        r2 += __shfl_xor(r2, 16); r2 += __shfl_xor(r2, 32);
        r3 += __shfl_xor(r3, 16); r3 += __shfl_xor(r3, 32);
        if (valid && g == 0) {
            el[m * 4 + 0] = e0; el[m * 4 + 1] = e1;
            el[m * 4 + 2] = e2; el[m * 4 + 3] = e3;
            er[m * 4 + 0] = r0; er[m * 4 + 1] = r1;
            er[m * 4 + 2] = r2; er[m * 4 + 3] = r3;
        }
    }
}

// ------------------------------- pre3 ----------------------------------------
// [N,128] @ Bpre[128,80] -> resmean fp32 (cols 0..63), el3 (64..67), er3 (68..71).

__global__ void __launch_bounds__(256)
pre3_kernel(const ushort* __restrict__ Ah, const ushort* __restrict__ Bpre,
            float* __restrict__ resmean, float* __restrict__ el,
            float* __restrict__ er, int M) {
    __shared__ ushort Ws[80 * 128];           // 20 KB
    const int tid = threadIdx.x;
    const int wv = tid >> 6;
    const int lane = tid & 63;
    const int l15 = lane & 15;
    const int g = lane >> 4;
    const int bm = blockIdx.x * 128 + wv * 32;

    {
        const uint4* gh = (const uint4*)Bpre;
        uint4* sh = (uint4*)Ws;
#pragma unroll
        for (int it = 0; it < 5; ++it) sh[it * 256 + tid] = gh[it * 256 + tid];
    }
    __syncthreads();

    const int m0 = bm + l15;
    const int m1 = bm + 16 + l15;
    const int mc0 = (m0 < M) ? m0 : (M - 1);
    const int mc1 = (m1 < M) ? m1 : (M - 1);
    bf16x8 xh[2][4];
#pragma unroll
    for (int kk = 0; kk < 4; ++kk) {
        xh[0][kk] = *(const bf16x8*)(Ah + (size_t)mc0 * 128 + kk * 32 + g * 8);
        xh[1][kk] = *(const bf16x8*)(Ah + (size_t)mc1 * 128 + kk * 32 + g * 8);
    }

    f32x4 acc[2][5] = {};
    const int swz = (l15 & 7) << 4;
#pragma unroll
    for (int n = 0; n < 5; ++n) {
        const int colb = (n * 16 + l15) * 256;
#pragma unroll
        for (int kk = 0; kk < 4; ++kk) {
            const int boff = colb + ((kk * 64 + g * 16) ^ swz);
            bf16x8 wh = *(const bf16x8*)((const char*)Ws + boff);
            acc[0][n] = __builtin_amdgcn_mfma_f32_16x16x32_bf16(wh, xh[0][kk], acc[0][n], 0, 0, 0);
            acc[1][n] = __builtin_amdgcn_mfma_f32_16x16x32_bf16(wh, xh[1][kk], acc[1][n], 0, 0, 0);
        }
    }

#pragma unroll
    for (int mf = 0; mf < 2; ++mf) {
        const int m = (mf == 0) ? m0 : m1;
        if (m >= M) continue;
#pragma unroll
        for (int n = 0; n < 4; ++n) {
            *(float4*)&resmean[(size_t)m * 64 + n * 16 + g * 4] =
                make_float4(acc[mf][n][0], acc[mf][n][1], acc[mf][n][2], acc[mf][n][3]);
        }
        if (g == 0) {
#pragma unroll
            for (int r = 0; r < 4; ++r) el[m * 4 + r] = acc[mf][4][r];
        } else if (g == 1) {
#pragma unroll
            for (int r = 0; r < 4; ++r) er[m * 4 + r] = acc[mf][4][r];
        }
    }
}

// --------------------------- aggregation -------------------------------------
// Layers 1/2: unchanged (wave = 2 halves x 2 edges/step, uint2 gathers).

__global__ void __launch_bounds__(256)
aggregate12_kernel(const ushort* __restrict__ featb, const float* __restrict__ el,
                   const float* __restrict__ er, const int* __restrict__ row_ptr,
                   const int* __restrict__ ssrc, const float* __restrict__ resf,
                   const ushort* __restrict__ rxh, ushort* __restrict__ xbh, int n) {
    const int wid = threadIdx.x >> 6;
    const int lane = threadIdx.x & 63;
    const int node = blockIdx.x * 4 + wid;
    if (node >= n) return;
    const int beg = row_ptr[node];
    const int end = row_ptr[node + 1];
    const int half = lane >> 5;
    const int l32 = lane & 31;
    const int hh = l32 >> 3;
    const float erh = er[node * 4 + hh];

    float ssum = 0.f, a0 = 0.f, a1 = 0.f, a2 = 0.f, a3 = 0.f;
    int p = beg;
    for (; p + 8 <= end; p += 8) {
        int s[4]; uint2 v[4]; float e[4];
#pragma unroll
        for (int j = 0; j < 4; ++j) s[j] = ssrc[p + 2 * j + half];
#pragma unroll
        for (int j = 0; j < 4; ++j) v[j] = *(const uint2*)&featb[(size_t)s[j] * 128 + l32 * 4];
#pragma unroll
        for (int j = 0; j < 4; ++j) e[j] = el[s[j] * 4 + hh];
#pragma unroll
        for (int j = 0; j < 4; ++j) {
            float w = __expf(leaky(e[j] + erh));
            ssum += w;
            a0 += w * lo16f(v[j].x);
            a1 += w * hi16f(v[j].x);
            a2 += w * lo16f(v[j].y);
            a3 += w * hi16f(v[j].y);
        }
    }
    for (; p < end; p += 2) {
        int pe = p + half;
        bool ok = pe < end;
        int s = ssrc[ok ? pe : beg];
        uint2 v = *(const uint2*)&featb[(size_t)s * 128 + l32 * 4];
        float w = ok ? __expf(leaky(el[s * 4 + hh] + erh)) : 0.f;
        ssum += w;
        a0 += w * lo16f(v.x);
        a1 += w * hi16f(v.x);
        a2 += w * lo16f(v.y);
        a3 += w * hi16f(v.y);
    }
    ssum += __shfl_xor(ssum, 32);
    a0 += __shfl_xor(a0, 32);
    a1 += __shfl_xor(a1, 32);
    a2 += __shfl_xor(a2, 32);
    a3 += __shfl_xor(a3, 32);
    float inv = (end > beg) ? 1.f / ssum : 0.f;
    if (half == 0) {
        size_t o = (size_t)node * 128 + l32 * 4;
        float rb0, rb1, rb2, rb3;
        if (resf) {
            float4 f = *(const float4*)&resf[o];
            rb0 = f.x; rb1 = f.y; rb2 = f.z; rb3 = f.w;
        } else {
            uint2 rh = *(const uint2*)&rxh[o];
            rb0 = lo16f(rh.x);
            rb1 = hi16f(rh.x);
            rb2 = lo16f(rh.y);
            rb3 = hi16f(rh.y);
        }
        float r0 = fmaxf(a0 * inv + rb0, 0.f);
        float r1 = fmaxf(a1 * inv + rb1, 0.f);
        float r2 = fmaxf(a2 * inv + rb2, 0.f);
        float r3 = fmaxf(a3 * inv + rb3, 0.f);
        uint2 oh;
        oh.x = (unsigned)f2bf(r0) | ((unsigned)f2bf(r1) << 16);
        oh.y = (unsigned)f2bf(r2) | ((unsigned)f2bf(r3) << 16);
        *(uint2*)&xbh[o] = oh;
    }
}

// Layer 3: gather x[src] (256B/edge), accumulate 4 per-head 128-dim sums.
// Wave = 2 halves x 2 edges/step; lane l32 owns dims 4*l32..4*l32+3.
// w per head computed on lanes l32<4, broadcast via shfl; per-head ssum on
// those lanes. Output: aggv bf16 [N][4][128] (normalized).

__global__ void __launch_bounds__(256)
aggregate3_kernel(const ushort* __restrict__ xb, const float* __restrict__ el,
                  const float* __restrict__ er, const int* __restrict__ row_ptr,
                  const int* __restrict__ ssrc, ushort* __restrict__ aggv, int n) {
    const int wid = threadIdx.x >> 6;
    const int lane = threadIdx.x & 63;
    const int node = blockIdx.x * 4 + wid;
    if (node >= n) return;
    const int beg = row_ptr[node];
    const int end = row_ptr[node + 1];
    const int half = lane >> 5;
    const int l32 = lane & 31;
    const int hsel = l32 & 3;
    const float erh = er[node * 4 + hsel];   // used only on lanes l32<4
    const int wbase = half << 5;

    float acc[4][4] = {};
    float ssuml = 0.f;                        // per-head partial on lanes l32<4
    int p = beg;
    for (; p + 8 <= end; p += 8) {
        int s[4]; uint2 v[4];
#pragma unroll
        for (int j = 0; j < 4; ++j) s[j] = ssrc[p + 2 * j + half];
#pragma unroll
        for (int j = 0; j < 4; ++j) v[j] = *(const uint2*)&xb[(size_t)s[j] * 128 + l32 * 4];
#pragma unroll
        for (int j = 0; j < 4; ++j) {
            float ww = (l32 < 4) ? __expf(leaky(el[s[j] * 4 + hsel] + erh)) : 0.f;
            ssuml += ww;
            float w0 = __shfl(ww, wbase + 0);
            float w1 = __shfl(ww, wbase + 1);
            float w2 = __shfl(ww, wbase + 2);
            float w3 = __shfl(ww, wbase + 3);
            float x0 = lo16f(v[j].x), x1 = hi16f(v[j].x);
            float x2 = lo16f(v[j].y), x3 = hi16f(v[j].y);
            acc[0][0] += w0 * x0; acc[0][1] += w0 * x1; acc[0][2] += w0 * x2; acc[0][3] += w0 * x3;
            acc[1][0] += w1 * x0; acc[1][1] += w1 * x1; acc[1][2] += w1 * x2; acc[1][3] += w1 * x3;
            acc[2][0] += w2 * x0; acc[2][1] += w2 * x1; acc[2][2] += w2 * x2; acc[2][3] += w2 * x3;
            acc[3][0] += w3 * x0; acc[3][1] += w3 * x1; acc[3][2] += w3 * x2; acc[3][3] += w3 * x3;
        }
    }
    for (; p < end; p += 2) {
        int pe = p + half;
        bool ok = pe < end;
        int s = ssrc[ok ? pe : beg];
        uint2 v = *(const uint2*)&xb[(size_t)s * 128 + l32 * 4];
        float ww = (ok && l32 < 4) ? __expf(leaky(el[s * 4 + hsel] + erh)) : 0.f;
        ssuml += ww;
        float w0 = __shfl(ww, wbase + 0);
        float w1 = __shfl(ww, wbase + 1);
        float w2 = __shfl(ww, wbase + 2);
        float w3 = __shfl(ww, wbase + 3);
        if (!ok) { w0 = w1 = w2 = w3 = 0.f; }
        float x0 = lo16f(v.x), x1 = hi16f(v.x);
        float x2 = lo16f(v.y), x3 = hi16f(v.y);
        acc[0][0] += w0 * x0; acc[0][1] += w0 * x1; acc[0][2] += w0 * x2; acc[0][3] += w0 * x3;
        acc[1][0] += w1 * x0; acc[1][1] += w1 * x1; acc[1][2] += w1 * x2; acc[1][3] += w1 * x3;
        acc[2][0] += w2 * x0; acc[2][1] += w2 * x1; acc[2][2] += w2 * x2; acc[2][3] += w2 * x3;
        acc[3][0] += w3 * x0; acc[3][1] += w3 * x1; acc[3][2] += w3 * x2; acc[3][3] += w3 * x3;
    }
    // combine halves
#pragma unroll
    for (int hh = 0; hh < 4; ++hh)
#pragma unroll
        for (int d = 0; d < 4; ++d) acc[hh][d] += __shfl_xor(acc[hh][d], 32);
    // per-head denominators (partials live on lanes 0..3 and 32..35)
    float s0 = __shfl(ssuml, 0) + __shfl(ssuml, 32);
    float s1 = __shfl(ssuml, 1) + __shfl(ssuml, 33);
    float s2 = __shfl(ssuml, 2) + __shfl(ssuml, 34);
    float s3 = __shfl(ssuml, 3) + __shfl(ssuml, 35);
    if (half == 0) {
        const bool has = (end > beg);
        float i0 = has ? 1.f / s0 : 0.f;
        float i1 = has ? 1.f / s1 : 0.f;
        float i2 = has ? 1.f / s2 : 0.f;
        float i3 = has ? 1.f / s3 : 0.f;
        float iv[4] = { i0, i1, i2, i3 };
        size_t base = (size_t)node * 512 + l32 * 4;
#pragma unroll
        for (int hh = 0; hh < 4; ++hh) {
            float r0 = acc[hh][0] * iv[hh];
            float r1 = acc[hh][1] * iv[hh];
            float r2 = acc[hh][2] * iv[hh];
            float r3 = acc[hh][3] * iv[hh];
            uint2 o;
            o.x = (unsigned)f2bf(r0) | ((unsigned)f2bf(r1) << 16);
            o.y = (unsigned)f2bf(r2) | ((unsigned)f2bf(r3) << 16);
            *(uint2*)&aggv[base + hh * 128] = o;
        }
    }
}

// ------------------------------- fin ----------------------------------------
// out[N,64] = aggv[N,512] @ Wft[512,64] + resmean. Wft staged in 64KB LDS.

__global__ void __launch_bounds__(256)
fin_kernel(const ushort* __restrict__ aggv, const ushort* __restrict__ Wft,
           const float* __restrict__ resmean, float* __restrict__ out, int M) {
    __shared__ ushort Ws[64 * 512];           // 64 KB
    const int tid = threadIdx.x;
    const int wv = tid >> 6;
    const int lane = tid & 63;
    const int l15 = lane & 15;
    const int g = lane >> 4;
    const int bm = blockIdx.x * 128 + wv * 32;

    {
        const uint4* gh = (const uint4*)Wft;
        uint4* sh = (uint4*)Ws;
#pragma unroll
        for (int it = 0; it < 16; ++it) sh[it * 256 + tid] = gh[it * 256 + tid];
    }
    __syncthreads();

    const int m0 = bm + l15;
    const int m1 = bm + 16 + l15;
    const int mc0 = (m0 < M) ? m0 : (M - 1);
    const int mc1 = (m1 < M) ? m1 : (M - 1);

    f32x4 acc[2][4] = {};
    const int swz = (l15 & 7) << 4;
#pragma unroll
    for (int kk = 0; kk < 16; ++kk) {
        bf16x8 x0 = *(const bf16x8*)(aggv + (size_t)mc0 * 512 + kk * 32 + g * 8);
        bf16x8 x1 = *(const bf16x8*)(aggv + (size_t)mc1 * 512 + kk * 32 + g * 8);
#pragma unroll
        for (int n = 0; n < 4; ++n) {
            const int boff = (n * 16 + l15) * 1024 + ((kk * 64 + g * 16) ^ swz);
            bf16x8 wh = *(const bf16x8*)((const char*)Ws + boff);
            acc[0][n] = __builtin_amdgcn_mfma_f32_16x16x32_bf16(wh, x0, acc[0][n], 0, 0, 0);
            acc[1][n] = __builtin_amdgcn_mfma_f32_16x16x32_bf16(wh, x1, acc[1][n], 0, 0, 0);
        }
    }

#pragma unroll
    for (int mf = 0; mf < 2; ++mf) {
        const int m = (mf == 0) ? m0 : m1;
        if (m >= M) continue;
#pragma unroll
        for (int n = 0; n < 4; ++n) {
            float4 rm = *(const float4*)&resmean[(size_t)m * 64 + n * 16 + g * 4];
            *(float4*)&out[(size_t)m * 64 + n * 16 + g * 4] =
                make_float4(acc[mf][n][0] + rm.x, acc[mf][n][1] + rm.y,
                            acc[mf][n][2] + rm.z, acc[mf][n][3] + rm.w);
        }
    }
}

// ------------------------------ launch ---------------------------------------

extern "C" void kernel_launch(void* const* d_in, const int* in_sizes, int n_in,
                              void* d_out, int out_size, void* d_ws, size_t ws_size,
                              hipStream_t stream) {
    const float* h   = (const float*)d_in[0];
    const float* W1  = (const float*)d_in[1];
    const float* al1 = (const float*)d_in[2];
    const float* ar1 = (const float*)d_in[3];
    const float* W2  = (const float*)d_in[4];
    const float* al2 = (const float*)d_in[5];
    const float* ar2 = (const float*)d_in[6];
    const float* W3  = (const float*)d_in[7];
    const float* al3 = (const float*)d_in[8];
    const float* ar3 = (const float*)d_in[9];
    const float* rW3 = (const float*)d_in[10];
    const int* src   = (const int*)d_in[11];
    const int* dstv  = (const int*)d_in[12];
    const int N = in_sizes[0] / 128;
    const int E = in_sizes[11];
    float* out = (float*)d_out;

    char* p = (char*)d_ws;
    auto alloc = [&](size_t bytes) -> char* {
        char* q = p;
        p += (bytes + 255) & ~(size_t)255;
        return q;
    };
    int*    row_ptr = (int*)alloc((size_t)(N + 1) * 4);
    int*    cursor  = (int*)alloc((size_t)N * 4);
    int*    loc     = (int*)alloc((size_t)N * 4);
    int*    bsum    = (int*)alloc(64 * 4);
    int*    ssrc    = (int*)alloc((size_t)E * 4);
    float*  el      = (float*)alloc((size_t)N * 16);
    float*  er      = (float*)alloc((size_t)N * 16);
    ushort* featb   = (ushort*)alloc((size_t)N * 128 * 2);
    ushort* xbh     = (ushort*)alloc((size_t)N * 128 * 2);
    ushort* aggv    = (ushort*)alloc((size_t)N * 512 * 2);
    ushort* W1th = (ushort*)alloc(128 * 128 * 2);
    ushort* W2th = (ushort*)alloc(128 * 128 * 2);
    ushort* Bpre = (ushort*)alloc(80 * 128 * 2);
    ushort* Wft  = (ushort*)alloc(64 * 512 * 2);
    float*  resmean = (float*)alloc((size_t)N * 64 * 4);

    // fused prep
    const int nh4 = N * 32;               // N*128/4 float4 groups
    const int prep_total = nh4 + 75776 + N;
    prep_kernel<<<(prep_total + 255) / 256, 256, 0, stream>>>(
        h, xbh, W1, W1th, W2, W2th, W3, Bpre, Wft, rW3, al3, ar3, cursor, nh4, N);

    // CSR build
    hist_kernel<<<(E + 255) / 256, 256, 0, stream>>>(dstv, cursor, E);
    int nb = (N + 1023) / 1024;
    block_scan_kernel<<<nb, 1024, 0, stream>>>(cursor, loc, bsum, N);
    apply_scan_kernel<<<(N + 255) / 256, 256, 0, stream>>>(loc, bsum, row_ptr, cursor, N, nb);
    scatter_kernel<<<(E + 255) / 256, 256, 0, stream>>>(src, dstv, cursor, ssrc, E);

    const int gx = (N + 127) / 128;
    int agg_grid = (N + 3) / 4;

    // layer 1 (residual from fp32 h)
    gemm_kernel<<<gx, 256, 0, stream>>>(xbh, W1th, featb, al1, ar1, el, er, N);
    aggregate12_kernel<<<agg_grid, 256, 0, stream>>>(featb, el, er, row_ptr, ssrc,
                                                     h, nullptr, xbh, N);

    // layer 2 (residual from bf16 x)
    gemm_kernel<<<gx, 256, 0, stream>>>(xbh, W2th, featb, al2, ar2, el, er, N);
    aggregate12_kernel<<<agg_grid, 256, 0, stream>>>(featb, el, er, row_ptr, ssrc,
                                                     nullptr, xbh, xbh, N);

    // layer 3: pre-projections, x-aggregation, final block-diag GEMM
    pre3_kernel<<<gx, 256, 0, stream>>>(xbh, Bpre, resmean, el, er, N);
    aggregate3_kernel<<<agg_grid, 256, 0, stream>>>(xbh, el, er, row_ptr, ssrc, aggv, N);
    fin_kernel<<<gx, 256, 0, stream>>>(aggv, Wft, resmean, out, N);
}